// Round 1
// baseline (5516.801 us; speedup 1.0000x reference)
//
#include <hip/hip_runtime.h>
#include <stdint.h>

#define NU 100000
#define NI 50000
#define NBK 10
#define DD 64
#define NE 1000000
#define BATCH 2048
#define LDSW 68

// ---------------- threefry2x32 (JAX-compatible, 20 rounds) ----------------
__host__ __device__ inline void tf2x32(uint32_t k0, uint32_t k1, uint32_t x0, uint32_t x1,
                                       uint32_t& o0, uint32_t& o1) {
  uint32_t ks0 = k0, ks1 = k1, ks2 = k0 ^ k1 ^ 0x1BD11BDAu;
  x0 += ks0; x1 += ks1;
#define TFR(r) { x0 += x1; x1 = (x1 << (r)) | (x1 >> (32 - (r))); x1 ^= x0; }
  TFR(13) TFR(15) TFR(26) TFR(6)   x0 += ks1; x1 += ks2 + 1u;
  TFR(17) TFR(29) TFR(16) TFR(24)  x0 += ks2; x1 += ks0 + 2u;
  TFR(13) TFR(15) TFR(26) TFR(6)   x0 += ks0; x1 += ks1 + 3u;
  TFR(17) TFR(29) TFR(16) TFR(24)  x0 += ks1; x1 += ks2 + 4u;
  TFR(13) TFR(15) TFR(26) TFR(6)   x0 += ks2; x1 += ks0 + 5u;
#undef TFR
  o0 = x0; o1 = x1;
}

// JAX original random_bits: iota split in half; element i<half gets out0 of
// hash(i, i+half), element i+half gets out1. uniform = bitcast(bits>>9|1.0f)-1.
__global__ void drop_kernel(const float* __restrict__ vals, float* __restrict__ out,
                            uint32_t k0, uint32_t k1) {
  int i = blockIdx.x * blockDim.x + threadIdx.x;
  const int half = NE / 2;
  if (i >= half) return;
  uint32_t o0, o1;
  tf2x32(k0, k1, (uint32_t)i, (uint32_t)(i + half), o0, o1);
  float u0 = __uint_as_float((o0 >> 9) | 0x3f800000u) - 1.0f;
  float u1 = __uint_as_float((o1 >> 9) | 0x3f800000u) - 1.0f;
  out[i]        = (u0 < 0.75f) ? vals[i] / 0.75f : 0.0f;
  out[i + half] = (u1 < 0.75f) ? vals[i + half] / 0.75f : 0.0f;
}

__global__ void init2_kernel(const float4* __restrict__ s, float4* __restrict__ a,
                             float4* __restrict__ b, int n) {
  for (int i = blockIdx.x * blockDim.x + threadIdx.x; i < n; i += gridDim.x * blockDim.x) {
    float4 v = s[i]; a[i] = v; b[i] = v;
  }
}

__global__ void add_kernel(float4* __restrict__ a, const float4* __restrict__ b, int n) {
  for (int i = blockIdx.x * blockDim.x + threadIdx.x; i < n; i += gridDim.x * blockDim.x) {
    float4 x = a[i], y = b[i];
    x.x += y.x; x.y += y.y; x.z += y.z; x.w += y.w;
    a[i] = x;
  }
}

// one wave per edge: lane = dim; coalesced gather of src row, atomic scatter to dst row
__global__ void spmm_kernel(const float* __restrict__ v, const int* __restrict__ dst,
                            const int* __restrict__ src, const float* __restrict__ S,
                            float* __restrict__ Dacc) {
  int lane = threadIdx.x & 63;
  int w = (blockIdx.x * blockDim.x + threadIdx.x) >> 6;
  int nw = (gridDim.x * blockDim.x) >> 6;
  for (int e = w; e < NE; e += nw) {
    float val = v[e];
    if (val != 0.0f) {
      int di = dst[e], si = src[e];
      atomicAdd(&Dacc[(size_t)di * DD + lane], val * S[(size_t)si * DD + lane]);
    }
  }
}

__global__ void edge_logit_kernel(const float* __restrict__ Eu, const float* __restrict__ Ev,
                                  const int* __restrict__ rows, const int* __restrict__ cols,
                                  const float* __restrict__ av, float* __restrict__ aug) {
  int lane = threadIdx.x & 63;
  int w = (blockIdx.x * blockDim.x + threadIdx.x) >> 6;
  int nw = (gridDim.x * blockDim.x) >> 6;
  for (int e = w; e < NE; e += nw) {
    float p = Eu[(size_t)rows[e] * DD + lane] * Ev[(size_t)cols[e] * DD + lane];
#pragma unroll
    for (int off = 32; off > 0; off >>= 1) p += __shfl_down(p, off);
    if (lane == 0) aug[e] = av[e] / (1.0f + __expf(-p));
  }
}

// S[b] += sum_j exp(dot(Z[ids[b]], E[j]) / TEMP) over this block's 64-j tile.
// 64x64 tile, K=64 in one pass. Strided 4x4 register tiles (rows ty+16i) keep
// LDS float4 reads at <=2-way bank aliasing (free).
__global__ __launch_bounds__(256)
void pcl_gemm_kernel(const float* __restrict__ Z, const float* __restrict__ E,
                     const int* __restrict__ ids, int nJ, float* __restrict__ S) {
  __shared__ float Zs[64 * LDSW];
  __shared__ float Es[64 * LDSW];
  int tid = threadIdx.x;
  int bm = blockIdx.y, bn = blockIdx.x;
  for (int f = tid; f < 64 * 16; f += 256) {
    int r = f >> 4, kq = f & 15;
    const float* zp = Z + (size_t)ids[bm * 64 + r] * DD + kq * 4;
    *(float4*)&Zs[r * LDSW + kq * 4] = *(const float4*)zp;
  }
  for (int f = tid; f < 64 * 16; f += 256) {
    int r = f >> 4, kq = f & 15;
    int j = bn * 64 + r;
    float4 v = make_float4(0.f, 0.f, 0.f, 0.f);
    if (j < nJ) v = *(const float4*)&E[(size_t)j * DD + kq * 4];
    *(float4*)&Es[r * LDSW + kq * 4] = v;
  }
  __syncthreads();
  int ty = tid >> 4, tx = tid & 15;
  float acc[4][4] = {};
#pragma unroll
  for (int kq = 0; kq < 16; ++kq) {
    float4 a[4], bb[4];
#pragma unroll
    for (int i = 0; i < 4; ++i) a[i] = *(const float4*)&Zs[(ty + 16 * i) * LDSW + kq * 4];
#pragma unroll
    for (int i = 0; i < 4; ++i) bb[i] = *(const float4*)&Es[(tx + 16 * i) * LDSW + kq * 4];
#pragma unroll
    for (int i = 0; i < 4; ++i)
#pragma unroll
      for (int jj = 0; jj < 4; ++jj)
        acc[i][jj] += a[i].x * bb[jj].x + a[i].y * bb[jj].y + a[i].z * bb[jj].z + a[i].w * bb[jj].w;
  }
#pragma unroll
  for (int i = 0; i < 4; ++i) {
    float rs = 0.f;
#pragma unroll
    for (int jj = 0; jj < 4; ++jj) {
      int j = bn * 64 + tx + 16 * jj;
      if (j < nJ) rs += __expf(acc[i][jj] * 5.0f);   // 1/TEMP = 5
    }
#pragma unroll
    for (int off = 8; off > 0; off >>= 1) rs += __shfl_down(rs, off, 16);
    if (tx == 0) atomicAdd(&S[bm * 64 + ty + 16 * i], rs);
  }
}

__global__ void bpr_kernel(const float* __restrict__ Eu, const float* __restrict__ Ev,
                           const int* __restrict__ uids, const int* __restrict__ pos,
                           const int* __restrict__ neg, float* __restrict__ ps,
                           float* __restrict__ acc) {
  int lane = threadIdx.x & 63;
  int b = (blockIdx.x * blockDim.x + threadIdx.x) >> 6;
  if (b >= BATCH) return;
  float u = Eu[(size_t)uids[b] * DD + lane];
  float p = u * Ev[(size_t)pos[b] * DD + lane];
  float n = u * Ev[(size_t)neg[b] * DD + lane];
#pragma unroll
  for (int off = 32; off > 0; off >>= 1) { p += __shfl_down(p, off); n += __shfl_down(n, off); }
  if (lane == 0) {
    ps[b] = p;
    float x = p - n;
    atomicAdd(&acc[0], logf(1.0f / (1.0f + __expf(-x))));
  }
}

__global__ void minmax_kernel(const float* __restrict__ ps, float* __restrict__ mm) {
  __shared__ float smn[256], smx[256];
  int tid = threadIdx.x;
  float mn = 3.0e38f, mx = -3.0e38f;
  for (int i = tid; i < BATCH; i += 256) { float v = ps[i]; mn = fminf(mn, v); mx = fmaxf(mx, v); }
  smn[tid] = mn; smx[tid] = mx;
  __syncthreads();
  for (int s = 128; s > 0; s >>= 1) {
    if (tid < s) { smn[tid] = fminf(smn[tid], smn[tid + s]); smx[tid] = fmaxf(smx[tid], smx[tid + s]); }
    __syncthreads();
  }
  if (tid == 0) { mm[0] = smn[0]; mm[1] = smx[0]; }
}

__global__ void bcl_kernel(const float* __restrict__ Eu, const float* __restrict__ Ev,
                           const float* __restrict__ Eb, const int* __restrict__ uids,
                           const int* __restrict__ pos, const float* __restrict__ ps,
                           const float* __restrict__ mm, float* __restrict__ acc) {
  int lane = threadIdx.x & 63;
  int b = (blockIdx.x * blockDim.x + threadIdx.x) >> 6;
  if (b >= BATCH) return;
  float wgt = (ps[b] - mm[0]) / (mm[1] - mm[0] + 1e-9f);
  int rel = (int)(wgt * 10.0f);
  rel = rel < 0 ? 0 : (rel > 9 ? 9 : rel);
  float el = 1.0f / (1.0f + __expf(-(Eu[(size_t)uids[b] * DD + lane] * Ev[(size_t)pos[b] * DD + lane])));
  float sneg = 0.f, spos = 0.f;
  for (int k = 0; k < NBK; ++k) {
    float d = el * Eb[k * DD + lane];
#pragma unroll
    for (int off = 32; off > 0; off >>= 1) d += __shfl_down(d, off);
    if (lane == 0) { if (k == rel) spos = d; else sneg += d; }
  }
  if (lane == 0) {
    atomicAdd(&acc[5], sneg * 0.1f);   // inner mean over N_B=10 includes the masked zero
    atomicAdd(&acc[6], spos);
  }
}

__global__ void pclpos_kernel(const float* __restrict__ Zc, const float* __restrict__ Ec,
                              const int* __restrict__ ids, float* __restrict__ acc, int idx) {
  int lane = threadIdx.x & 63;
  int b = (blockIdx.x * blockDim.x + threadIdx.x) >> 6;
  if (b >= BATCH) return;
  size_t r = (size_t)ids[b] * DD + lane;
  float p = Zc[r] * Ec[r];
#pragma unroll
  for (int off = 32; off > 0; off >>= 1) p += __shfl_down(p, off);
  if (lane == 0) {
    float x = p * 5.0f;
    x = fminf(5.0f, fmaxf(-5.0f, x));
    atomicAdd(&acc[idx], x);
  }
}

__global__ void sumsq_kernel(const float* __restrict__ x, int n, float* __restrict__ acc, int idx) {
  __shared__ float red[256];
  int tid = threadIdx.x;
  float s = 0.f;
  for (int i = blockIdx.x * blockDim.x + tid; i < n; i += gridDim.x * blockDim.x) {
    float v = x[i]; s += v * v;
  }
  red[tid] = s;
  __syncthreads();
  for (int st = 128; st > 0; st >>= 1) {
    if (tid < st) red[tid] += red[tid + st];
    __syncthreads();
  }
  if (tid == 0) atomicAdd(&acc[idx], red[0]);
}

__global__ void finalize_kernel(const float* __restrict__ Su, const float* __restrict__ Si,
                                const float* __restrict__ acc, float* __restrict__ out) {
  __shared__ float r1[256], r2[256];
  int tid = threadIdx.x;
  float su = 0.f, si = 0.f;
  for (int b = tid; b < BATCH; b += 256) {
    su += logf(Su[b] + 1e-8f);
    si += logf(Si[b] + 1e-8f);
  }
  r1[tid] = su; r2[tid] = si;
  __syncthreads();
  for (int s = 128; s > 0; s >>= 1) {
    if (tid < s) { r1[tid] += r1[tid + s]; r2[tid] += r2[tid + s]; }
    __syncthreads();
  }
  if (tid == 0) {
    const float inv = 1.0f / (float)BATCH;
    float neg_s = (r1[0] + r2[0]) * inv;
    float pos_s = (acc[3] + acc[4]) * inv;
    float pcl = neg_s - pos_s;
    float bpr = -acc[0] * inv;
    float bcl = (acc[5] - acc[6]) * inv;
    float reg = 1e-7f * (acc[7] + acc[8] + acc[9]);
    float loss = bpr + 0.2f * pcl + 0.2f * bcl + reg;
    out[0] = loss; out[1] = bpr; out[2] = 0.2f * pcl; out[3] = 0.2f * bcl;
  }
}

extern "C" void kernel_launch(void* const* d_in, const int* in_sizes, int n_in,
                              void* d_out, int out_size, void* d_ws, size_t ws_size,
                              hipStream_t stream) {
  (void)in_sizes; (void)n_in; (void)out_size; (void)ws_size;
  const float* Eu0 = (const float*)d_in[0];
  const float* Ev0 = (const float*)d_in[1];
  const float* Eb  = (const float*)d_in[2];
  const float* av  = (const float*)d_in[3];
  const int* rows  = (const int*)d_in[4];
  const int* cols  = (const int*)d_in[5];
  const int* uids  = (const int*)d_in[6];
  const int* iids  = (const int*)d_in[7];
  const int* pos   = (const int*)d_in[8];
  const int* neg   = (const int*)d_in[9];
  float* out = (float*)d_out;

  float* w = (float*)d_ws;
  size_t o = 0;
  float* bu0 = w + o; o += (size_t)NU * DD;
  float* bu1 = w + o; o += (size_t)NU * DD;
  float* Eu  = w + o; o += (size_t)NU * DD;   // E_u (prop-0 sums)
  float* Zu  = w + o; o += (size_t)NU * DD;   // Z_u (prop-1 sums)
  float* bv0 = w + o; o += (size_t)NI * DD;
  float* bv1 = w + o; o += (size_t)NI * DD;
  float* Ev  = w + o; o += (size_t)NI * DD;
  float* Zi  = w + o; o += (size_t)NI * DD;
  float* dropv = w + o; o += NE;
  float* augv  = w + o; o += NE;
  float* ps  = w + o; o += BATCH;
  float* Su  = w + o; o += BATCH;
  float* Si  = w + o; o += BATCH;
  float* acc = w + o; o += 16;
  float* mm  = w + o; o += 2;

  // key chain: key(42) = (0,42); fold_in(k,d) = threefry2x32(k, [0,d])
  uint32_t bk[2][2], lk[2][4][2];
  tf2x32(0u, 42u, 0u, 0u, bk[0][0], bk[0][1]);
  tf2x32(0u, 42u, 0u, 1u, bk[1][0], bk[1][1]);
  for (int p = 0; p < 2; ++p)
    for (int t = 0; t < 4; ++t)
      tf2x32(bk[p][0], bk[p][1], 0u, (uint32_t)t, lk[p][t][0], lk[p][t][1]);

  auto propagate = [&](const float* vsrc, float* sum_u, float* sum_v, uint32_t (*k4)[2]) {
    float* cu = bu0; float* nu = bu1; float* cv = bv0; float* nv = bv1;
    init2_kernel<<<4096, 256, 0, stream>>>((const float4*)Eu0, (float4*)cu, (float4*)sum_u, NU * DD / 4);
    init2_kernel<<<2048, 256, 0, stream>>>((const float4*)Ev0, (float4*)cv, (float4*)sum_v, NI * DD / 4);
    for (int l = 0; l < 2; ++l) {
      drop_kernel<<<(NE / 2 + 255) / 256, 256, 0, stream>>>(vsrc, dropv, k4[2 * l][0], k4[2 * l][1]);
      hipMemsetAsync(nu, 0, (size_t)NU * DD * sizeof(float), stream);
      spmm_kernel<<<2048, 256, 0, stream>>>(dropv, rows, cols, cv, nu);
      drop_kernel<<<(NE / 2 + 255) / 256, 256, 0, stream>>>(vsrc, dropv, k4[2 * l + 1][0], k4[2 * l + 1][1]);
      hipMemsetAsync(nv, 0, (size_t)NI * DD * sizeof(float), stream);
      spmm_kernel<<<2048, 256, 0, stream>>>(dropv, cols, rows, cu, nv);
      add_kernel<<<4096, 256, 0, stream>>>((float4*)sum_u, (const float4*)nu, NU * DD / 4);
      add_kernel<<<2048, 256, 0, stream>>>((float4*)sum_v, (const float4*)nv, NI * DD / 4);
      float* t = cu; cu = nu; nu = t;
      t = cv; cv = nv; nv = t;
    }
  };

  propagate(av, Eu, Ev, lk[0]);
  edge_logit_kernel<<<2048, 256, 0, stream>>>(Eu, Ev, rows, cols, av, augv);
  propagate(augv, Zu, Zi, lk[1]);

  hipMemsetAsync(acc, 0, 16 * sizeof(float), stream);
  hipMemsetAsync(Su, 0, BATCH * sizeof(float), stream);
  hipMemsetAsync(Si, 0, BATCH * sizeof(float), stream);

  bpr_kernel<<<BATCH / 4, 256, 0, stream>>>(Eu, Ev, uids, pos, neg, ps, acc);
  minmax_kernel<<<1, 256, 0, stream>>>(ps, mm);
  bcl_kernel<<<BATCH / 4, 256, 0, stream>>>(Eu, Ev, Eb, uids, pos, ps, mm, acc);

  dim3 gu((NU + 63) / 64, BATCH / 64);
  pcl_gemm_kernel<<<gu, 256, 0, stream>>>(Zu, Eu, uids, NU, Su);
  dim3 gi((NI + 63) / 64, BATCH / 64);
  pcl_gemm_kernel<<<gi, 256, 0, stream>>>(Zi, Ev, iids, NI, Si);
  pclpos_kernel<<<BATCH / 4, 256, 0, stream>>>(Zu, Eu, uids, acc, 3);
  pclpos_kernel<<<BATCH / 4, 256, 0, stream>>>(Zi, Ev, iids, acc, 4);

  sumsq_kernel<<<1024, 256, 0, stream>>>(Eu0, NU * DD, acc, 7);
  sumsq_kernel<<<512, 256, 0, stream>>>(Ev0, NI * DD, acc, 8);
  sumsq_kernel<<<4, 256, 0, stream>>>(Eb, NBK * DD, acc, 9);

  finalize_kernel<<<1, 256, 0, stream>>>(Su, Si, acc, out);
}

// Round 2
// 2126.092 us; speedup vs baseline: 2.5948x; 2.5948x over previous
//
#include <hip/hip_runtime.h>
#include <stdint.h>

#define NU 100000
#define NI 50000
#define NBK 10
#define DD 64
#define NE 1000000
#define BATCH 2048
#define LDB 72   // bf16 elems per LDS row: 64 + 8 pad (144B stride -> conflict-free b128)

typedef __bf16 bf16x8 __attribute__((ext_vector_type(8)));
typedef float f32x4 __attribute__((ext_vector_type(4)));

// ---------------- threefry2x32 (JAX-compatible, 20 rounds) ----------------
__host__ __device__ inline void tf2x32(uint32_t k0, uint32_t k1, uint32_t x0, uint32_t x1,
                                       uint32_t& o0, uint32_t& o1) {
  uint32_t ks0 = k0, ks1 = k1, ks2 = k0 ^ k1 ^ 0x1BD11BDAu;
  x0 += ks0; x1 += ks1;
#define TFR(r) { x0 += x1; x1 = (x1 << (r)) | (x1 >> (32 - (r))); x1 ^= x0; }
  TFR(13) TFR(15) TFR(26) TFR(6)   x0 += ks1; x1 += ks2 + 1u;
  TFR(17) TFR(29) TFR(16) TFR(24)  x0 += ks2; x1 += ks0 + 2u;
  TFR(13) TFR(15) TFR(26) TFR(6)   x0 += ks0; x1 += ks1 + 3u;
  TFR(17) TFR(29) TFR(16) TFR(24)  x0 += ks1; x1 += ks2 + 4u;
  TFR(13) TFR(15) TFR(26) TFR(6)   x0 += ks2; x1 += ks0 + 5u;
#undef TFR
  o0 = x0; o1 = x1;
}

__device__ inline uint16_t f2bf(float f) {
  uint32_t u = __float_as_uint(f);
  return (uint16_t)((u + 0x7fffu + ((u >> 16) & 1u)) >> 16);   // RNE
}

__global__ void drop_kernel(const float* __restrict__ vals, float* __restrict__ out,
                            uint32_t k0, uint32_t k1) {
  int i = blockIdx.x * blockDim.x + threadIdx.x;
  const int half = NE / 2;
  if (i >= half) return;
  uint32_t o0, o1;
  tf2x32(k0, k1, (uint32_t)i, (uint32_t)(i + half), o0, o1);
  float u0 = __uint_as_float((o0 >> 9) | 0x3f800000u) - 1.0f;
  float u1 = __uint_as_float((o1 >> 9) | 0x3f800000u) - 1.0f;
  out[i]        = (u0 < 0.75f) ? vals[i] / 0.75f : 0.0f;
  out[i + half] = (u1 < 0.75f) ? vals[i + half] / 0.75f : 0.0f;
}

__global__ void init2_kernel(const float4* __restrict__ s, float4* __restrict__ a,
                             float4* __restrict__ b, int n) {
  for (int i = blockIdx.x * blockDim.x + threadIdx.x; i < n; i += gridDim.x * blockDim.x) {
    float4 v = s[i]; a[i] = v; b[i] = v;
  }
}

__global__ void add_kernel(float4* __restrict__ a, const float4* __restrict__ b, int n) {
  for (int i = blockIdx.x * blockDim.x + threadIdx.x; i < n; i += gridDim.x * blockDim.x) {
    float4 x = a[i], y = b[i];
    x.x += y.x; x.y += y.y; x.z += y.z; x.w += y.w;
    a[i] = x;
  }
}

// one wave per edge: lane = dim; coalesced gather of src row, atomic scatter to dst row
__global__ void spmm_kernel(const float* __restrict__ v, const int* __restrict__ dst,
                            const int* __restrict__ src, const float* __restrict__ S,
                            float* __restrict__ Dacc) {
  int lane = threadIdx.x & 63;
  int w = (blockIdx.x * blockDim.x + threadIdx.x) >> 6;
  int nw = (gridDim.x * blockDim.x) >> 6;
  for (int e = w; e < NE; e += nw) {
    float val = v[e];
    if (val != 0.0f) {
      int di = dst[e], si = src[e];
      atomicAdd(&Dacc[(size_t)di * DD + lane], val * S[(size_t)si * DD + lane]);
    }
  }
}

__global__ void edge_logit_kernel(const float* __restrict__ Eu, const float* __restrict__ Ev,
                                  const int* __restrict__ rows, const int* __restrict__ cols,
                                  const float* __restrict__ av, float* __restrict__ aug) {
  int lane = threadIdx.x & 63;
  int w = (blockIdx.x * blockDim.x + threadIdx.x) >> 6;
  int nw = (gridDim.x * blockDim.x) >> 6;
  for (int e = w; e < NE; e += nw) {
    float p = Eu[(size_t)rows[e] * DD + lane] * Ev[(size_t)cols[e] * DD + lane];
#pragma unroll
    for (int off = 32; off > 0; off >>= 1) p += __shfl_down(p, off);
    if (lane == 0) aug[e] = av[e] / (1.0f + __expf(-p));
  }
}

// fp32 -> bf16 bulk convert (4 elems/thread)
__global__ void cvt_bf16_kernel(const float4* __restrict__ x, uint2* __restrict__ y, int n4) {
  int i = blockIdx.x * blockDim.x + threadIdx.x;
  if (i >= n4) return;
  float4 v = x[i];
  uint2 o;
  o.x = (uint32_t)f2bf(v.x) | ((uint32_t)f2bf(v.y) << 16);
  o.y = (uint32_t)f2bf(v.z) | ((uint32_t)f2bf(v.w) << 16);
  y[i] = o;
}

// gather rows Z[ids[b]] -> bf16 [BATCH][64]
__global__ void gather_bf16_kernel(const float* __restrict__ Z, const int* __restrict__ ids,
                                   uint16_t* __restrict__ out) {
  int b = blockIdx.x, lane = threadIdx.x;
  out[(size_t)b * 64 + lane] = f2bf(Z[(size_t)ids[b] * 64 + lane]);
}

// S[m] += sum_n exp(5 * dot(Zg[m], E[n])) via bf16 MFMA 16x16x32.
// Block: 4 waves; wave w owns m-rows [mb*64 + w*16, +16), A frags live in regs
// across the whole n loop. B tile (64 n-rows x K=64) staged in LDS (stride 72).
__global__ __launch_bounds__(256)
void pcl_mfma_kernel(const uint16_t* __restrict__ Zg, const uint16_t* __restrict__ E16,
                     int nJ, int nTiles, float* __restrict__ S) {
  __shared__ uint16_t Bt[64 * LDB];
  int tid = threadIdx.x;
  int wave = tid >> 6, lane = tid & 63;
  int quad = lane >> 4, l15 = lane & 15;
  int mb = blockIdx.y;
  const uint16_t* arow = Zg + (size_t)(mb * 64 + wave * 16 + l15) * 64 + quad * 8;
  bf16x8 a0 = *(const bf16x8*)(arow);        // k = quad*8 + 0..7
  bf16x8 a1 = *(const bf16x8*)(arow + 32);   // k = 32 + quad*8 + 0..7
  f32x4 rowsum = {0.f, 0.f, 0.f, 0.f};
  int sr = tid >> 2, sc = (tid & 3) * 16;    // staging: 32B per thread
  for (int nb = blockIdx.x; nb < nTiles; nb += gridDim.x) {
    __syncthreads();                         // previous iter's LDS reads done
    {
      int gn = nb * 64 + sr;
      uint4 v0 = make_uint4(0, 0, 0, 0), v1 = v0;
      if (gn < nJ) {
        const uint4* srcp = (const uint4*)(E16 + (size_t)gn * 64 + sc);
        v0 = srcp[0]; v1 = srcp[1];
      }
      uint16_t* dstp = Bt + sr * LDB + sc;
      *(uint4*)(dstp) = v0;
      *(uint4*)(dstp + 8) = v1;
    }
    __syncthreads();
#pragma unroll
    for (int t = 0; t < 4; ++t) {
      const uint16_t* brow = Bt + (t * 16 + l15) * LDB + quad * 8;
      bf16x8 b0 = *(const bf16x8*)(brow);
      bf16x8 b1 = *(const bf16x8*)(brow + 32);
      f32x4 c4 = {0.f, 0.f, 0.f, 0.f};
      c4 = __builtin_amdgcn_mfma_f32_16x16x32_bf16(a0, b0, c4, 0, 0, 0);
      c4 = __builtin_amdgcn_mfma_f32_16x16x32_bf16(a1, b1, c4, 0, 0, 0);
      int n = nb * 64 + t * 16 + l15;        // C/D: col = l15, row = quad*4+reg
      if (n < nJ) {
#pragma unroll
        for (int r = 0; r < 4; ++r) rowsum[r] += __expf(c4[r] * 5.0f);
      }
    }
  }
#pragma unroll
  for (int off = 8; off > 0; off >>= 1) {
#pragma unroll
    for (int r = 0; r < 4; ++r) rowsum[r] += __shfl_down(rowsum[r], off, 16);
  }
  if (l15 == 0) {
#pragma unroll
    for (int r = 0; r < 4; ++r)
      atomicAdd(&S[mb * 64 + wave * 16 + quad * 4 + r], rowsum[r]);
  }
}

__global__ void bpr_kernel(const float* __restrict__ Eu, const float* __restrict__ Ev,
                           const int* __restrict__ uids, const int* __restrict__ pos,
                           const int* __restrict__ neg, float* __restrict__ ps,
                           float* __restrict__ acc) {
  int lane = threadIdx.x & 63;
  int b = (blockIdx.x * blockDim.x + threadIdx.x) >> 6;
  if (b >= BATCH) return;
  float u = Eu[(size_t)uids[b] * DD + lane];
  float p = u * Ev[(size_t)pos[b] * DD + lane];
  float n = u * Ev[(size_t)neg[b] * DD + lane];
#pragma unroll
  for (int off = 32; off > 0; off >>= 1) { p += __shfl_down(p, off); n += __shfl_down(n, off); }
  if (lane == 0) {
    ps[b] = p;
    float x = p - n;
    atomicAdd(&acc[0], logf(1.0f / (1.0f + __expf(-x))));
  }
}

__global__ void minmax_kernel(const float* __restrict__ ps, float* __restrict__ mm) {
  __shared__ float smn[256], smx[256];
  int tid = threadIdx.x;
  float mn = 3.0e38f, mx = -3.0e38f;
  for (int i = tid; i < BATCH; i += 256) { float v = ps[i]; mn = fminf(mn, v); mx = fmaxf(mx, v); }
  smn[tid] = mn; smx[tid] = mx;
  __syncthreads();
  for (int s = 128; s > 0; s >>= 1) {
    if (tid < s) { smn[tid] = fminf(smn[tid], smn[tid + s]); smx[tid] = fmaxf(smx[tid], smx[tid + s]); }
    __syncthreads();
  }
  if (tid == 0) { mm[0] = smn[0]; mm[1] = smx[0]; }
}

__global__ void bcl_kernel(const float* __restrict__ Eu, const float* __restrict__ Ev,
                           const float* __restrict__ Eb, const int* __restrict__ uids,
                           const int* __restrict__ pos, const float* __restrict__ ps,
                           const float* __restrict__ mm, float* __restrict__ acc) {
  int lane = threadIdx.x & 63;
  int b = (blockIdx.x * blockDim.x + threadIdx.x) >> 6;
  if (b >= BATCH) return;
  float wgt = (ps[b] - mm[0]) / (mm[1] - mm[0] + 1e-9f);
  int rel = (int)(wgt * 10.0f);
  rel = rel < 0 ? 0 : (rel > 9 ? 9 : rel);
  float el = 1.0f / (1.0f + __expf(-(Eu[(size_t)uids[b] * DD + lane] * Ev[(size_t)pos[b] * DD + lane])));
  float sneg = 0.f, spos = 0.f;
  for (int k = 0; k < NBK; ++k) {
    float d = el * Eb[k * DD + lane];
#pragma unroll
    for (int off = 32; off > 0; off >>= 1) d += __shfl_down(d, off);
    if (lane == 0) { if (k == rel) spos = d; else sneg += d; }
  }
  if (lane == 0) {
    atomicAdd(&acc[5], sneg * 0.1f);
    atomicAdd(&acc[6], spos);
  }
}

__global__ void pclpos_kernel(const float* __restrict__ Zc, const float* __restrict__ Ec,
                              const int* __restrict__ ids, float* __restrict__ acc, int idx) {
  int lane = threadIdx.x & 63;
  int b = (blockIdx.x * blockDim.x + threadIdx.x) >> 6;
  if (b >= BATCH) return;
  size_t r = (size_t)ids[b] * DD + lane;
  float p = Zc[r] * Ec[r];
#pragma unroll
  for (int off = 32; off > 0; off >>= 1) p += __shfl_down(p, off);
  if (lane == 0) {
    float x = p * 5.0f;
    x = fminf(5.0f, fmaxf(-5.0f, x));
    atomicAdd(&acc[idx], x);
  }
}

__global__ void sumsq_kernel(const float* __restrict__ x, int n, float* __restrict__ acc, int idx) {
  __shared__ float red[256];
  int tid = threadIdx.x;
  float s = 0.f;
  for (int i = blockIdx.x * blockDim.x + tid; i < n; i += gridDim.x * blockDim.x) {
    float v = x[i]; s += v * v;
  }
  red[tid] = s;
  __syncthreads();
  for (int st = 128; st > 0; st >>= 1) {
    if (tid < st) red[tid] += red[tid + st];
    __syncthreads();
  }
  if (tid == 0) atomicAdd(&acc[idx], red[0]);
}

__global__ void finalize_kernel(const float* __restrict__ Su, const float* __restrict__ Si,
                                const float* __restrict__ acc, float* __restrict__ out) {
  __shared__ float r1[256], r2[256];
  int tid = threadIdx.x;
  float su = 0.f, si = 0.f;
  for (int b = tid; b < BATCH; b += 256) {
    su += logf(Su[b] + 1e-8f);
    si += logf(Si[b] + 1e-8f);
  }
  r1[tid] = su; r2[tid] = si;
  __syncthreads();
  for (int s = 128; s > 0; s >>= 1) {
    if (tid < s) { r1[tid] += r1[tid + s]; r2[tid] += r2[tid + s]; }
    __syncthreads();
  }
  if (tid == 0) {
    const float inv = 1.0f / (float)BATCH;
    float neg_s = (r1[0] + r2[0]) * inv;
    float pos_s = (acc[3] + acc[4]) * inv;
    float pcl = neg_s - pos_s;
    float bpr = -acc[0] * inv;
    float bcl = (acc[5] - acc[6]) * inv;
    float reg = 1e-7f * (acc[7] + acc[8] + acc[9]);
    float loss = bpr + 0.2f * pcl + 0.2f * bcl + reg;
    out[0] = loss; out[1] = bpr; out[2] = 0.2f * pcl; out[3] = 0.2f * bcl;
  }
}

extern "C" void kernel_launch(void* const* d_in, const int* in_sizes, int n_in,
                              void* d_out, int out_size, void* d_ws, size_t ws_size,
                              hipStream_t stream) {
  (void)in_sizes; (void)n_in; (void)out_size; (void)ws_size;
  const float* Eu0 = (const float*)d_in[0];
  const float* Ev0 = (const float*)d_in[1];
  const float* Eb  = (const float*)d_in[2];
  const float* av  = (const float*)d_in[3];
  const int* rows  = (const int*)d_in[4];
  const int* cols  = (const int*)d_in[5];
  const int* uids  = (const int*)d_in[6];
  const int* iids  = (const int*)d_in[7];
  const int* pos   = (const int*)d_in[8];
  const int* neg   = (const int*)d_in[9];
  float* out = (float*)d_out;

  float* w = (float*)d_ws;
  size_t o = 0;
  float* bu0 = w + o; o += (size_t)NU * DD;
  float* bu1 = w + o; o += (size_t)NU * DD;
  float* Eu  = w + o; o += (size_t)NU * DD;   // E_u (prop-0 sums)
  float* Zu  = w + o; o += (size_t)NU * DD;   // Z_u (prop-1 sums)
  float* bv0 = w + o; o += (size_t)NI * DD;
  float* bv1 = w + o; o += (size_t)NI * DD;
  float* Ev  = w + o; o += (size_t)NI * DD;
  float* Zi  = w + o; o += (size_t)NI * DD;
  float* dropv = w + o; o += NE;
  float* augv  = w + o; o += NE;
  float* ps  = w + o; o += BATCH;
  float* Su  = w + o; o += BATCH;
  float* Si  = w + o; o += BATCH;
  float* acc = w + o; o += 16;
  float* mm  = w + o; o += 2;

  // bf16 buffers overlay the ping-pong buffers (dead after both propagations):
  // bu0 (25.6MB) hosts E16u (12.8MB); bv0 (12.8MB) hosts E16i (6.4MB);
  // bu1 hosts the two gathered Z matrices (256KB).
  uint16_t* E16u = (uint16_t*)bu0;
  uint16_t* E16i = (uint16_t*)bv0;
  uint16_t* Zgu  = (uint16_t*)bu1;
  uint16_t* Zgi  = Zgu + (size_t)BATCH * DD;

  // key chain: key(42) = (0,42); fold_in(k,d) = threefry2x32(k, [0,d])
  uint32_t bk[2][2], lk[2][4][2];
  tf2x32(0u, 42u, 0u, 0u, bk[0][0], bk[0][1]);
  tf2x32(0u, 42u, 0u, 1u, bk[1][0], bk[1][1]);
  for (int p = 0; p < 2; ++p)
    for (int t = 0; t < 4; ++t)
      tf2x32(bk[p][0], bk[p][1], 0u, (uint32_t)t, lk[p][t][0], lk[p][t][1]);

  auto propagate = [&](const float* vsrc, float* sum_u, float* sum_v, uint32_t (*k4)[2]) {
    float* cu = bu0; float* nu = bu1; float* cv = bv0; float* nv = bv1;
    init2_kernel<<<4096, 256, 0, stream>>>((const float4*)Eu0, (float4*)cu, (float4*)sum_u, NU * DD / 4);
    init2_kernel<<<2048, 256, 0, stream>>>((const float4*)Ev0, (float4*)cv, (float4*)sum_v, NI * DD / 4);
    for (int l = 0; l < 2; ++l) {
      drop_kernel<<<(NE / 2 + 255) / 256, 256, 0, stream>>>(vsrc, dropv, k4[2 * l][0], k4[2 * l][1]);
      hipMemsetAsync(nu, 0, (size_t)NU * DD * sizeof(float), stream);
      spmm_kernel<<<2048, 256, 0, stream>>>(dropv, rows, cols, cv, nu);
      drop_kernel<<<(NE / 2 + 255) / 256, 256, 0, stream>>>(vsrc, dropv, k4[2 * l + 1][0], k4[2 * l + 1][1]);
      hipMemsetAsync(nv, 0, (size_t)NI * DD * sizeof(float), stream);
      spmm_kernel<<<2048, 256, 0, stream>>>(dropv, cols, rows, cu, nv);
      add_kernel<<<4096, 256, 0, stream>>>((float4*)sum_u, (const float4*)nu, NU * DD / 4);
      add_kernel<<<2048, 256, 0, stream>>>((float4*)sum_v, (const float4*)nv, NI * DD / 4);
      float* t = cu; cu = nu; nu = t;
      t = cv; cv = nv; nv = t;
    }
  };

  propagate(av, Eu, Ev, lk[0]);
  edge_logit_kernel<<<2048, 256, 0, stream>>>(Eu, Ev, rows, cols, av, augv);
  propagate(augv, Zu, Zi, lk[1]);

  // bf16 conversions for the MFMA PCL kernels
  cvt_bf16_kernel<<<(NU * DD / 4 + 255) / 256, 256, 0, stream>>>((const float4*)Eu, (uint2*)E16u, NU * DD / 4);
  cvt_bf16_kernel<<<(NI * DD / 4 + 255) / 256, 256, 0, stream>>>((const float4*)Ev, (uint2*)E16i, NI * DD / 4);
  gather_bf16_kernel<<<BATCH, 64, 0, stream>>>(Zu, uids, Zgu);
  gather_bf16_kernel<<<BATCH, 64, 0, stream>>>(Zi, iids, Zgi);

  hipMemsetAsync(acc, 0, 16 * sizeof(float), stream);
  hipMemsetAsync(Su, 0, BATCH * sizeof(float), stream);
  hipMemsetAsync(Si, 0, BATCH * sizeof(float), stream);

  bpr_kernel<<<BATCH / 4, 256, 0, stream>>>(Eu, Ev, uids, pos, neg, ps, acc);
  minmax_kernel<<<1, 256, 0, stream>>>(ps, mm);
  bcl_kernel<<<BATCH / 4, 256, 0, stream>>>(Eu, Ev, Eb, uids, pos, ps, mm, acc);

  dim3 gu(64, 32);   // 2048 blocks; each strides over ceil(100000/64)=1563 n-tiles
  pcl_mfma_kernel<<<gu, 256, 0, stream>>>(Zgu, E16u, NU, (NU + 63) / 64, Su);
  dim3 gi(32, 32);   // 1024 blocks; 782 n-tiles
  pcl_mfma_kernel<<<gi, 256, 0, stream>>>(Zgi, E16i, NI, (NI + 63) / 64, Si);

  pclpos_kernel<<<BATCH / 4, 256, 0, stream>>>(Zu, Eu, uids, acc, 3);
  pclpos_kernel<<<BATCH / 4, 256, 0, stream>>>(Zi, Ev, iids, acc, 4);

  sumsq_kernel<<<1024, 256, 0, stream>>>(Eu0, NU * DD, acc, 7);
  sumsq_kernel<<<512, 256, 0, stream>>>(Ev0, NI * DD, acc, 8);
  sumsq_kernel<<<4, 256, 0, stream>>>(Eb, NBK * DD, acc, 9);

  finalize_kernel<<<1, 256, 0, stream>>>(Su, Si, acc, out);
}

// Round 3
// 1881.208 us; speedup vs baseline: 2.9326x; 1.1302x over previous
//
#include <hip/hip_runtime.h>
#include <stdint.h>

#define NU 100000
#define NI 50000
#define NBK 10
#define DD 64
#define NE 1000000
#define BATCH 2048

typedef __bf16 bf16x8 __attribute__((ext_vector_type(8)));
typedef float f32x4 __attribute__((ext_vector_type(4)));

// ---------------- threefry2x32 (JAX-compatible, 20 rounds) ----------------
__host__ __device__ inline void tf2x32(uint32_t k0, uint32_t k1, uint32_t x0, uint32_t x1,
                                       uint32_t& o0, uint32_t& o1) {
  uint32_t ks0 = k0, ks1 = k1, ks2 = k0 ^ k1 ^ 0x1BD11BDAu;
  x0 += ks0; x1 += ks1;
#define TFR(r) { x0 += x1; x1 = (x1 << (r)) | (x1 >> (32 - (r))); x1 ^= x0; }
  TFR(13) TFR(15) TFR(26) TFR(6)   x0 += ks1; x1 += ks2 + 1u;
  TFR(17) TFR(29) TFR(16) TFR(24)  x0 += ks2; x1 += ks0 + 2u;
  TFR(13) TFR(15) TFR(26) TFR(6)   x0 += ks0; x1 += ks1 + 3u;
  TFR(17) TFR(29) TFR(16) TFR(24)  x0 += ks1; x1 += ks2 + 4u;
  TFR(13) TFR(15) TFR(26) TFR(6)   x0 += ks2; x1 += ks0 + 5u;
#undef TFR
  o0 = x0; o1 = x1;
}

__device__ inline uint16_t f2bf(float f) {
  uint32_t u = __float_as_uint(f);
  return (uint16_t)((u + 0x7fffu + ((u >> 16) & 1u)) >> 16);   // RNE
}

// ---------------- CSR build ----------------
__global__ void hist_kernel(const int* __restrict__ rows, const int* __restrict__ cols,
                            int* __restrict__ cntU, int* __restrict__ cntI) {
  int e = blockIdx.x * blockDim.x + threadIdx.x;
  if (e >= NE) return;
  atomicAdd(&cntU[rows[e]], 1);
  atomicAdd(&cntI[cols[e]], 1);
}

#define SCAN_B 256
__global__ void scan_phase1(const int* __restrict__ cnt, int n, int* __restrict__ bs) {
  __shared__ int red[SCAN_B];
  int t = threadIdx.x, i = blockIdx.x * SCAN_B + t;
  red[t] = (i < n) ? cnt[i] : 0;
  __syncthreads();
  for (int s = 128; s > 0; s >>= 1) {
    if (t < s) red[t] += red[t + s];
    __syncthreads();
  }
  if (t == 0) bs[blockIdx.x] = red[0];
}
__global__ void scan_phase2(int* __restrict__ bs, int nb) {  // 1 block, 1024 thr, nb<=1024
  __shared__ int sh[1024];
  int t = threadIdx.x;
  int v = (t < nb) ? bs[t] : 0;
  sh[t] = v;
  __syncthreads();
  for (int off = 1; off < 1024; off <<= 1) {
    int add = (t >= off) ? sh[t - off] : 0;
    __syncthreads();
    sh[t] += add;
    __syncthreads();
  }
  if (t < nb) bs[t] = sh[t] - v;   // exclusive
}
__global__ void scan_phase3(const int* __restrict__ cnt, int n, const int* __restrict__ bs,
                            int* __restrict__ off) {
  __shared__ int sh[SCAN_B];
  int t = threadIdx.x, i = blockIdx.x * SCAN_B + t;
  int v = (i < n) ? cnt[i] : 0;
  sh[t] = v;
  __syncthreads();
  for (int o = 1; o < SCAN_B; o <<= 1) {
    int add = (t >= o) ? sh[t - o] : 0;
    __syncthreads();
    sh[t] += add;
    __syncthreads();
  }
  if (i < n) off[i] = bs[blockIdx.x] + sh[t] - v;
  if (i == n - 1) off[n] = bs[blockIdx.x] + sh[t];
}

__global__ void scatter_kernel(const int* __restrict__ rows, const int* __restrict__ cols,
                               const int* __restrict__ offU, const int* __restrict__ offI,
                               int* __restrict__ fillU, int* __restrict__ fillI,
                               int* __restrict__ colU, int* __restrict__ peU,
                               int* __restrict__ colI, int* __restrict__ peI) {
  int e = blockIdx.x * blockDim.x + threadIdx.x;
  if (e >= NE) return;
  int r = rows[e], c = cols[e];
  int pu = offU[r] + atomicAdd(&fillU[r], 1);
  colU[pu] = c; peU[pu] = e;
  int pi = offI[c] + atomicAdd(&fillI[c], 1);
  colI[pi] = r; peI[pi] = e;
}

// dropout fused with CSR permutation: valP[p] = drop(src[pe[p]])
__global__ void drop_perm_kernel(const float* __restrict__ src, const int* __restrict__ pe,
                                 float* __restrict__ valP, uint32_t k0, uint32_t k1) {
  int p = blockIdx.x * blockDim.x + threadIdx.x;
  if (p >= NE) return;
  int e = pe[p];
  const uint32_t half = NE / 2;
  uint32_t lo = (e < (int)half) ? (uint32_t)e : (uint32_t)e - half;
  uint32_t o0, o1;
  tf2x32(k0, k1, lo, lo + half, o0, o1);
  uint32_t bits = (e < (int)half) ? o0 : o1;
  float u = __uint_as_float((bits >> 9) | 0x3f800000u) - 1.0f;
  valP[p] = (u < 0.75f) ? src[e] / 0.75f : 0.0f;
}

// gather-reduce SpMM: one wave per output row, lane = dim. No atomics.
// Sum[idx] = (base ? base[idx] : Sum[idx]) + acc  (fused layer-sum update)
__global__ __launch_bounds__(256)
void spmm_csr_kernel(const int* __restrict__ off, const int* __restrict__ col,
                     const float* __restrict__ valP, const float* __restrict__ S,
                     float* __restrict__ Dout, float* __restrict__ Sum,
                     const float* __restrict__ base, int nR) {
  int lane = threadIdx.x & 63;
  int r = (blockIdx.x * blockDim.x + threadIdx.x) >> 6;
  if (r >= nR) return;
  int p0 = off[r], p1 = off[r + 1];
  float acc = 0.f;
  for (int p = p0; p < p1; ++p) {
    float v = valP[p];
    if (v != 0.f) {
      int s = col[p];
      acc += v * S[(size_t)s * DD + lane];
    }
  }
  size_t idx = (size_t)r * DD + lane;
  Dout[idx] = acc;
  Sum[idx] = (base ? base[idx] : Sum[idx]) + acc;
}

// 4 edges per wave (16 lanes each, float4 over dims)
__global__ void edge_logit_kernel(const float* __restrict__ Eu, const float* __restrict__ Ev,
                                  const int* __restrict__ rows, const int* __restrict__ cols,
                                  const float* __restrict__ av, float* __restrict__ aug) {
  int lane = threadIdx.x & 63;
  int sub = lane >> 4, l15 = lane & 15;
  int w = (blockIdx.x * blockDim.x + threadIdx.x) >> 6;
  int nw = (gridDim.x * blockDim.x) >> 6;
  for (int b = w * 4; b < NE; b += nw * 4) {
    int e = b + sub;
    float4 a = *(const float4*)&Eu[(size_t)rows[e] * DD + l15 * 4];
    float4 c = *(const float4*)&Ev[(size_t)cols[e] * DD + l15 * 4];
    float p = a.x * c.x + a.y * c.y + a.z * c.z + a.w * c.w;
#pragma unroll
    for (int off = 8; off > 0; off >>= 1) p += __shfl_down(p, off, 16);
    if (l15 == 0) aug[e] = av[e] / (1.0f + __expf(-p));
  }
}

// fp32 -> bf16 bulk convert (4 elems/thread)
__global__ void cvt_bf16_kernel(const float4* __restrict__ x, uint2* __restrict__ y, int n4) {
  int i = blockIdx.x * blockDim.x + threadIdx.x;
  if (i >= n4) return;
  float4 v = x[i];
  uint2 o;
  o.x = (uint32_t)f2bf(v.x) | ((uint32_t)f2bf(v.y) << 16);
  o.y = (uint32_t)f2bf(v.z) | ((uint32_t)f2bf(v.w) << 16);
  y[i] = o;
}

// gather rows Z[ids[b]] -> bf16 [BATCH][64]
__global__ void gather_bf16_kernel(const float* __restrict__ Z, const int* __restrict__ ids,
                                   uint16_t* __restrict__ out) {
  int b = blockIdx.x, lane = threadIdx.x;
  out[(size_t)b * 64 + lane] = f2bf(Z[(size_t)ids[b] * 64 + lane]);
}

// PCL denominator: S[m] += sum_n exp(5*dot(Zg[m],E[n])), bf16 MFMA 16x16x32.
// No LDS, no barriers: wave pins A-frags (16 m-rows) in regs, streams B-frags
// from global (L1/L2-resident) with one-deep prefetch. blockIdx.y*4+wave = m-tile,
// blockIdx.x = n-split. NT, BATCH are exact multiples of 16 -> no guards.
__global__ __launch_bounds__(256)
void pcl_mfma2_kernel(const uint16_t* __restrict__ Zg, const uint16_t* __restrict__ E16,
                      int NT, int SPL, float* __restrict__ S) {
  int lane = threadIdx.x & 63;
  int wave = threadIdx.x >> 6;
  int quad = lane >> 4, l15 = lane & 15;
  int mt = blockIdx.y * 4 + wave;
  const uint16_t* ar = Zg + (size_t)(mt * 16 + l15) * 64 + quad * 8;
  bf16x8 a0 = *(const bf16x8*)ar;
  bf16x8 a1 = *(const bf16x8*)(ar + 32);
  f32x4 rowsum = {0.f, 0.f, 0.f, 0.f};
  int nt = blockIdx.x;
  bf16x8 b0 = {}, b1 = {};
  if (nt < NT) {
    const uint16_t* br = E16 + (size_t)(nt * 16 + l15) * 64 + quad * 8;
    b0 = *(const bf16x8*)br;
    b1 = *(const bf16x8*)(br + 32);
  }
  while (nt < NT) {
    int nn = nt + SPL;
    bf16x8 p0 = {}, p1 = {};
    if (nn < NT) {                       // prefetch next tile while MFMA+exp run
      const uint16_t* br = E16 + (size_t)(nn * 16 + l15) * 64 + quad * 8;
      p0 = *(const bf16x8*)br;
      p1 = *(const bf16x8*)(br + 32);
    }
    f32x4 c = {0.f, 0.f, 0.f, 0.f};
    c = __builtin_amdgcn_mfma_f32_16x16x32_bf16(a0, b0, c, 0, 0, 0);
    c = __builtin_amdgcn_mfma_f32_16x16x32_bf16(a1, b1, c, 0, 0, 0);
#pragma unroll
    for (int r = 0; r < 4; ++r) rowsum[r] += __expf(c[r] * 5.0f);
    b0 = p0; b1 = p1; nt = nn;
  }
#pragma unroll
  for (int off = 8; off > 0; off >>= 1) {
#pragma unroll
    for (int r = 0; r < 4; ++r) rowsum[r] += __shfl_down(rowsum[r], off, 16);
  }
  if (l15 == 0) {
#pragma unroll
    for (int r = 0; r < 4; ++r)
      atomicAdd(&S[mt * 16 + quad * 4 + r], rowsum[r]);
  }
}

__global__ void bpr_kernel(const float* __restrict__ Eu, const float* __restrict__ Ev,
                           const int* __restrict__ uids, const int* __restrict__ pos,
                           const int* __restrict__ neg, float* __restrict__ ps,
                           float* __restrict__ acc) {
  int lane = threadIdx.x & 63;
  int b = (blockIdx.x * blockDim.x + threadIdx.x) >> 6;
  if (b >= BATCH) return;
  float u = Eu[(size_t)uids[b] * DD + lane];
  float p = u * Ev[(size_t)pos[b] * DD + lane];
  float n = u * Ev[(size_t)neg[b] * DD + lane];
#pragma unroll
  for (int off = 32; off > 0; off >>= 1) { p += __shfl_down(p, off); n += __shfl_down(n, off); }
  if (lane == 0) {
    ps[b] = p;
    float x = p - n;
    atomicAdd(&acc[0], logf(1.0f / (1.0f + __expf(-x))));
  }
}

__global__ void minmax_kernel(const float* __restrict__ ps, float* __restrict__ mm) {
  __shared__ float smn[256], smx[256];
  int tid = threadIdx.x;
  float mn = 3.0e38f, mx = -3.0e38f;
  for (int i = tid; i < BATCH; i += 256) { float v = ps[i]; mn = fminf(mn, v); mx = fmaxf(mx, v); }
  smn[tid] = mn; smx[tid] = mx;
  __syncthreads();
  for (int s = 128; s > 0; s >>= 1) {
    if (tid < s) { smn[tid] = fminf(smn[tid], smn[tid + s]); smx[tid] = fmaxf(smx[tid], smx[tid + s]); }
    __syncthreads();
  }
  if (tid == 0) { mm[0] = smn[0]; mm[1] = smx[0]; }
}

__global__ void bcl_kernel(const float* __restrict__ Eu, const float* __restrict__ Ev,
                           const float* __restrict__ Eb, const int* __restrict__ uids,
                           const int* __restrict__ pos, const float* __restrict__ ps,
                           const float* __restrict__ mm, float* __restrict__ acc) {
  int lane = threadIdx.x & 63;
  int b = (blockIdx.x * blockDim.x + threadIdx.x) >> 6;
  if (b >= BATCH) return;
  float wgt = (ps[b] - mm[0]) / (mm[1] - mm[0] + 1e-9f);
  int rel = (int)(wgt * 10.0f);
  rel = rel < 0 ? 0 : (rel > 9 ? 9 : rel);
  float el = 1.0f / (1.0f + __expf(-(Eu[(size_t)uids[b] * DD + lane] * Ev[(size_t)pos[b] * DD + lane])));
  float sneg = 0.f, spos = 0.f;
  for (int k = 0; k < NBK; ++k) {
    float d = el * Eb[k * DD + lane];
#pragma unroll
    for (int off = 32; off > 0; off >>= 1) d += __shfl_down(d, off);
    if (lane == 0) { if (k == rel) spos = d; else sneg += d; }
  }
  if (lane == 0) {
    atomicAdd(&acc[5], sneg * 0.1f);
    atomicAdd(&acc[6], spos);
  }
}

__global__ void pclpos_kernel(const float* __restrict__ Zc, const float* __restrict__ Ec,
                              const int* __restrict__ ids, float* __restrict__ acc, int idx) {
  int lane = threadIdx.x & 63;
  int b = (blockIdx.x * blockDim.x + threadIdx.x) >> 6;
  if (b >= BATCH) return;
  size_t r = (size_t)ids[b] * DD + lane;
  float p = Zc[r] * Ec[r];
#pragma unroll
  for (int off = 32; off > 0; off >>= 1) p += __shfl_down(p, off);
  if (lane == 0) {
    float x = p * 5.0f;
    x = fminf(5.0f, fmaxf(-5.0f, x));
    atomicAdd(&acc[idx], x);
  }
}

__global__ void sumsq_kernel(const float* __restrict__ x, int n, float* __restrict__ acc, int idx) {
  __shared__ float red[256];
  int tid = threadIdx.x;
  float s = 0.f;
  for (int i = blockIdx.x * blockDim.x + tid; i < n; i += gridDim.x * blockDim.x) {
    float v = x[i]; s += v * v;
  }
  red[tid] = s;
  __syncthreads();
  for (int st = 128; st > 0; st >>= 1) {
    if (tid < st) red[tid] += red[tid + st];
    __syncthreads();
  }
  if (tid == 0) atomicAdd(&acc[idx], red[0]);
}

__global__ void finalize_kernel(const float* __restrict__ Su, const float* __restrict__ Si,
                                const float* __restrict__ acc, float* __restrict__ out) {
  __shared__ float r1[256], r2[256];
  int tid = threadIdx.x;
  float su = 0.f, si = 0.f;
  for (int b = tid; b < BATCH; b += 256) {
    su += logf(Su[b] + 1e-8f);
    si += logf(Si[b] + 1e-8f);
  }
  r1[tid] = su; r2[tid] = si;
  __syncthreads();
  for (int s = 128; s > 0; s >>= 1) {
    if (tid < s) { r1[tid] += r1[tid + s]; r2[tid] += r2[tid + s]; }
    __syncthreads();
  }
  if (tid == 0) {
    const float inv = 1.0f / (float)BATCH;
    float neg_s = (r1[0] + r2[0]) * inv;
    float pos_s = (acc[3] + acc[4]) * inv;
    float pcl = neg_s - pos_s;
    float bpr = -acc[0] * inv;
    float bcl = (acc[5] - acc[6]) * inv;
    float reg = 1e-7f * (acc[7] + acc[8] + acc[9]);
    float loss = bpr + 0.2f * pcl + 0.2f * bcl + reg;
    out[0] = loss; out[1] = bpr; out[2] = 0.2f * pcl; out[3] = 0.2f * bcl;
  }
}

extern "C" void kernel_launch(void* const* d_in, const int* in_sizes, int n_in,
                              void* d_out, int out_size, void* d_ws, size_t ws_size,
                              hipStream_t stream) {
  (void)in_sizes; (void)n_in; (void)out_size; (void)ws_size;
  const float* Eu0 = (const float*)d_in[0];
  const float* Ev0 = (const float*)d_in[1];
  const float* Eb  = (const float*)d_in[2];
  const float* av  = (const float*)d_in[3];
  const int* rows  = (const int*)d_in[4];
  const int* cols  = (const int*)d_in[5];
  const int* uids  = (const int*)d_in[6];
  const int* iids  = (const int*)d_in[7];
  const int* pos   = (const int*)d_in[8];
  const int* neg   = (const int*)d_in[9];
  float* out = (float*)d_out;

  float* w = (float*)d_ws;
  size_t o = 0;
  float* bu0 = w + o; o += (size_t)NU * DD;   // layer-0 u out / prop input
  float* bu1 = w + o; o += (size_t)NU * DD;   // layer-1 u out
  float* Eu  = w + o; o += (size_t)NU * DD;   // E_u (prop-0 sums)
  float* Zu  = w + o; o += (size_t)NU * DD;   // Z_u (prop-1 sums)
  float* bv0 = w + o; o += (size_t)NI * DD;
  float* bv1 = w + o; o += (size_t)NI * DD;
  float* Ev  = w + o; o += (size_t)NI * DD;
  float* Zi  = w + o; o += (size_t)NI * DD;
  float* augv  = w + o; o += NE;
  float* valPU = w + o; o += NE;
  float* valPI = w + o; o += NE;
  float* ps  = w + o; o += BATCH;
  float* Su  = w + o; o += BATCH;
  float* Si  = w + o; o += BATCH;
  float* acc = w + o; o += 16;
  float* mm  = w + o; o += 2;
  // int region
  int* ip = (int*)(w + o);
  int* offU = ip; ip += NU + 1;
  int* offI = ip; ip += NI + 1;
  int* cntU = ip; ip += NU;       // cntU/cntI adjacent: one memset covers both
  int* cntI = ip; ip += NI;
  int* colU = ip; ip += NE;
  int* peU  = ip; ip += NE;
  int* colI = ip; ip += NE;
  int* peI  = ip; ip += NE;

  // bf16 overlays on buffers dead after both propagations
  uint16_t* E16u = (uint16_t*)bu0;
  uint16_t* E16i = (uint16_t*)bv0;
  uint16_t* Zgu  = (uint16_t*)bu1;
  uint16_t* Zgi  = Zgu + (size_t)BATCH * DD;

  // key chain: key(42) = (0,42); fold_in(k,d) = threefry2x32(k, [0,d])
  uint32_t bk[2][2], lk[2][4][2];
  tf2x32(0u, 42u, 0u, 0u, bk[0][0], bk[0][1]);
  tf2x32(0u, 42u, 0u, 1u, bk[1][0], bk[1][1]);
  for (int p = 0; p < 2; ++p)
    for (int t = 0; t < 4; ++t)
      tf2x32(bk[p][0], bk[p][1], 0u, (uint32_t)t, lk[p][t][0], lk[p][t][1]);

  const int EB = (NE + 255) / 256;

  // ---- CSR build (once per call; reused by all 8 SpMMs) ----
  hipMemsetAsync(cntU, 0, (size_t)(NU + NI) * sizeof(int), stream);
  hist_kernel<<<EB, 256, 0, stream>>>(rows, cols, cntU, cntI);
  {
    int nbU = (NU + SCAN_B - 1) / SCAN_B;       // 391
    int nbI = (NI + SCAN_B - 1) / SCAN_B;       // 196
    int* bsU = peU;                              // scratch (overwritten later by scatter)
    int* bsI = peI;
    scan_phase1<<<nbU, SCAN_B, 0, stream>>>(cntU, NU, bsU);
    scan_phase2<<<1, 1024, 0, stream>>>(bsU, nbU);
    scan_phase3<<<nbU, SCAN_B, 0, stream>>>(cntU, NU, bsU, offU);
    scan_phase1<<<nbI, SCAN_B, 0, stream>>>(cntI, NI, bsI);
    scan_phase2<<<1, 1024, 0, stream>>>(bsI, nbI);
    scan_phase3<<<nbI, SCAN_B, 0, stream>>>(cntI, NI, bsI, offI);
  }
  hipMemsetAsync(cntU, 0, (size_t)(NU + NI) * sizeof(int), stream);   // reuse as fill
  scatter_kernel<<<EB, 256, 0, stream>>>(rows, cols, offU, offI, cntU, cntI,
                                         colU, peU, colI, peI);

  // ---- propagation (fused dropout-permute + gather SpMM + layer-sum) ----
  auto propagate = [&](const float* vsrc, float* sumU, float* sumV, uint32_t (*k4)[2]) {
    // layer 0: inputs are Eu0/Ev0, sums initialized from base
    drop_perm_kernel<<<EB, 256, 0, stream>>>(vsrc, peU, valPU, k4[0][0], k4[0][1]);
    spmm_csr_kernel<<<NU / 4, 256, 0, stream>>>(offU, colU, valPU, Ev0, bu0, sumU, Eu0, NU);
    drop_perm_kernel<<<EB, 256, 0, stream>>>(vsrc, peI, valPI, k4[1][0], k4[1][1]);
    spmm_csr_kernel<<<NI / 4, 256, 0, stream>>>(offI, colI, valPI, Eu0, bv0, sumV, Ev0, NI);
    // layer 1
    drop_perm_kernel<<<EB, 256, 0, stream>>>(vsrc, peU, valPU, k4[2][0], k4[2][1]);
    spmm_csr_kernel<<<NU / 4, 256, 0, stream>>>(offU, colU, valPU, bv0, bu1, sumU, nullptr, NU);
    drop_perm_kernel<<<EB, 256, 0, stream>>>(vsrc, peI, valPI, k4[3][0], k4[3][1]);
    spmm_csr_kernel<<<NI / 4, 256, 0, stream>>>(offI, colI, valPI, bu0, bv1, sumV, nullptr, NI);
  };

  propagate(av, Eu, Ev, lk[0]);
  edge_logit_kernel<<<2048, 256, 0, stream>>>(Eu, Ev, rows, cols, av, augv);
  propagate(augv, Zu, Zi, lk[1]);

  // ---- bf16 conversions for MFMA PCL ----
  cvt_bf16_kernel<<<(NU * DD / 4 + 255) / 256, 256, 0, stream>>>((const float4*)Eu, (uint2*)E16u, NU * DD / 4);
  cvt_bf16_kernel<<<(NI * DD / 4 + 255) / 256, 256, 0, stream>>>((const float4*)Ev, (uint2*)E16i, NI * DD / 4);
  gather_bf16_kernel<<<BATCH, 64, 0, stream>>>(Zu, uids, Zgu);
  gather_bf16_kernel<<<BATCH, 64, 0, stream>>>(Zi, iids, Zgi);

  hipMemsetAsync(acc, 0, 16 * sizeof(float), stream);
  hipMemsetAsync(Su, 0, BATCH * sizeof(float), stream);
  hipMemsetAsync(Si, 0, BATCH * sizeof(float), stream);

  bpr_kernel<<<BATCH / 4, 256, 0, stream>>>(Eu, Ev, uids, pos, neg, ps, acc);
  minmax_kernel<<<1, 256, 0, stream>>>(ps, mm);
  bcl_kernel<<<BATCH / 4, 256, 0, stream>>>(Eu, Ev, Eb, uids, pos, ps, mm, acc);

  // PCL denominators: 128 m-tiles x SPL n-splits, 4 waves/block
  pcl_mfma2_kernel<<<dim3(64, 32), 256, 0, stream>>>(Zgu, E16u, NU / 16, 64, Su);
  pcl_mfma2_kernel<<<dim3(32, 32), 256, 0, stream>>>(Zgi, E16i, NI / 16, 32, Si);

  pclpos_kernel<<<BATCH / 4, 256, 0, stream>>>(Zu, Eu, uids, acc, 3);
  pclpos_kernel<<<BATCH / 4, 256, 0, stream>>>(Zi, Ev, iids, acc, 4);

  sumsq_kernel<<<1024, 256, 0, stream>>>(Eu0, NU * DD, acc, 7);
  sumsq_kernel<<<512, 256, 0, stream>>>(Ev0, NI * DD, acc, 8);
  sumsq_kernel<<<4, 256, 0, stream>>>(Eb, NBK * DD, acc, 9);

  finalize_kernel<<<1, 256, 0, stream>>>(Su, Si, acc, out);
}

// Round 5
// 1217.041 us; speedup vs baseline: 4.5330x; 1.5457x over previous
//
#include <hip/hip_runtime.h>
#include <stdint.h>

#define NU 100000
#define NI 50000
#define NBK 10
#define DD 64
#define NE 1000000
#define BATCH 2048

typedef __bf16 bf16x8 __attribute__((ext_vector_type(8)));
typedef float f32x4 __attribute__((ext_vector_type(4)));

// ---------------- threefry2x32 (JAX-compatible, 20 rounds) ----------------
__host__ __device__ inline void tf2x32(uint32_t k0, uint32_t k1, uint32_t x0, uint32_t x1,
                                       uint32_t& o0, uint32_t& o1) {
  uint32_t ks0 = k0, ks1 = k1, ks2 = k0 ^ k1 ^ 0x1BD11BDAu;
  x0 += ks0; x1 += ks1;
#define TFR(r) { x0 += x1; x1 = (x1 << (r)) | (x1 >> (32 - (r))); x1 ^= x0; }
  TFR(13) TFR(15) TFR(26) TFR(6)   x0 += ks1; x1 += ks2 + 1u;
  TFR(17) TFR(29) TFR(16) TFR(24)  x0 += ks2; x1 += ks0 + 2u;
  TFR(13) TFR(15) TFR(26) TFR(6)   x0 += ks0; x1 += ks1 + 3u;
  TFR(17) TFR(29) TFR(16) TFR(24)  x0 += ks1; x1 += ks2 + 4u;
  TFR(13) TFR(15) TFR(26) TFR(6)   x0 += ks2; x1 += ks0 + 5u;
#undef TFR
  o0 = x0; o1 = x1;
}

__device__ inline uint16_t f2bf(float f) {
  uint32_t u = __float_as_uint(f);
  return (uint16_t)((u + 0x7fffu + ((u >> 16) & 1u)) >> 16);   // RNE
}

// dropout value for edge e under key (k0,k1): JAX split-iota bernoulli
__device__ inline float drop_val(float s, int e, uint32_t k0, uint32_t k1) {
  const uint32_t half = NE / 2;
  uint32_t lo = (e < (int)half) ? (uint32_t)e : (uint32_t)e - half;
  uint32_t o0, o1;
  tf2x32(k0, k1, lo, lo + half, o0, o1);
  uint32_t bits = (e < (int)half) ? o0 : o1;
  float u = __uint_as_float((bits >> 9) | 0x3f800000u) - 1.0f;
  return (u < 0.75f) ? s * (1.0f / 0.75f) : 0.0f;
}

// ---------------- CSR build ----------------
__global__ void hist_kernel(const int* __restrict__ rows, const int* __restrict__ cols,
                            int* __restrict__ cntU, int* __restrict__ cntI) {
  int e = blockIdx.x * blockDim.x + threadIdx.x;
  if (e >= NE) return;
  atomicAdd(&cntU[rows[e]], 1);
  atomicAdd(&cntI[cols[e]], 1);
}

#define SCAN_B 256
__global__ void scan_phase1(const int* __restrict__ cnt, int n, int* __restrict__ bs) {
  __shared__ int red[SCAN_B];
  int t = threadIdx.x, i = blockIdx.x * SCAN_B + t;
  red[t] = (i < n) ? cnt[i] : 0;
  __syncthreads();
  for (int s = 128; s > 0; s >>= 1) {
    if (t < s) red[t] += red[t + s];
    __syncthreads();
  }
  if (t == 0) bs[blockIdx.x] = red[0];
}
__global__ void scan_phase2(int* __restrict__ bs, int nb) {  // 1 block, 1024 thr, nb<=1024
  __shared__ int sh[1024];
  int t = threadIdx.x;
  int v = (t < nb) ? bs[t] : 0;
  sh[t] = v;
  __syncthreads();
  for (int off = 1; off < 1024; off <<= 1) {
    int add = (t >= off) ? sh[t - off] : 0;
    __syncthreads();
    sh[t] += add;
    __syncthreads();
  }
  if (t < nb) bs[t] = sh[t] - v;   // exclusive
}
__global__ void scan_phase3(const int* __restrict__ cnt, int n, const int* __restrict__ bs,
                            int* __restrict__ off) {
  __shared__ int sh[SCAN_B];
  int t = threadIdx.x, i = blockIdx.x * SCAN_B + t;
  int v = (i < n) ? cnt[i] : 0;
  sh[t] = v;
  __syncthreads();
  for (int o = 1; o < SCAN_B; o <<= 1) {
    int add = (t >= o) ? sh[t - o] : 0;
    __syncthreads();
    sh[t] += add;
    __syncthreads();
  }
  if (i < n) off[i] = bs[blockIdx.x] + sh[t] - v;
  if (i == n - 1) off[n] = bs[blockIdx.x] + sh[t];
}

__global__ void scatter_kernel(const int* __restrict__ rows, const int* __restrict__ cols,
                               const int* __restrict__ offU, const int* __restrict__ offI,
                               int* __restrict__ fillU, int* __restrict__ fillI,
                               int* __restrict__ colU, int* __restrict__ peU,
                               int* __restrict__ colI, int* __restrict__ peI) {
  int e = blockIdx.x * blockDim.x + threadIdx.x;
  if (e >= NE) return;
  int r = rows[e], c = cols[e];
  int pu = offU[r] + atomicAdd(&fillU[r], 1);
  colU[pu] = c; peU[pu] = e;
  int pi = offI[c] + atomicAdd(&fillI[c], 1);
  colI[pi] = r; peI[pi] = e;
}

// all 4 dropout-value arrays for one propagation in a single pass
__global__ void drop_batch_kernel(const float* __restrict__ src,
                                  const int* __restrict__ peU, const int* __restrict__ peI,
                                  float* __restrict__ vU0, float* __restrict__ vU1,
                                  float* __restrict__ vI0, float* __restrict__ vI1,
                                  uint32_t k00, uint32_t k01, uint32_t k10, uint32_t k11,
                                  uint32_t k20, uint32_t k21, uint32_t k30, uint32_t k31) {
  int p = blockIdx.x * blockDim.x + threadIdx.x;
  if (p >= NE) return;
  int eU = peU[p], eI = peI[p];
  float sU = src[eU], sI = src[eI];
  vU0[p] = drop_val(sU, eU, k00, k01);   // layer0 U (fold 0)
  vU1[p] = drop_val(sU, eU, k20, k21);   // layer1 U (fold 2)
  vI0[p] = drop_val(sI, eI, k10, k11);   // layer0 I (fold 1)
  vI1[p] = drop_val(sI, eI, k30, k31);   // layer1 I (fold 3)
}

// gather-reduce SpMM: one wave per output row, lane = dim. No atomics.
// Sum[idx] = (base ? base[idx] : Sum[idx]) + acc  (fused layer-sum update)
__global__ __launch_bounds__(256)
void spmm_csr_kernel(const int* __restrict__ off, const int* __restrict__ col,
                     const float* __restrict__ valP, const float* __restrict__ S,
                     float* __restrict__ Dout, float* __restrict__ Sum,
                     const float* __restrict__ base, int nR) {
  int lane = threadIdx.x & 63;
  int r = (blockIdx.x * blockDim.x + threadIdx.x) >> 6;
  if (r >= nR) return;
  int p0 = off[r], p1 = off[r + 1];
  float acc = 0.f;
  int p = p0;
  for (; p + 4 <= p1; p += 4) {          // 4 concurrent gathers per chunk
    int c0 = col[p], c1 = col[p + 1], c2 = col[p + 2], c3 = col[p + 3];
    float v0 = valP[p], v1 = valP[p + 1], v2 = valP[p + 2], v3 = valP[p + 3];
    float s0 = S[(size_t)c0 * DD + lane];
    float s1 = S[(size_t)c1 * DD + lane];
    float s2 = S[(size_t)c2 * DD + lane];
    float s3 = S[(size_t)c3 * DD + lane];
    acc += v0 * s0 + v1 * s1 + v2 * s2 + v3 * s3;
  }
  for (; p < p1; ++p) {
    float v = valP[p];
    if (v != 0.f) acc += v * S[(size_t)col[p] * DD + lane];
  }
  size_t idx = (size_t)r * DD + lane;
  Dout[idx] = acc;
  Sum[idx] = (base ? base[idx] : Sum[idx]) + acc;
}

// 4 edges per wave (16 lanes each, float4 over dims)
__global__ void edge_logit_kernel(const float* __restrict__ Eu, const float* __restrict__ Ev,
                                  const int* __restrict__ rows, const int* __restrict__ cols,
                                  const float* __restrict__ av, float* __restrict__ aug) {
  int lane = threadIdx.x & 63;
  int sub = lane >> 4, l15 = lane & 15;
  int w = (blockIdx.x * blockDim.x + threadIdx.x) >> 6;
  int nw = (gridDim.x * blockDim.x) >> 6;
  for (int b = w * 4; b < NE; b += nw * 4) {
    int e = b + sub;
    float4 a = *(const float4*)&Eu[(size_t)rows[e] * DD + l15 * 4];
    float4 c = *(const float4*)&Ev[(size_t)cols[e] * DD + l15 * 4];
    float p = a.x * c.x + a.y * c.y + a.z * c.z + a.w * c.w;
#pragma unroll
    for (int off = 8; off > 0; off >>= 1) p += __shfl_down(p, off, 16);
    if (l15 == 0) aug[e] = av[e] / (1.0f + __expf(-p));
  }
}

// fp32 -> bf16 bulk convert (4 elems/thread)
__global__ void cvt_bf16_kernel(const float4* __restrict__ x, uint2* __restrict__ y, int n4) {
  int i = blockIdx.x * blockDim.x + threadIdx.x;
  if (i >= n4) return;
  float4 v = x[i];
  uint2 o;
  o.x = (uint32_t)f2bf(v.x) | ((uint32_t)f2bf(v.y) << 16);
  o.y = (uint32_t)f2bf(v.z) | ((uint32_t)f2bf(v.w) << 16);
  y[i] = o;
}

// gather rows Z[ids[b]] -> bf16 [BATCH][64]
__global__ void gather_bf16_kernel(const float* __restrict__ Z, const int* __restrict__ ids,
                                   uint16_t* __restrict__ out) {
  int b = blockIdx.x, lane = threadIdx.x;
  out[(size_t)b * 64 + lane] = f2bf(Z[(size_t)ids[b] * 64 + lane]);
}

// PCL denominator: S[m] += sum_n exp(5*dot(Zg[m],E[n])), bf16 MFMA 16x16x32.
// Each wave pins A-frags for FOUR m-tiles (64 m-rows) in regs; per B-tile load
// it runs 8 MFMA + 16 exp2 (~140 busy cyc) -> L1/L2 latency fully hidden, B
// traffic per FLOP /4 vs round-3. One-deep prefetch on top.
__global__ __launch_bounds__(256)
void pcl_mfma3_kernel(const uint16_t* __restrict__ Zg, const uint16_t* __restrict__ E16,
                      int NT, int SPL, float* __restrict__ S) {
  int lane = threadIdx.x & 63;
  int wave = threadIdx.x >> 6;
  int quad = lane >> 4, l15 = lane & 15;
  int mt0 = (blockIdx.y * 4 + wave) * 4;       // 4 consecutive m-tiles per wave
  bf16x8 a0[4], a1[4];
#pragma unroll
  for (int i = 0; i < 4; ++i) {
    const uint16_t* ar = Zg + (size_t)((mt0 + i) * 16 + l15) * 64 + quad * 8;
    a0[i] = *(const bf16x8*)ar;
    a1[i] = *(const bf16x8*)(ar + 32);
  }
  f32x4 rs[4] = {};
  int nt = blockIdx.x;
  bf16x8 b0 = {}, b1 = {};
  if (nt < NT) {
    const uint16_t* br = E16 + (size_t)(nt * 16 + l15) * 64 + quad * 8;
    b0 = *(const bf16x8*)br;
    b1 = *(const bf16x8*)(br + 32);
  }
  const float LOG2E5 = 7.2134752f;             // 5 * log2(e): exp(5x)=2^(x*LOG2E5)
  while (nt < NT) {
    int nn = nt + SPL;
    bf16x8 p0 = {}, p1 = {};
    if (nn < NT) {
      const uint16_t* pr = E16 + (size_t)(nn * 16 + l15) * 64 + quad * 8;
      p0 = *(const bf16x8*)pr;
      p1 = *(const bf16x8*)(pr + 32);
    }
#pragma unroll
    for (int i = 0; i < 4; ++i) {
      f32x4 c = {0.f, 0.f, 0.f, 0.f};
      c = __builtin_amdgcn_mfma_f32_16x16x32_bf16(a0[i], b0, c, 0, 0, 0);
      c = __builtin_amdgcn_mfma_f32_16x16x32_bf16(a1[i], b1, c, 0, 0, 0);
#pragma unroll
      for (int r = 0; r < 4; ++r) rs[i][r] += __builtin_amdgcn_exp2f(c[r] * LOG2E5);
    }
    b0 = p0; b1 = p1; nt = nn;
  }
#pragma unroll
  for (int off = 8; off > 0; off >>= 1) {
#pragma unroll
    for (int i = 0; i < 4; ++i)
#pragma unroll
      for (int r = 0; r < 4; ++r) rs[i][r] += __shfl_down(rs[i][r], off, 16);
  }
  if (l15 == 0) {
#pragma unroll
    for (int i = 0; i < 4; ++i)
#pragma unroll
      for (int r = 0; r < 4; ++r)
        atomicAdd(&S[(mt0 + i) * 16 + quad * 4 + r], rs[i][r]);
  }
}

__global__ void bpr_kernel(const float* __restrict__ Eu, const float* __restrict__ Ev,
                           const int* __restrict__ uids, const int* __restrict__ pos,
                           const int* __restrict__ neg, float* __restrict__ ps,
                           float* __restrict__ acc) {
  int lane = threadIdx.x & 63;
  int b = (blockIdx.x * blockDim.x + threadIdx.x) >> 6;
  if (b >= BATCH) return;
  float u = Eu[(size_t)uids[b] * DD + lane];
  float p = u * Ev[(size_t)pos[b] * DD + lane];
  float n = u * Ev[(size_t)neg[b] * DD + lane];
#pragma unroll
  for (int off = 32; off > 0; off >>= 1) { p += __shfl_down(p, off); n += __shfl_down(n, off); }
  if (lane == 0) {
    ps[b] = p;
    float x = p - n;
    atomicAdd(&acc[0], logf(1.0f / (1.0f + __expf(-x))));
  }
}

__global__ void minmax_kernel(const float* __restrict__ ps, float* __restrict__ mm) {
  __shared__ float smn[256], smx[256];
  int tid = threadIdx.x;
  float mn = 3.0e38f, mx = -3.0e38f;
  for (int i = tid; i < BATCH; i += 256) { float v = ps[i]; mn = fminf(mn, v); mx = fmaxf(mx, v); }
  smn[tid] = mn; smx[tid] = mx;
  __syncthreads();
  for (int s = 128; s > 0; s >>= 1) {
    if (tid < s) { smn[tid] = fminf(smn[tid], smn[tid + s]); smx[tid] = fmaxf(smx[tid], smx[tid + s]); }
    __syncthreads();
  }
  if (tid == 0) { mm[0] = smn[0]; mm[1] = smx[0]; }
}

__global__ void bcl_kernel(const float* __restrict__ Eu, const float* __restrict__ Ev,
                           const float* __restrict__ Eb, const int* __restrict__ uids,
                           const int* __restrict__ pos, const float* __restrict__ ps,
                           const float* __restrict__ mm, float* __restrict__ acc) {
  int lane = threadIdx.x & 63;
  int b = (blockIdx.x * blockDim.x + threadIdx.x) >> 6;
  if (b >= BATCH) return;
  float wgt = (ps[b] - mm[0]) / (mm[1] - mm[0] + 1e-9f);
  int rel = (int)(wgt * 10.0f);
  rel = rel < 0 ? 0 : (rel > 9 ? 9 : rel);
  float el = 1.0f / (1.0f + __expf(-(Eu[(size_t)uids[b] * DD + lane] * Ev[(size_t)pos[b] * DD + lane])));
  float sneg = 0.f, spos = 0.f;
  for (int k = 0; k < NBK; ++k) {
    float d = el * Eb[k * DD + lane];
#pragma unroll
    for (int off = 32; off > 0; off >>= 1) d += __shfl_down(d, off);
    if (lane == 0) { if (k == rel) spos = d; else sneg += d; }
  }
  if (lane == 0) {
    atomicAdd(&acc[5], sneg * 0.1f);
    atomicAdd(&acc[6], spos);
  }
}

__global__ void pclpos_kernel(const float* __restrict__ Zc, const float* __restrict__ Ec,
                              const int* __restrict__ ids, float* __restrict__ acc, int idx) {
  int lane = threadIdx.x & 63;
  int b = (blockIdx.x * blockDim.x + threadIdx.x) >> 6;
  if (b >= BATCH) return;
  size_t r = (size_t)ids[b] * DD + lane;
  float p = Zc[r] * Ec[r];
#pragma unroll
  for (int off = 32; off > 0; off >>= 1) p += __shfl_down(p, off);
  if (lane == 0) {
    float x = p * 5.0f;
    x = fminf(5.0f, fmaxf(-5.0f, x));
    atomicAdd(&acc[idx], x);
  }
}

__global__ void sumsq_kernel(const float* __restrict__ x, int n, float* __restrict__ acc, int idx) {
  __shared__ float red[256];
  int tid = threadIdx.x;
  float s = 0.f;
  for (int i = blockIdx.x * blockDim.x + tid; i < n; i += gridDim.x * blockDim.x) {
    float v = x[i]; s += v * v;
  }
  red[tid] = s;
  __syncthreads();
  for (int st = 128; st > 0; st >>= 1) {
    if (tid < st) red[tid] += red[tid + st];
    __syncthreads();
  }
  if (tid == 0) atomicAdd(&acc[idx], red[0]);
}

__global__ void finalize_kernel(const float* __restrict__ Su, const float* __restrict__ Si,
                                const float* __restrict__ acc, float* __restrict__ out) {
  __shared__ float r1[256], r2[256];
  int tid = threadIdx.x;
  float su = 0.f, si = 0.f;
  for (int b = tid; b < BATCH; b += 256) {
    su += logf(Su[b] + 1e-8f);
    si += logf(Si[b] + 1e-8f);
  }
  r1[tid] = su; r2[tid] = si;
  __syncthreads();
  for (int s = 128; s > 0; s >>= 1) {
    if (tid < s) { r1[tid] += r1[tid + s]; r2[tid] += r2[tid + s]; }
    __syncthreads();
  }
  if (tid == 0) {
    const float inv = 1.0f / (float)BATCH;
    float neg_s = (r1[0] + r2[0]) * inv;
    float pos_s = (acc[3] + acc[4]) * inv;
    float pcl = neg_s - pos_s;
    float bpr = -acc[0] * inv;
    float bcl = (acc[5] - acc[6]) * inv;
    float reg = 1e-7f * (acc[7] + acc[8] + acc[9]);
    float loss = bpr + 0.2f * pcl + 0.2f * bcl + reg;
    out[0] = loss; out[1] = bpr; out[2] = 0.2f * pcl; out[3] = 0.2f * bcl;
  }
}

extern "C" void kernel_launch(void* const* d_in, const int* in_sizes, int n_in,
                              void* d_out, int out_size, void* d_ws, size_t ws_size,
                              hipStream_t stream) {
  (void)in_sizes; (void)n_in; (void)out_size; (void)ws_size;
  const float* Eu0 = (const float*)d_in[0];
  const float* Ev0 = (const float*)d_in[1];
  const float* Eb  = (const float*)d_in[2];
  const float* av  = (const float*)d_in[3];
  const int* rows  = (const int*)d_in[4];
  const int* cols  = (const int*)d_in[5];
  const int* uids  = (const int*)d_in[6];
  const int* iids  = (const int*)d_in[7];
  const int* pos   = (const int*)d_in[8];
  const int* neg   = (const int*)d_in[9];
  float* out = (float*)d_out;

  float* w = (float*)d_ws;
  size_t o = 0;
  float* bu0 = w + o; o += (size_t)NU * DD;   // layer-0 u out
  float* bu1 = w + o; o += (size_t)NU * DD;   // layer-1 u out
  float* Eu  = w + o; o += (size_t)NU * DD;   // E_u (prop-0 sums)
  float* Zu  = w + o; o += (size_t)NU * DD;   // Z_u (prop-1 sums)
  float* bv0 = w + o; o += (size_t)NI * DD;
  float* bv1 = w + o; o += (size_t)NI * DD;
  float* Ev  = w + o; o += (size_t)NI * DD;
  float* Zi  = w + o; o += (size_t)NI * DD;
  // 5M-word scratch union: during props = 4 dropout-value arrays + augv;
  // after props reused for bf16 tables (4.8M words needed <= 5M).
  float* vU0  = w + o; o += NE;
  float* vU1  = w + o; o += NE;
  float* vI0  = w + o; o += NE;
  float* vI1  = w + o; o += NE;
  float* augv = w + o; o += NE;
  float* ps  = w + o; o += BATCH;
  float* Su  = w + o; o += BATCH;
  float* Si  = w + o; o += BATCH;
  float* acc = w + o; o += 16;
  float* mm  = w + o; o += 2;
  // int region
  int* ip = (int*)(w + o);
  int* offU = ip; ip += NU + 1;
  int* offI = ip; ip += NI + 1;
  int* cntU = ip; ip += NU;       // cntU/cntI adjacent: one memset covers both
  int* cntI = ip; ip += NI;
  int* colU = ip; ip += NE;
  int* peU  = ip; ip += NE;
  int* colI = ip; ip += NE;
  int* peI  = ip; ip += NE;

  // bf16 overlays (dead regions after both propagations)
  uint16_t* E16u = (uint16_t*)vU0;                        // 3.2M words
  uint16_t* E16i = (uint16_t*)(vU0 + (size_t)NU * DD / 2); // 1.6M words
  uint16_t* Zgu  = (uint16_t*)bu1;
  uint16_t* Zgi  = Zgu + (size_t)BATCH * DD;

  // key chain: key(42) = (0,42); fold_in(k,d) = threefry2x32(k, [0,d])
  uint32_t bk[2][2], lk[2][4][2];
  tf2x32(0u, 42u, 0u, 0u, bk[0][0], bk[0][1]);
  tf2x32(0u, 42u, 0u, 1u, bk[1][0], bk[1][1]);
  for (int p = 0; p < 2; ++p)
    for (int t = 0; t < 4; ++t)
      tf2x32(bk[p][0], bk[p][1], 0u, (uint32_t)t, lk[p][t][0], lk[p][t][1]);

  const int EB = (NE + 255) / 256;

  // ---- CSR build (once per call; reused by all 8 SpMMs) ----
  (void)hipMemsetAsync(cntU, 0, (size_t)(NU + NI) * sizeof(int), stream);
  hist_kernel<<<EB, 256, 0, stream>>>(rows, cols, cntU, cntI);
  {
    int nbU = (NU + SCAN_B - 1) / SCAN_B;
    int nbI = (NI + SCAN_B - 1) / SCAN_B;
    int* bsU = peU;                              // scratch (overwritten by scatter later)
    int* bsI = peI;
    scan_phase1<<<nbU, SCAN_B, 0, stream>>>(cntU, NU, bsU);
    scan_phase2<<<1, 1024, 0, stream>>>(bsU, nbU);
    scan_phase3<<<nbU, SCAN_B, 0, stream>>>(cntU, NU, bsU, offU);
    scan_phase1<<<nbI, SCAN_B, 0, stream>>>(cntI, NI, bsI);
    scan_phase2<<<1, 1024, 0, stream>>>(bsI, nbI);
    scan_phase3<<<nbI, SCAN_B, 0, stream>>>(cntI, NI, bsI, offI);
  }
  (void)hipMemsetAsync(cntU, 0, (size_t)(NU + NI) * sizeof(int), stream);   // reuse as fill
  scatter_kernel<<<EB, 256, 0, stream>>>(rows, cols, offU, offI, cntU, cntI,
                                         colU, peU, colI, peI);

  // ---- propagation (batched dropout + gather SpMM + fused layer-sum) ----
  auto propagate = [&](const float* vsrc, float* sumU, float* sumV, uint32_t (*k4)[2]) {
    drop_batch_kernel<<<EB, 256, 0, stream>>>(vsrc, peU, peI, vU0, vU1, vI0, vI1,
                                              k4[0][0], k4[0][1], k4[1][0], k4[1][1],
                                              k4[2][0], k4[2][1], k4[3][0], k4[3][1]);
    // layer 0: inputs Eu0/Ev0, sums seeded from base
    spmm_csr_kernel<<<NU / 4, 256, 0, stream>>>(offU, colU, vU0, Ev0, bu0, sumU, Eu0, NU);
    spmm_csr_kernel<<<NI / 4, 256, 0, stream>>>(offI, colI, vI0, Eu0, bv0, sumV, Ev0, NI);
    // layer 1
    spmm_csr_kernel<<<NU / 4, 256, 0, stream>>>(offU, colU, vU1, bv0, bu1, sumU, nullptr, NU);
    spmm_csr_kernel<<<NI / 4, 256, 0, stream>>>(offI, colI, vI1, bu0, bv1, sumV, nullptr, NI);
  };

  propagate(av, Eu, Ev, lk[0]);
  edge_logit_kernel<<<2048, 256, 0, stream>>>(Eu, Ev, rows, cols, av, augv);
  propagate(augv, Zu, Zi, lk[1]);

  // ---- bf16 conversions for MFMA PCL (scratch union is dead now) ----
  cvt_bf16_kernel<<<(NU * DD / 4 + 255) / 256, 256, 0, stream>>>((const float4*)Eu, (uint2*)E16u, NU * DD / 4);
  cvt_bf16_kernel<<<(NI * DD / 4 + 255) / 256, 256, 0, stream>>>((const float4*)Ev, (uint2*)E16i, NI * DD / 4);
  gather_bf16_kernel<<<BATCH, 64, 0, stream>>>(Zu, uids, Zgu);
  gather_bf16_kernel<<<BATCH, 64, 0, stream>>>(Zi, iids, Zgi);

  (void)hipMemsetAsync(Su, 0, (2 * BATCH + 16) * sizeof(float), stream);   // Su,Si,acc adjacent

  bpr_kernel<<<BATCH / 4, 256, 0, stream>>>(Eu, Ev, uids, pos, neg, ps, acc);
  minmax_kernel<<<1, 256, 0, stream>>>(ps, mm);
  bcl_kernel<<<BATCH / 4, 256, 0, stream>>>(Eu, Ev, Eb, uids, pos, ps, mm, acc);

  // PCL denominators: wave = 4 m-tiles; grid y=8 (128 m-tiles), x = n-splits
  pcl_mfma3_kernel<<<dim3(256, 8), 256, 0, stream>>>(Zgu, E16u, NU / 16, 256, Su);
  pcl_mfma3_kernel<<<dim3(128, 8), 256, 0, stream>>>(Zgi, E16i, NI / 16, 128, Si);

  pclpos_kernel<<<BATCH / 4, 256, 0, stream>>>(Zu, Eu, uids, acc, 3);
  pclpos_kernel<<<BATCH / 4, 256, 0, stream>>>(Zi, Ev, iids, acc, 4);

  sumsq_kernel<<<1024, 256, 0, stream>>>(Eu0, NU * DD, acc, 7);
  sumsq_kernel<<<512, 256, 0, stream>>>(Ev0, NI * DD, acc, 8);
  sumsq_kernel<<<4, 256, 0, stream>>>(Eb, NBK * DD, acc, 9);

  finalize_kernel<<<1, 256, 0, stream>>>(Su, Si, acc, out);
}

// Round 6
// 1158.238 us; speedup vs baseline: 4.7631x; 1.0508x over previous
//
#include <hip/hip_runtime.h>
#include <stdint.h>

#define NU 100000
#define NI 50000
#define NBK 10
#define DD 64
#define NE 1000000
#define BATCH 2048

typedef __bf16 bf16x8 __attribute__((ext_vector_type(8)));
typedef float f32x4 __attribute__((ext_vector_type(4)));

// ---------------- threefry2x32 (JAX-compatible, 20 rounds) ----------------
__host__ __device__ inline void tf2x32(uint32_t k0, uint32_t k1, uint32_t x0, uint32_t x1,
                                       uint32_t& o0, uint32_t& o1) {
  uint32_t ks0 = k0, ks1 = k1, ks2 = k0 ^ k1 ^ 0x1BD11BDAu;
  x0 += ks0; x1 += ks1;
#define TFR(r) { x0 += x1; x1 = (x1 << (r)) | (x1 >> (32 - (r))); x1 ^= x0; }
  TFR(13) TFR(15) TFR(26) TFR(6)   x0 += ks1; x1 += ks2 + 1u;
  TFR(17) TFR(29) TFR(16) TFR(24)  x0 += ks2; x1 += ks0 + 2u;
  TFR(13) TFR(15) TFR(26) TFR(6)   x0 += ks0; x1 += ks1 + 3u;
  TFR(17) TFR(29) TFR(16) TFR(24)  x0 += ks1; x1 += ks2 + 4u;
  TFR(13) TFR(15) TFR(26) TFR(6)   x0 += ks2; x1 += ks0 + 5u;
#undef TFR
  o0 = x0; o1 = x1;
}

__device__ inline uint16_t f2bf(float f) {
  uint32_t u = __float_as_uint(f);
  return (uint16_t)((u + 0x7fffu + ((u >> 16) & 1u)) >> 16);   // RNE
}
__device__ inline float bf2f(uint16_t u) {
  return __uint_as_float(((uint32_t)u) << 16);
}

// dropout value for edge e under key (k0,k1): JAX split-iota bernoulli
__device__ inline float drop_val(float s, int e, uint32_t k0, uint32_t k1) {
  const uint32_t half = NE / 2;
  uint32_t lo = (e < (int)half) ? (uint32_t)e : (uint32_t)e - half;
  uint32_t o0, o1;
  tf2x32(k0, k1, lo, lo + half, o0, o1);
  uint32_t bits = (e < (int)half) ? o0 : o1;
  float u = __uint_as_float((bits >> 9) | 0x3f800000u) - 1.0f;
  return (u < 0.75f) ? s * (1.0f / 0.75f) : 0.0f;
}

// ---------------- CSR build ----------------
__global__ void hist_kernel(const int* __restrict__ rows, const int* __restrict__ cols,
                            int* __restrict__ cntU, int* __restrict__ cntI) {
  int e = blockIdx.x * blockDim.x + threadIdx.x;
  if (e >= NE) return;
  atomicAdd(&cntU[rows[e]], 1);
  atomicAdd(&cntI[cols[e]], 1);
}

#define SCAN_B 256
__global__ void scan_phase1(const int* __restrict__ cnt, int n, int* __restrict__ bs) {
  __shared__ int red[SCAN_B];
  int t = threadIdx.x, i = blockIdx.x * SCAN_B + t;
  red[t] = (i < n) ? cnt[i] : 0;
  __syncthreads();
  for (int s = 128; s > 0; s >>= 1) {
    if (t < s) red[t] += red[t + s];
    __syncthreads();
  }
  if (t == 0) bs[blockIdx.x] = red[0];
}
__global__ void scan_phase2(int* __restrict__ bs, int nb) {  // 1 block, 1024 thr, nb<=1024
  __shared__ int sh[1024];
  int t = threadIdx.x;
  int v = (t < nb) ? bs[t] : 0;
  sh[t] = v;
  __syncthreads();
  for (int off = 1; off < 1024; off <<= 1) {
    int add = (t >= off) ? sh[t - off] : 0;
    __syncthreads();
    sh[t] += add;
    __syncthreads();
  }
  if (t < nb) bs[t] = sh[t] - v;   // exclusive
}
__global__ void scan_phase3(const int* __restrict__ cnt, int n, const int* __restrict__ bs,
                            int* __restrict__ off) {
  __shared__ int sh[SCAN_B];
  int t = threadIdx.x, i = blockIdx.x * SCAN_B + t;
  int v = (i < n) ? cnt[i] : 0;
  sh[t] = v;
  __syncthreads();
  for (int o = 1; o < SCAN_B; o <<= 1) {
    int add = (t >= o) ? sh[t - o] : 0;
    __syncthreads();
    sh[t] += add;
    __syncthreads();
  }
  if (i < n) off[i] = bs[blockIdx.x] + sh[t] - v;
  if (i == n - 1) off[n] = bs[blockIdx.x] + sh[t];
}

// packed scatter: one 8B write per side per edge (col, edge)
__global__ void scatter_kernel(const int* __restrict__ rows, const int* __restrict__ cols,
                               const int* __restrict__ offU, const int* __restrict__ offI,
                               int* __restrict__ fillU, int* __restrict__ fillI,
                               int2* __restrict__ cpU, int2* __restrict__ cpI) {
  int e = blockIdx.x * blockDim.x + threadIdx.x;
  if (e >= NE) return;
  int r = rows[e], c = cols[e];
  int pu = offU[r] + atomicAdd(&fillU[r], 1);
  cpU[pu] = make_int2(c, e);
  int pi = offI[c] + atomicAdd(&fillI[c], 1);
  cpI[pi] = make_int2(r, e);
}

// all 4 dropout-value arrays for one propagation in a single pass
__global__ void drop_batch_kernel(const float* __restrict__ src,
                                  const int2* __restrict__ cpU, const int2* __restrict__ cpI,
                                  float* __restrict__ vU0, float* __restrict__ vU1,
                                  float* __restrict__ vI0, float* __restrict__ vI1,
                                  uint32_t k00, uint32_t k01, uint32_t k10, uint32_t k11,
                                  uint32_t k20, uint32_t k21, uint32_t k30, uint32_t k31) {
  int p = blockIdx.x * blockDim.x + threadIdx.x;
  if (p >= NE) return;
  int eU = cpU[p].y, eI = cpI[p].y;
  float sU = src[eU], sI = src[eI];
  vU0[p] = drop_val(sU, eU, k00, k01);   // layer0 U (fold 0)
  vU1[p] = drop_val(sU, eU, k20, k21);   // layer1 U (fold 2)
  vI0[p] = drop_val(sI, eI, k10, k11);   // layer0 I (fold 1)
  vI1[p] = drop_val(sI, eI, k30, k31);   // layer1 I (fold 3)
}

// merged U+I gather-reduce SpMM over bf16 tables: one wave per output row,
// lane = dim. Layer0 (D16 != null): writes bf16 out + Sum = base + acc.
// Layer1 (D16 == null): Sum += acc only.
__global__ __launch_bounds__(256)
void spmm_layer_kernel(const int* __restrict__ offU, const int2* __restrict__ cpU,
                       const float* __restrict__ vU,
                       const int* __restrict__ offI, const int2* __restrict__ cpI,
                       const float* __restrict__ vI,
                       const uint16_t* __restrict__ SU, const uint16_t* __restrict__ SI,
                       uint16_t* __restrict__ dU, uint16_t* __restrict__ dI,
                       float* __restrict__ sumU, float* __restrict__ sumI,
                       const float* __restrict__ baseU, const float* __restrict__ baseI) {
  int lane = threadIdx.x & 63;
  int r = (blockIdx.x * blockDim.x + threadIdx.x) >> 6;
  const int* off; const int2* cp; const float* val; const uint16_t* S;
  uint16_t* D; float* Sum; const float* base; int row;
  if (r < NU) {
    row = r; off = offU; cp = cpU; val = vU; S = SU; D = dU; Sum = sumU; base = baseU;
  } else {
    row = r - NU; off = offI; cp = cpI; val = vI; S = SI; D = dI; Sum = sumI; base = baseI;
  }
  int p0 = off[row], p1 = off[row + 1];
  float acc = 0.f;
  int p = p0;
  for (; p + 4 <= p1; p += 4) {          // 4 concurrent 128B row-gathers
    int2 c0 = cp[p], c1 = cp[p + 1], c2 = cp[p + 2], c3 = cp[p + 3];
    float v0 = val[p], v1 = val[p + 1], v2 = val[p + 2], v3 = val[p + 3];
    float s0 = bf2f(S[(size_t)c0.x * DD + lane]);
    float s1 = bf2f(S[(size_t)c1.x * DD + lane]);
    float s2 = bf2f(S[(size_t)c2.x * DD + lane]);
    float s3 = bf2f(S[(size_t)c3.x * DD + lane]);
    acc += v0 * s0 + v1 * s1 + v2 * s2 + v3 * s3;
  }
  for (; p < p1; ++p) {
    float v = val[p];
    if (v != 0.f) acc += v * bf2f(S[(size_t)cp[p].x * DD + lane]);
  }
  size_t idx = (size_t)row * DD + lane;
  if (D) {
    D[idx] = f2bf(acc);
    Sum[idx] = base[idx] + acc;
  } else {
    Sum[idx] += acc;
  }
}

// 4 edges per wave (16 lanes each, ushort4 over dims), bf16 tables
__global__ void edge_logit_kernel(const uint16_t* __restrict__ E16u,
                                  const uint16_t* __restrict__ E16i,
                                  const int* __restrict__ rows, const int* __restrict__ cols,
                                  const float* __restrict__ av, float* __restrict__ aug) {
  int lane = threadIdx.x & 63;
  int sub = lane >> 4, l15 = lane & 15;
  int w = (blockIdx.x * blockDim.x + threadIdx.x) >> 6;
  int nw = (gridDim.x * blockDim.x) >> 6;
  for (int b = w * 4; b < NE; b += nw * 4) {
    int e = b + sub;
    ushort4 a = *(const ushort4*)&E16u[(size_t)rows[e] * DD + l15 * 4];
    ushort4 c = *(const ushort4*)&E16i[(size_t)cols[e] * DD + l15 * 4];
    float p = bf2f(a.x) * bf2f(c.x) + bf2f(a.y) * bf2f(c.y) +
              bf2f(a.z) * bf2f(c.z) + bf2f(a.w) * bf2f(c.w);
#pragma unroll
    for (int off = 8; off > 0; off >>= 1) p += __shfl_down(p, off, 16);
    if (l15 == 0) aug[e] = av[e] / (1.0f + __expf(-p));
  }
}

// fp32 -> bf16 bulk convert (4 elems/thread)
__global__ void cvt_bf16_kernel(const float4* __restrict__ x, uint2* __restrict__ y, int n4) {
  int i = blockIdx.x * blockDim.x + threadIdx.x;
  if (i >= n4) return;
  float4 v = x[i];
  uint2 o;
  o.x = (uint32_t)f2bf(v.x) | ((uint32_t)f2bf(v.y) << 16);
  o.y = (uint32_t)f2bf(v.z) | ((uint32_t)f2bf(v.w) << 16);
  y[i] = o;
}

// gather rows Z[ids[b]] -> bf16 [BATCH][64]
__global__ void gather_bf16_kernel(const float* __restrict__ Z, const int* __restrict__ ids,
                                   uint16_t* __restrict__ out) {
  int b = blockIdx.x, lane = threadIdx.x;
  out[(size_t)b * 64 + lane] = f2bf(Z[(size_t)ids[b] * 64 + lane]);
}

// PCL denominator: S[m] += sum_n exp(5*dot(Zg[m],E[n])), bf16 MFMA 16x16x32.
// Wave pins A-frags for 4 m-tiles (64 m-rows); per B-tile: 8 MFMA + 16 exp2.
__global__ __launch_bounds__(256)
void pcl_mfma3_kernel(const uint16_t* __restrict__ Zg, const uint16_t* __restrict__ E16,
                      int NT, int SPL, float* __restrict__ S) {
  int lane = threadIdx.x & 63;
  int wave = threadIdx.x >> 6;
  int quad = lane >> 4, l15 = lane & 15;
  int mt0 = (blockIdx.y * 4 + wave) * 4;
  bf16x8 a0[4], a1[4];
#pragma unroll
  for (int i = 0; i < 4; ++i) {
    const uint16_t* ar = Zg + (size_t)((mt0 + i) * 16 + l15) * 64 + quad * 8;
    a0[i] = *(const bf16x8*)ar;
    a1[i] = *(const bf16x8*)(ar + 32);
  }
  f32x4 rs[4] = {};
  int nt = blockIdx.x;
  bf16x8 b0 = {}, b1 = {};
  if (nt < NT) {
    const uint16_t* br = E16 + (size_t)(nt * 16 + l15) * 64 + quad * 8;
    b0 = *(const bf16x8*)br;
    b1 = *(const bf16x8*)(br + 32);
  }
  const float LOG2E5 = 7.2134752f;             // 5*log2(e): exp(5x)=2^(x*LOG2E5)
  while (nt < NT) {
    int nn = nt + SPL;
    bf16x8 p0 = {}, p1 = {};
    if (nn < NT) {
      const uint16_t* pr = E16 + (size_t)(nn * 16 + l15) * 64 + quad * 8;
      p0 = *(const bf16x8*)pr;
      p1 = *(const bf16x8*)(pr + 32);
    }
#pragma unroll
    for (int i = 0; i < 4; ++i) {
      f32x4 c = {0.f, 0.f, 0.f, 0.f};
      c = __builtin_amdgcn_mfma_f32_16x16x32_bf16(a0[i], b0, c, 0, 0, 0);
      c = __builtin_amdgcn_mfma_f32_16x16x32_bf16(a1[i], b1, c, 0, 0, 0);
#pragma unroll
      for (int r = 0; r < 4; ++r) rs[i][r] += __builtin_amdgcn_exp2f(c[r] * LOG2E5);
    }
    b0 = p0; b1 = p1; nt = nn;
  }
#pragma unroll
  for (int off = 8; off > 0; off >>= 1) {
#pragma unroll
    for (int i = 0; i < 4; ++i)
#pragma unroll
      for (int r = 0; r < 4; ++r) rs[i][r] += __shfl_down(rs[i][r], off, 16);
  }
  if (l15 == 0) {
#pragma unroll
    for (int i = 0; i < 4; ++i)
#pragma unroll
      for (int r = 0; r < 4; ++r)
        atomicAdd(&S[(mt0 + i) * 16 + quad * 4 + r], rs[i][r]);
  }
}

__global__ void bpr_kernel(const float* __restrict__ Eu, const float* __restrict__ Ev,
                           const int* __restrict__ uids, const int* __restrict__ pos,
                           const int* __restrict__ neg, float* __restrict__ ps,
                           float* __restrict__ acc) {
  int lane = threadIdx.x & 63;
  int b = (blockIdx.x * blockDim.x + threadIdx.x) >> 6;
  if (b >= BATCH) return;
  float u = Eu[(size_t)uids[b] * DD + lane];
  float p = u * Ev[(size_t)pos[b] * DD + lane];
  float n = u * Ev[(size_t)neg[b] * DD + lane];
#pragma unroll
  for (int off = 32; off > 0; off >>= 1) { p += __shfl_down(p, off); n += __shfl_down(n, off); }
  if (lane == 0) {
    ps[b] = p;
    float x = p - n;
    atomicAdd(&acc[0], logf(1.0f / (1.0f + __expf(-x))));
  }
}

__global__ void minmax_kernel(const float* __restrict__ ps, float* __restrict__ mm) {
  __shared__ float smn[256], smx[256];
  int tid = threadIdx.x;
  float mn = 3.0e38f, mx = -3.0e38f;
  for (int i = tid; i < BATCH; i += 256) { float v = ps[i]; mn = fminf(mn, v); mx = fmaxf(mx, v); }
  smn[tid] = mn; smx[tid] = mx;
  __syncthreads();
  for (int s = 128; s > 0; s >>= 1) {
    if (tid < s) { smn[tid] = fminf(smn[tid], smn[tid + s]); smx[tid] = fmaxf(smx[tid], smx[tid + s]); }
    __syncthreads();
  }
  if (tid == 0) { mm[0] = smn[0]; mm[1] = smx[0]; }
}

__global__ void bcl_kernel(const float* __restrict__ Eu, const float* __restrict__ Ev,
                           const float* __restrict__ Eb, const int* __restrict__ uids,
                           const int* __restrict__ pos, const float* __restrict__ ps,
                           const float* __restrict__ mm, float* __restrict__ acc) {
  int lane = threadIdx.x & 63;
  int b = (blockIdx.x * blockDim.x + threadIdx.x) >> 6;
  if (b >= BATCH) return;
  float wgt = (ps[b] - mm[0]) / (mm[1] - mm[0] + 1e-9f);
  int rel = (int)(wgt * 10.0f);
  rel = rel < 0 ? 0 : (rel > 9 ? 9 : rel);
  float el = 1.0f / (1.0f + __expf(-(Eu[(size_t)uids[b] * DD + lane] * Ev[(size_t)pos[b] * DD + lane])));
  float sneg = 0.f, spos = 0.f;
  for (int k = 0; k < NBK; ++k) {
    float d = el * Eb[k * DD + lane];
#pragma unroll
    for (int off = 32; off > 0; off >>= 1) d += __shfl_down(d, off);
    if (lane == 0) { if (k == rel) spos = d; else sneg += d; }
  }
  if (lane == 0) {
    atomicAdd(&acc[5], sneg * 0.1f);
    atomicAdd(&acc[6], spos);
  }
}

__global__ void pclpos_kernel(const float* __restrict__ Zc, const float* __restrict__ Ec,
                              const int* __restrict__ ids, float* __restrict__ acc, int idx) {
  int lane = threadIdx.x & 63;
  int b = (blockIdx.x * blockDim.x + threadIdx.x) >> 6;
  if (b >= BATCH) return;
  size_t r = (size_t)ids[b] * DD + lane;
  float p = Zc[r] * Ec[r];
#pragma unroll
  for (int off = 32; off > 0; off >>= 1) p += __shfl_down(p, off);
  if (lane == 0) {
    float x = p * 5.0f;
    x = fminf(5.0f, fmaxf(-5.0f, x));
    atomicAdd(&acc[idx], x);
  }
}

__global__ void sumsq_kernel(const float* __restrict__ x, int n, float* __restrict__ acc, int idx) {
  __shared__ float red[256];
  int tid = threadIdx.x;
  float s = 0.f;
  for (int i = blockIdx.x * blockDim.x + tid; i < n; i += gridDim.x * blockDim.x) {
    float v = x[i]; s += v * v;
  }
  red[tid] = s;
  __syncthreads();
  for (int st = 128; st > 0; st >>= 1) {
    if (tid < st) red[tid] += red[tid + st];
    __syncthreads();
  }
  if (tid == 0) atomicAdd(&acc[idx], red[0]);
}

__global__ void finalize_kernel(const float* __restrict__ Su, const float* __restrict__ Si,
                                const float* __restrict__ acc, float* __restrict__ out) {
  __shared__ float r1[256], r2[256];
  int tid = threadIdx.x;
  float su = 0.f, si = 0.f;
  for (int b = tid; b < BATCH; b += 256) {
    su += logf(Su[b] + 1e-8f);
    si += logf(Si[b] + 1e-8f);
  }
  r1[tid] = su; r2[tid] = si;
  __syncthreads();
  for (int s = 128; s > 0; s >>= 1) {
    if (tid < s) { r1[tid] += r1[tid + s]; r2[tid] += r2[tid + s]; }
    __syncthreads();
  }
  if (tid == 0) {
    const float inv = 1.0f / (float)BATCH;
    float neg_s = (r1[0] + r2[0]) * inv;
    float pos_s = (acc[3] + acc[4]) * inv;
    float pcl = neg_s - pos_s;
    float bpr = -acc[0] * inv;
    float bcl = (acc[5] - acc[6]) * inv;
    float reg = 1e-7f * (acc[7] + acc[8] + acc[9]);
    float loss = bpr + 0.2f * pcl + 0.2f * bcl + reg;
    out[0] = loss; out[1] = bpr; out[2] = 0.2f * pcl; out[3] = 0.2f * bcl;
  }
}

extern "C" void kernel_launch(void* const* d_in, const int* in_sizes, int n_in,
                              void* d_out, int out_size, void* d_ws, size_t ws_size,
                              hipStream_t stream) {
  (void)in_sizes; (void)n_in; (void)out_size; (void)ws_size;
  const float* Eu0 = (const float*)d_in[0];
  const float* Ev0 = (const float*)d_in[1];
  const float* Eb  = (const float*)d_in[2];
  const float* av  = (const float*)d_in[3];
  const int* rows  = (const int*)d_in[4];
  const int* cols  = (const int*)d_in[5];
  const int* uids  = (const int*)d_in[6];
  const int* iids  = (const int*)d_in[7];
  const int* pos   = (const int*)d_in[8];
  const int* neg   = (const int*)d_in[9];
  float* out = (float*)d_out;

  float* w = (float*)d_ws;
  size_t o = 0;
  float* Eu  = w + o; o += (size_t)NU * DD;   // E_u (prop-0 sums, fp32)
  float* Zu  = w + o; o += (size_t)NU * DD;
  float* Ev  = w + o; o += (size_t)NI * DD;
  float* Zi  = w + o; o += (size_t)NI * DD;
  float* vU0  = w + o; o += NE;
  float* vU1  = w + o; o += NE;
  float* vI0  = w + o; o += NE;
  float* vI1  = w + o; o += NE;
  float* augv = w + o; o += NE;
  float* ps  = w + o; o += BATCH;
  float* Su  = w + o; o += BATCH;
  float* Si  = w + o; o += BATCH;
  float* acc = w + o; o += 16;
  float* mm  = w + o; o += 2;
  // bf16 region (u16 units)
  uint16_t* hp = (uint16_t*)(w + o);
  uint16_t* E0u16 = hp; hp += (size_t)NU * DD;   // bf16(Eu0)
  uint16_t* E0v16 = hp; hp += (size_t)NI * DD;   // bf16(Ev0)
  uint16_t* d16U  = hp; hp += (size_t)NU * DD;   // layer0 U out (per prop)
  uint16_t* d16I  = hp; hp += (size_t)NI * DD;   // layer0 I out (per prop)
  uint16_t* E16u  = hp; hp += (size_t)NU * DD;   // bf16(E_u sums)
  uint16_t* E16i  = hp; hp += (size_t)NI * DD;   // bf16(E_v sums)
  uint16_t* Zgu   = hp; hp += (size_t)BATCH * DD;
  uint16_t* Zgi   = hp; hp += (size_t)BATCH * DD;
  // int region
  int* ip = (int*)hp;
  if (((uintptr_t)ip) & 7) ip = (int*)(((uintptr_t)ip + 7) & ~(uintptr_t)7);
  int* offU = ip; ip += NU + 1;
  int* offI = ip; ip += NI + 1;
  int* cntU = ip; ip += NU;       // cntU/cntI adjacent: one memset covers both
  int* cntI = ip; ip += NI;
  ip += 2;                        // pad to 8B for int2
  int2* cpU = (int2*)ip; ip += 2 * (size_t)NE;
  int2* cpI = (int2*)ip; ip += 2 * (size_t)NE;

  // key chain: key(42) = (0,42); fold_in(k,d) = threefry2x32(k, [0,d])
  uint32_t bk[2][2], lk[2][4][2];
  tf2x32(0u, 42u, 0u, 0u, bk[0][0], bk[0][1]);
  tf2x32(0u, 42u, 0u, 1u, bk[1][0], bk[1][1]);
  for (int p = 0; p < 2; ++p)
    for (int t = 0; t < 4; ++t)
      tf2x32(bk[p][0], bk[p][1], 0u, (uint32_t)t, lk[p][t][0], lk[p][t][1]);

  const int EB = (NE + 255) / 256;

  // ---- one-time bf16 copies of the base embeddings ----
  cvt_bf16_kernel<<<(NU * DD / 4 + 255) / 256, 256, 0, stream>>>((const float4*)Eu0, (uint2*)E0u16, NU * DD / 4);
  cvt_bf16_kernel<<<(NI * DD / 4 + 255) / 256, 256, 0, stream>>>((const float4*)Ev0, (uint2*)E0v16, NI * DD / 4);

  // ---- CSR build (once per call; reused by all SpMMs) ----
  (void)hipMemsetAsync(cntU, 0, (size_t)(NU + NI) * sizeof(int), stream);
  hist_kernel<<<EB, 256, 0, stream>>>(rows, cols, cntU, cntI);
  {
    int nbU = (NU + SCAN_B - 1) / SCAN_B;
    int nbI = (NI + SCAN_B - 1) / SCAN_B;
    int* bsU = (int*)cpU;                        // scratch (overwritten by scatter later)
    int* bsI = (int*)cpI;
    scan_phase1<<<nbU, SCAN_B, 0, stream>>>(cntU, NU, bsU);
    scan_phase2<<<1, 1024, 0, stream>>>(bsU, nbU);
    scan_phase3<<<nbU, SCAN_B, 0, stream>>>(cntU, NU, bsU, offU);
    scan_phase1<<<nbI, SCAN_B, 0, stream>>>(cntI, NI, bsI);
    scan_phase2<<<1, 1024, 0, stream>>>(bsI, nbI);
    scan_phase3<<<nbI, SCAN_B, 0, stream>>>(cntI, NI, bsI, offI);
  }
  (void)hipMemsetAsync(cntU, 0, (size_t)(NU + NI) * sizeof(int), stream);   // reuse as fill
  scatter_kernel<<<EB, 256, 0, stream>>>(rows, cols, offU, offI, cntU, cntI, cpU, cpI);

  const int SPB = (NU + NI) / 4;   // merged spmm: (NU+NI) waves, 4/block

  auto propagate = [&](const float* vsrc, float* sumU, float* sumV, uint32_t (*k4)[2]) {
    drop_batch_kernel<<<EB, 256, 0, stream>>>(vsrc, cpU, cpI, vU0, vU1, vI0, vI1,
                                              k4[0][0], k4[0][1], k4[1][0], k4[1][1],
                                              k4[2][0], k4[2][1], k4[3][0], k4[3][1]);
    // layer 0: gather base bf16 tables, write bf16 outs + seeded sums
    spmm_layer_kernel<<<SPB, 256, 0, stream>>>(offU, cpU, vU0, offI, cpI, vI0,
                                               E0v16, E0u16, d16U, d16I,
                                               sumU, sumV, Eu0, Ev0);
    // layer 1: gather layer-0 bf16 outs, accumulate sums only
    spmm_layer_kernel<<<SPB, 256, 0, stream>>>(offU, cpU, vU1, offI, cpI, vI1,
                                               d16I, d16U, nullptr, nullptr,
                                               sumU, sumV, nullptr, nullptr);
  };

  propagate(av, Eu, Ev, lk[0]);

  // bf16 copies of the prop-0 sums (used by edge_logit now, PCL later)
  cvt_bf16_kernel<<<(NU * DD / 4 + 255) / 256, 256, 0, stream>>>((const float4*)Eu, (uint2*)E16u, NU * DD / 4);
  cvt_bf16_kernel<<<(NI * DD / 4 + 255) / 256, 256, 0, stream>>>((const float4*)Ev, (uint2*)E16i, NI * DD / 4);

  edge_logit_kernel<<<4096, 256, 0, stream>>>(E16u, E16i, rows, cols, av, augv);

  propagate(augv, Zu, Zi, lk[1]);

  gather_bf16_kernel<<<BATCH, 64, 0, stream>>>(Zu, uids, Zgu);
  gather_bf16_kernel<<<BATCH, 64, 0, stream>>>(Zi, iids, Zgi);

  (void)hipMemsetAsync(Su, 0, (2 * BATCH + 16) * sizeof(float), stream);   // Su,Si,acc adjacent

  bpr_kernel<<<BATCH / 4, 256, 0, stream>>>(Eu, Ev, uids, pos, neg, ps, acc);
  minmax_kernel<<<1, 256, 0, stream>>>(ps, mm);
  bcl_kernel<<<BATCH / 4, 256, 0, stream>>>(Eu, Ev, Eb, uids, pos, ps, mm, acc);

  // PCL denominators: wave = 4 m-tiles; grid y=8 (128 m-tiles), x = n-splits
  pcl_mfma3_kernel<<<dim3(256, 8), 256, 0, stream>>>(Zgu, E16u, NU / 16, 256, Su);
  pcl_mfma3_kernel<<<dim3(128, 8), 256, 0, stream>>>(Zgi, E16i, NI / 16, 128, Si);

  pclpos_kernel<<<BATCH / 4, 256, 0, stream>>>(Zu, Eu, uids, acc, 3);
  pclpos_kernel<<<BATCH / 4, 256, 0, stream>>>(Zi, Ev, iids, acc, 4);

  sumsq_kernel<<<1024, 256, 0, stream>>>(Eu0, NU * DD, acc, 7);
  sumsq_kernel<<<512, 256, 0, stream>>>(Ev0, NI * DD, acc, 8);
  sumsq_kernel<<<4, 256, 0, stream>>>(Eb, NBK * DD, acc, 9);

  finalize_kernel<<<1, 256, 0, stream>>>(Su, Si, acc, out);
}

// Round 7
// 1148.154 us; speedup vs baseline: 4.8049x; 1.0088x over previous
//
#include <hip/hip_runtime.h>
#include <stdint.h>

#define NU 100000
#define NI 50000
#define NBK 10
#define DD 64
#define NE 1000000
#define BATCH 2048
#define NSLICE 8
#define USLICE ((NU + NSLICE - 1) / NSLICE)   // 12500
#define ISLICE ((NI + NSLICE - 1) / NSLICE)   // 6250
#define NCHUNK 512
#define EPC ((NE + NCHUNK - 1) / NCHUNK)      // 1954

typedef __bf16 bf16x8 __attribute__((ext_vector_type(8)));
typedef float f32x4 __attribute__((ext_vector_type(4)));

struct Keys8 { uint32_t k[8][2]; };   // U:p0l0,p0l1,p1l0,p1l1 then I: same order

// ---------------- threefry2x32 (JAX-compatible, 20 rounds) ----------------
__host__ __device__ inline void tf2x32(uint32_t k0, uint32_t k1, uint32_t x0, uint32_t x1,
                                       uint32_t& o0, uint32_t& o1) {
  uint32_t ks0 = k0, ks1 = k1, ks2 = k0 ^ k1 ^ 0x1BD11BDAu;
  x0 += ks0; x1 += ks1;
#define TFR(r) { x0 += x1; x1 = (x1 << (r)) | (x1 >> (32 - (r))); x1 ^= x0; }
  TFR(13) TFR(15) TFR(26) TFR(6)   x0 += ks1; x1 += ks2 + 1u;
  TFR(17) TFR(29) TFR(16) TFR(24)  x0 += ks2; x1 += ks0 + 2u;
  TFR(13) TFR(15) TFR(26) TFR(6)   x0 += ks0; x1 += ks1 + 3u;
  TFR(17) TFR(29) TFR(16) TFR(24)  x0 += ks1; x1 += ks2 + 4u;
  TFR(13) TFR(15) TFR(26) TFR(6)   x0 += ks2; x1 += ks0 + 5u;
#undef TFR
  o0 = x0; o1 = x1;
}

__device__ inline uint16_t f2bf(float f) {
  uint32_t u = __float_as_uint(f);
  return (uint16_t)((u + 0x7fffu + ((u >> 16) & 1u)) >> 16);   // RNE
}
__device__ inline float bf2f(uint16_t u) {
  return __uint_as_float(((uint32_t)u) << 16);
}

__device__ inline uint32_t drop_mask(int e, uint32_t k0, uint32_t k1) {
  const uint32_t half = NE / 2;
  uint32_t lo = (e < (int)half) ? (uint32_t)e : (uint32_t)e - half;
  uint32_t o0, o1;
  tf2x32(k0, k1, lo, lo + half, o0, o1);
  uint32_t bits = (e < (int)half) ? o0 : o1;
  float u = __uint_as_float((bits >> 9) | 0x3f800000u) - 1.0f;
  return (u < 0.75f) ? 1u : 0u;
}

// all 8 dropout mask bits per edge, coalesced (bits 0-3 U p0l0..p1l1, 4-7 I)
__global__ void mask_kernel(uint8_t* __restrict__ mask, Keys8 K) {
  int e = blockIdx.x * blockDim.x + threadIdx.x;
  if (e >= NE) return;
  uint32_t m = 0;
#pragma unroll
  for (int j = 0; j < 8; ++j) m |= drop_mask(e, K.k[j][0], K.k[j][1]) << j;
  mask[e] = (uint8_t)m;
}

// ---------------- CSR build ----------------
__global__ void hist_kernel(const int* __restrict__ rows, const int* __restrict__ cols,
                            int* __restrict__ cntU, int* __restrict__ cntI) {
  int e = blockIdx.x * blockDim.x + threadIdx.x;
  if (e >= NE) return;
  atomicAdd(&cntU[rows[e]], 1);
  atomicAdd(&cntI[cols[e]], 1);
}

#define SCAN_B 256
// merged U+I block sums
__global__ void scan_phase1(const int* __restrict__ cntU, const int* __restrict__ cntI,
                            int nbU, int* __restrict__ bs) {
  __shared__ int red[SCAN_B];
  int blk = blockIdx.x, t = threadIdx.x;
  const int* cnt; int n, j;
  if (blk < nbU) { cnt = cntU; n = NU; j = blk; }
  else { cnt = cntI; n = NI; j = blk - nbU; }
  int i = j * SCAN_B + t;
  red[t] = (i < n) ? cnt[i] : 0;
  __syncthreads();
  for (int s = 128; s > 0; s >>= 1) {
    if (t < s) red[t] += red[t + s];
    __syncthreads();
  }
  if (t == 0) bs[blk] = red[0];
}
// one block scans both halves (nbU,nbI <= 512)
__global__ void scan_phase2(int* __restrict__ bs, int nbU, int nbI) {
  __shared__ int sh[512];
  int t = threadIdx.x;
  int v = (t < nbU) ? bs[t] : 0;
  sh[t] = v;
  __syncthreads();
  for (int off = 1; off < 512; off <<= 1) {
    int add = (t >= off) ? sh[t - off] : 0;
    __syncthreads();
    sh[t] += add;
    __syncthreads();
  }
  if (t < nbU) bs[t] = sh[t] - v;
  __syncthreads();
  int v2 = (t < nbI) ? bs[nbU + t] : 0;
  sh[t] = v2;
  __syncthreads();
  for (int off = 1; off < 512; off <<= 1) {
    int add = (t >= off) ? sh[t - off] : 0;
    __syncthreads();
    sh[t] += add;
    __syncthreads();
  }
  if (t < nbI) bs[nbU + t] = sh[t] - v2;
}
__global__ void scan_phase3(const int* __restrict__ cntU, const int* __restrict__ cntI,
                            int nbU, const int* __restrict__ bs,
                            int* __restrict__ offU, int* __restrict__ offI) {
  __shared__ int sh[SCAN_B];
  int blk = blockIdx.x, t = threadIdx.x;
  const int* cnt; int n, j; int* off;
  if (blk < nbU) { cnt = cntU; n = NU; j = blk; off = offU; }
  else { cnt = cntI; n = NI; j = blk - nbU; off = offI; }
  int i = j * SCAN_B + t;
  int v = (i < n) ? cnt[i] : 0;
  sh[t] = v;
  __syncthreads();
  for (int o = 1; o < SCAN_B; o <<= 1) {
    int add = (t >= o) ? sh[t - o] : 0;
    __syncthreads();
    sh[t] += add;
    __syncthreads();
  }
  if (i < n) off[i] = bs[blk] + sh[t] - v;
  if (i == n - 1) off[n] = bs[blk] + sh[t];
}

// XCD-sliced scatter: slice = blockIdx&7 (round-robin -> one XCD per slice);
// each slice owns a contiguous ~1/8 of cpU/cpI, so dirty lines live in ONE
// XCD's L2 (writeback once, not 8x). Mask bits packed into col high bits.
__global__ __launch_bounds__(256)
void scatter_kernel(const int* __restrict__ rows, const int* __restrict__ cols,
                    const uint8_t* __restrict__ mask,
                    const int* __restrict__ offU, const int* __restrict__ offI,
                    int* __restrict__ fillU, int* __restrict__ fillI,
                    int2* __restrict__ cpU, int2* __restrict__ cpI) {
  int slice = blockIdx.x & 7;
  int chunk = blockIdx.x >> 3;
  int base = chunk * EPC;
  int end = base + EPC; if (end > NE) end = NE;
  for (int e = base + threadIdx.x; e < end; e += 256) {
    int r = rows[e], c = cols[e];
    uint32_t m = mask[e];
    if (r / USLICE == slice) {
      int packed = c | (int)((m & 0xFu) << 17);
      int pu = offU[r] + atomicAdd(&fillU[r], 1);
      cpU[pu] = make_int2(packed, e);
    }
    if (c / ISLICE == slice) {
      int packed = r | (int)(((m >> 4) & 0xFu) << 17);
      int pi = offI[c] + atomicAdd(&fillI[c], 1);
      cpI[pi] = make_int2(packed, e);
    }
  }
}

// merged U+I gather-reduce SpMM over bf16 tables: one wave per output row.
// v_edge = esrc[e] * maskbit; 4/3 inverted-dropout scale folded at the end.
// Layer0 (D16): bf16 out + Sum = base + acc. Layer1: Sum += acc (+opt bf16 sum).
__global__ __launch_bounds__(256)
void spmm_layer_kernel(const int* __restrict__ offU, const int2* __restrict__ cpU,
                       const int* __restrict__ offI, const int2* __restrict__ cpI,
                       const float* __restrict__ esrc, int shift,
                       const uint16_t* __restrict__ SU, const uint16_t* __restrict__ SI,
                       uint16_t* __restrict__ dU, uint16_t* __restrict__ dI,
                       float* __restrict__ sumU, float* __restrict__ sumI,
                       const float* __restrict__ baseU, const float* __restrict__ baseI,
                       uint16_t* __restrict__ s16U, uint16_t* __restrict__ s16I) {
  int lane = threadIdx.x & 63;
  int r = (blockIdx.x * blockDim.x + threadIdx.x) >> 6;
  const int* off; const int2* cp; const uint16_t* S;
  uint16_t* D; float* Sum; const float* base; uint16_t* S16; int row;
  if (r < NU) {
    row = r; off = offU; cp = cpU; S = SU; D = dU; Sum = sumU; base = baseU; S16 = s16U;
  } else {
    row = r - NU; off = offI; cp = cpI; S = SI; D = dI; Sum = sumI; base = baseI; S16 = s16I;
  }
  int p0 = off[row], p1 = off[row + 1];
  float acc = 0.f;
  int p = p0;
  for (; p + 4 <= p1; p += 4) {          // 4 concurrent 128B row-gathers
    int2 c0 = cp[p], c1 = cp[p + 1], c2 = cp[p + 2], c3 = cp[p + 3];
    float v0 = esrc[c0.y] * (float)((c0.x >> shift) & 1);
    float v1 = esrc[c1.y] * (float)((c1.x >> shift) & 1);
    float v2 = esrc[c2.y] * (float)((c2.x >> shift) & 1);
    float v3 = esrc[c3.y] * (float)((c3.x >> shift) & 1);
    float s0 = bf2f(S[(size_t)(c0.x & 0x1FFFF) * DD + lane]);
    float s1 = bf2f(S[(size_t)(c1.x & 0x1FFFF) * DD + lane]);
    float s2 = bf2f(S[(size_t)(c2.x & 0x1FFFF) * DD + lane]);
    float s3 = bf2f(S[(size_t)(c3.x & 0x1FFFF) * DD + lane]);
    acc += v0 * s0 + v1 * s1 + v2 * s2 + v3 * s3;
  }
  for (; p < p1; ++p) {
    int2 cc = cp[p];
    float v = esrc[cc.y] * (float)((cc.x >> shift) & 1);
    if (v != 0.f) acc += v * bf2f(S[(size_t)(cc.x & 0x1FFFF) * DD + lane]);
  }
  acc *= (4.0f / 3.0f);                   // inverted-dropout rescale
  size_t idx = (size_t)row * DD + lane;
  if (D) {
    D[idx] = f2bf(acc);
    Sum[idx] = base[idx] + acc;
  } else {
    float s = Sum[idx] + acc;
    Sum[idx] = s;
    if (S16) S16[idx] = f2bf(s);
  }
}

// 4 edges per wave (16 lanes each, ushort4 over dims), bf16 tables
__global__ void edge_logit_kernel(const uint16_t* __restrict__ E16u,
                                  const uint16_t* __restrict__ E16i,
                                  const int* __restrict__ rows, const int* __restrict__ cols,
                                  const float* __restrict__ av, float* __restrict__ aug) {
  int lane = threadIdx.x & 63;
  int sub = lane >> 4, l15 = lane & 15;
  int w = (blockIdx.x * blockDim.x + threadIdx.x) >> 6;
  int nw = (gridDim.x * blockDim.x) >> 6;
  for (int b = w * 4; b < NE; b += nw * 4) {
    int e = b + sub;
    ushort4 a = *(const ushort4*)&E16u[(size_t)rows[e] * DD + l15 * 4];
    ushort4 c = *(const ushort4*)&E16i[(size_t)cols[e] * DD + l15 * 4];
    float p = bf2f(a.x) * bf2f(c.x) + bf2f(a.y) * bf2f(c.y) +
              bf2f(a.z) * bf2f(c.z) + bf2f(a.w) * bf2f(c.w);
#pragma unroll
    for (int off = 8; off > 0; off >>= 1) p += __shfl_down(p, off, 16);
    if (l15 == 0) aug[e] = av[e] / (1.0f + __expf(-p));
  }
}

// both base tables fp32 -> bf16 in one launch
__global__ void cvt2_bf16_kernel(const float4* __restrict__ a, int na4, uint2* __restrict__ oa,
                                 const float4* __restrict__ b, int nb4, uint2* __restrict__ ob) {
  int total = na4 + nb4;
  for (int i = blockIdx.x * blockDim.x + threadIdx.x; i < total; i += gridDim.x * blockDim.x) {
    float4 v = (i < na4) ? a[i] : b[i - na4];
    uint2 o;
    o.x = (uint32_t)f2bf(v.x) | ((uint32_t)f2bf(v.y) << 16);
    o.y = (uint32_t)f2bf(v.z) | ((uint32_t)f2bf(v.w) << 16);
    if (i < na4) oa[i] = o; else ob[i - na4] = o;
  }
}

// gather both Z row sets -> bf16 in one launch (grid = 2*BATCH, block = 64)
__global__ void gather2_bf16_kernel(const float* __restrict__ Zu, const int* __restrict__ uids,
                                    uint16_t* __restrict__ ou,
                                    const float* __restrict__ Zi, const int* __restrict__ iids,
                                    uint16_t* __restrict__ oi) {
  int b = blockIdx.x, lane = threadIdx.x;
  if (b < BATCH) ou[(size_t)b * 64 + lane] = f2bf(Zu[(size_t)uids[b] * 64 + lane]);
  else {
    int bb = b - BATCH;
    oi[(size_t)bb * 64 + lane] = f2bf(Zi[(size_t)iids[bb] * 64 + lane]);
  }
}

// PCL denominator: S[m] += sum_n exp(5*dot(Zg[m],E[n])), bf16 MFMA 16x16x32.
// Wave pins A-frags for 4 m-tiles (64 m-rows); per B-tile: 8 MFMA + 16 exp2.
__global__ __launch_bounds__(256)
void pcl_mfma3_kernel(const uint16_t* __restrict__ Zg, const uint16_t* __restrict__ E16,
                      int NT, int SPL, float* __restrict__ S) {
  int lane = threadIdx.x & 63;
  int wave = threadIdx.x >> 6;
  int quad = lane >> 4, l15 = lane & 15;
  int mt0 = (blockIdx.y * 4 + wave) * 4;
  bf16x8 a0[4], a1[4];
#pragma unroll
  for (int i = 0; i < 4; ++i) {
    const uint16_t* ar = Zg + (size_t)((mt0 + i) * 16 + l15) * 64 + quad * 8;
    a0[i] = *(const bf16x8*)ar;
    a1[i] = *(const bf16x8*)(ar + 32);
  }
  f32x4 rs[4] = {};
  int nt = blockIdx.x;
  bf16x8 b0 = {}, b1 = {};
  if (nt < NT) {
    const uint16_t* br = E16 + (size_t)(nt * 16 + l15) * 64 + quad * 8;
    b0 = *(const bf16x8*)br;
    b1 = *(const bf16x8*)(br + 32);
  }
  const float LOG2E5 = 7.2134752f;             // 5*log2(e): exp(5x)=2^(x*LOG2E5)
  while (nt < NT) {
    int nn = nt + SPL;
    bf16x8 p0 = {}, p1 = {};
    if (nn < NT) {
      const uint16_t* pr = E16 + (size_t)(nn * 16 + l15) * 64 + quad * 8;
      p0 = *(const bf16x8*)pr;
      p1 = *(const bf16x8*)(pr + 32);
    }
#pragma unroll
    for (int i = 0; i < 4; ++i) {
      f32x4 c = {0.f, 0.f, 0.f, 0.f};
      c = __builtin_amdgcn_mfma_f32_16x16x32_bf16(a0[i], b0, c, 0, 0, 0);
      c = __builtin_amdgcn_mfma_f32_16x16x32_bf16(a1[i], b1, c, 0, 0, 0);
#pragma unroll
      for (int r = 0; r < 4; ++r) rs[i][r] += __builtin_amdgcn_exp2f(c[r] * LOG2E5);
    }
    b0 = p0; b1 = p1; nt = nn;
  }
#pragma unroll
  for (int off = 8; off > 0; off >>= 1) {
#pragma unroll
    for (int i = 0; i < 4; ++i)
#pragma unroll
      for (int r = 0; r < 4; ++r) rs[i][r] += __shfl_down(rs[i][r], off, 16);
  }
  if (l15 == 0) {
#pragma unroll
    for (int i = 0; i < 4; ++i)
#pragma unroll
      for (int r = 0; r < 4; ++r)
        atomicAdd(&S[(mt0 + i) * 16 + quad * 4 + r], rs[i][r]);
  }
}

__global__ void bpr_kernel(const float* __restrict__ Eu, const float* __restrict__ Ev,
                           const int* __restrict__ uids, const int* __restrict__ pos,
                           const int* __restrict__ neg, float* __restrict__ ps,
                           float* __restrict__ acc) {
  int lane = threadIdx.x & 63;
  int b = (blockIdx.x * blockDim.x + threadIdx.x) >> 6;
  if (b >= BATCH) return;
  float u = Eu[(size_t)uids[b] * DD + lane];
  float p = u * Ev[(size_t)pos[b] * DD + lane];
  float n = u * Ev[(size_t)neg[b] * DD + lane];
#pragma unroll
  for (int off = 32; off > 0; off >>= 1) { p += __shfl_down(p, off); n += __shfl_down(n, off); }
  if (lane == 0) {
    ps[b] = p;
    float x = p - n;
    atomicAdd(&acc[0], logf(1.0f / (1.0f + __expf(-x))));
  }
}

__global__ void minmax_kernel(const float* __restrict__ ps, float* __restrict__ mm) {
  __shared__ float smn[256], smx[256];
  int tid = threadIdx.x;
  float mn = 3.0e38f, mx = -3.0e38f;
  for (int i = tid; i < BATCH; i += 256) { float v = ps[i]; mn = fminf(mn, v); mx = fmaxf(mx, v); }
  smn[tid] = mn; smx[tid] = mx;
  __syncthreads();
  for (int s = 128; s > 0; s >>= 1) {
    if (tid < s) { smn[tid] = fminf(smn[tid], smn[tid + s]); smx[tid] = fmaxf(smx[tid], smx[tid + s]); }
    __syncthreads();
  }
  if (tid == 0) { mm[0] = smn[0]; mm[1] = smx[0]; }
}

__global__ void bcl_kernel(const float* __restrict__ Eu, const float* __restrict__ Ev,
                           const float* __restrict__ Eb, const int* __restrict__ uids,
                           const int* __restrict__ pos, const float* __restrict__ ps,
                           const float* __restrict__ mm, float* __restrict__ acc) {
  int lane = threadIdx.x & 63;
  int b = (blockIdx.x * blockDim.x + threadIdx.x) >> 6;
  if (b >= BATCH) return;
  float wgt = (ps[b] - mm[0]) / (mm[1] - mm[0] + 1e-9f);
  int rel = (int)(wgt * 10.0f);
  rel = rel < 0 ? 0 : (rel > 9 ? 9 : rel);
  float el = 1.0f / (1.0f + __expf(-(Eu[(size_t)uids[b] * DD + lane] * Ev[(size_t)pos[b] * DD + lane])));
  float sneg = 0.f, spos = 0.f;
  for (int k = 0; k < NBK; ++k) {
    float d = el * Eb[k * DD + lane];
#pragma unroll
    for (int off = 32; off > 0; off >>= 1) d += __shfl_down(d, off);
    if (lane == 0) { if (k == rel) spos = d; else sneg += d; }
  }
  if (lane == 0) {
    atomicAdd(&acc[5], sneg * 0.1f);
    atomicAdd(&acc[6], spos);
  }
}

// both PCL positive terms in one launch (b < BATCH: U, else I)
__global__ void pclpos2_kernel(const float* __restrict__ Zu, const float* __restrict__ Eu,
                               const int* __restrict__ uids,
                               const float* __restrict__ Zi, const float* __restrict__ Ev,
                               const int* __restrict__ iids, float* __restrict__ acc) {
  int lane = threadIdx.x & 63;
  int b = (blockIdx.x * blockDim.x + threadIdx.x) >> 6;
  if (b >= 2 * BATCH) return;
  const float *Z, *E; const int* ids; int idx, bb;
  if (b < BATCH) { Z = Zu; E = Eu; ids = uids; idx = 3; bb = b; }
  else { Z = Zi; E = Ev; ids = iids; idx = 4; bb = b - BATCH; }
  size_t r = (size_t)ids[bb] * DD + lane;
  float p = Z[r] * E[r];
#pragma unroll
  for (int off = 32; off > 0; off >>= 1) p += __shfl_down(p, off);
  if (lane == 0) {
    float x = p * 5.0f;
    x = fminf(5.0f, fmaxf(-5.0f, x));
    atomicAdd(&acc[idx], x);
  }
}

// L2 reg over all three parameter tensors in one launch
__global__ void sumsq3_kernel(const float* __restrict__ a, int na,
                              const float* __restrict__ b, int nb,
                              const float* __restrict__ c, int nc,
                              float* __restrict__ acc) {
  __shared__ float red[256];
  int tid = threadIdx.x;
  int total = na + nb + nc;
  float s = 0.f;
  for (int i = blockIdx.x * blockDim.x + tid; i < total; i += gridDim.x * blockDim.x) {
    float v = (i < na) ? a[i] : (i < na + nb) ? b[i - na] : c[i - na - nb];
    s += v * v;
  }
  red[tid] = s;
  __syncthreads();
  for (int st = 128; st > 0; st >>= 1) {
    if (tid < st) red[tid] += red[tid + st];
    __syncthreads();
  }
  if (tid == 0) atomicAdd(&acc[7], red[0]);
}

__global__ void finalize_kernel(const float* __restrict__ Su, const float* __restrict__ Si,
                                const float* __restrict__ acc, float* __restrict__ out) {
  __shared__ float r1[256], r2[256];
  int tid = threadIdx.x;
  float su = 0.f, si = 0.f;
  for (int b = tid; b < BATCH; b += 256) {
    su += logf(Su[b] + 1e-8f);
    si += logf(Si[b] + 1e-8f);
  }
  r1[tid] = su; r2[tid] = si;
  __syncthreads();
  for (int s = 128; s > 0; s >>= 1) {
    if (tid < s) { r1[tid] += r1[tid + s]; r2[tid] += r2[tid + s]; }
    __syncthreads();
  }
  if (tid == 0) {
    const float inv = 1.0f / (float)BATCH;
    float neg_s = (r1[0] + r2[0]) * inv;
    float pos_s = (acc[3] + acc[4]) * inv;
    float pcl = neg_s - pos_s;
    float bpr = -acc[0] * inv;
    float bcl = (acc[5] - acc[6]) * inv;
    float reg = 1e-7f * acc[7];
    float loss = bpr + 0.2f * pcl + 0.2f * bcl + reg;
    out[0] = loss; out[1] = bpr; out[2] = 0.2f * pcl; out[3] = 0.2f * bcl;
  }
}

extern "C" void kernel_launch(void* const* d_in, const int* in_sizes, int n_in,
                              void* d_out, int out_size, void* d_ws, size_t ws_size,
                              hipStream_t stream) {
  (void)in_sizes; (void)n_in; (void)out_size; (void)ws_size;
  const float* Eu0 = (const float*)d_in[0];
  const float* Ev0 = (const float*)d_in[1];
  const float* Eb  = (const float*)d_in[2];
  const float* av  = (const float*)d_in[3];
  const int* rows  = (const int*)d_in[4];
  const int* cols  = (const int*)d_in[5];
  const int* uids  = (const int*)d_in[6];
  const int* iids  = (const int*)d_in[7];
  const int* pos   = (const int*)d_in[8];
  const int* neg   = (const int*)d_in[9];
  float* out = (float*)d_out;

  float* w = (float*)d_ws;
  size_t o = 0;
  float* Eu  = w + o; o += (size_t)NU * DD;   // E_u (prop-0 sums, fp32)
  float* Zu  = w + o; o += (size_t)NU * DD;
  float* Ev  = w + o; o += (size_t)NI * DD;
  float* Zi  = w + o; o += (size_t)NI * DD;
  float* augv = w + o; o += NE;
  float* ps  = w + o; o += BATCH;
  float* Su  = w + o; o += BATCH;
  float* Si  = w + o; o += BATCH;
  float* acc = w + o; o += 16;
  float* mm  = w + o; o += 2;
  // bf16 region (u16 units)
  uint16_t* hp = (uint16_t*)(w + o);
  uint16_t* E0u16 = hp; hp += (size_t)NU * DD;   // bf16(Eu0)
  uint16_t* E0v16 = hp; hp += (size_t)NI * DD;   // bf16(Ev0)
  uint16_t* d16U  = hp; hp += (size_t)NU * DD;   // layer0 U out (per prop)
  uint16_t* d16I  = hp; hp += (size_t)NI * DD;   // layer0 I out (per prop)
  uint16_t* E16u  = hp; hp += (size_t)NU * DD;   // bf16(E_u sums), by spmm epilogue
  uint16_t* E16i  = hp; hp += (size_t)NI * DD;
  uint16_t* Zgu   = hp; hp += (size_t)BATCH * DD;
  uint16_t* Zgi   = hp; hp += (size_t)BATCH * DD;
  uint8_t* mask8 = (uint8_t*)hp; hp += NE / 2;   // NE bytes
  // int region (8B aligned)
  int* ip = (int*)hp;
  if (((uintptr_t)ip) & 7) ip = (int*)(((uintptr_t)ip + 7) & ~(uintptr_t)7);
  int* offU = ip; ip += NU + 1;
  int* offI = ip; ip += NI + 1;
  int* cntU = ip; ip += NU;       // cntU/cntI adjacent: one memset covers both
  int* cntI = ip; ip += NI;
  ip += 2;                        // pad to 8B for int2
  int2* cpU = (int2*)ip; ip += 2 * (size_t)NE;
  int2* cpI = (int2*)ip; ip += 2 * (size_t)NE;

  // key chain: key(42) = (0,42); fold_in(k,d) = threefry2x32(k, [0,d])
  uint32_t bk[2][2];
  tf2x32(0u, 42u, 0u, 0u, bk[0][0], bk[0][1]);
  tf2x32(0u, 42u, 0u, 1u, bk[1][0], bk[1][1]);
  Keys8 K;
  // U-side: folds 0 (layer0) and 2 (layer1) per prop; I-side: folds 1 and 3
  for (int p = 0; p < 2; ++p)
    for (int l = 0; l < 2; ++l) {
      tf2x32(bk[p][0], bk[p][1], 0u, (uint32_t)(2 * l),     K.k[p * 2 + l][0], K.k[p * 2 + l][1]);
      tf2x32(bk[p][0], bk[p][1], 0u, (uint32_t)(2 * l + 1), K.k[4 + p * 2 + l][0], K.k[4 + p * 2 + l][1]);
    }

  const int EB = (NE + 255) / 256;
  const int nbU = (NU + SCAN_B - 1) / SCAN_B;   // 391
  const int nbI = (NI + SCAN_B - 1) / SCAN_B;   // 196

  // ---- base bf16 tables + dropout masks + CSR build ----
  cvt2_bf16_kernel<<<4096, 256, 0, stream>>>((const float4*)Eu0, NU * DD / 4, (uint2*)E0u16,
                                             (const float4*)Ev0, NI * DD / 4, (uint2*)E0v16);
  mask_kernel<<<EB, 256, 0, stream>>>(mask8, K);
  (void)hipMemsetAsync(cntU, 0, (size_t)(NU + NI) * sizeof(int), stream);
  hist_kernel<<<EB, 256, 0, stream>>>(rows, cols, cntU, cntI);
  {
    int* bs = (int*)cpU;                        // scratch (overwritten by scatter later)
    scan_phase1<<<nbU + nbI, SCAN_B, 0, stream>>>(cntU, cntI, nbU, bs);
    scan_phase2<<<1, 512, 0, stream>>>(bs, nbU, nbI);
    scan_phase3<<<nbU + nbI, SCAN_B, 0, stream>>>(cntU, cntI, nbU, bs, offU, offI);
  }
  (void)hipMemsetAsync(cntU, 0, (size_t)(NU + NI) * sizeof(int), stream);   // reuse as fill
  scatter_kernel<<<NCHUNK * NSLICE, 256, 0, stream>>>(rows, cols, mask8, offU, offI,
                                                      cntU, cntI, cpU, cpI);

  const int SPB = (NU + NI) / 4;   // merged spmm: (NU+NI) waves, 4/block

  // ---- propagation 0 (masks: bit17 layer0, bit18 layer1) ----
  spmm_layer_kernel<<<SPB, 256, 0, stream>>>(offU, cpU, offI, cpI, av, 17,
                                             E0v16, E0u16, d16U, d16I,
                                             Eu, Ev, Eu0, Ev0, nullptr, nullptr);
  spmm_layer_kernel<<<SPB, 256, 0, stream>>>(offU, cpU, offI, cpI, av, 18,
                                             d16I, d16U, nullptr, nullptr,
                                             Eu, Ev, nullptr, nullptr, E16u, E16i);

  edge_logit_kernel<<<4096, 256, 0, stream>>>(E16u, E16i, rows, cols, av, augv);

  // ---- propagation 1 (masks: bit19 layer0, bit20 layer1) ----
  spmm_layer_kernel<<<SPB, 256, 0, stream>>>(offU, cpU, offI, cpI, augv, 19,
                                             E0v16, E0u16, d16U, d16I,
                                             Zu, Zi, Eu0, Ev0, nullptr, nullptr);
  spmm_layer_kernel<<<SPB, 256, 0, stream>>>(offU, cpU, offI, cpI, augv, 20,
                                             d16I, d16U, nullptr, nullptr,
                                             Zu, Zi, nullptr, nullptr, nullptr, nullptr);

  gather2_bf16_kernel<<<2 * BATCH, 64, 0, stream>>>(Zu, uids, Zgu, Zi, iids, Zgi);

  (void)hipMemsetAsync(Su, 0, (2 * BATCH + 16) * sizeof(float), stream);   // Su,Si,acc adjacent

  bpr_kernel<<<BATCH / 4, 256, 0, stream>>>(Eu, Ev, uids, pos, neg, ps, acc);
  minmax_kernel<<<1, 256, 0, stream>>>(ps, mm);
  bcl_kernel<<<BATCH / 4, 256, 0, stream>>>(Eu, Ev, Eb, uids, pos, ps, mm, acc);

  // PCL denominators: wave = 4 m-tiles; grid y=8 (128 m-tiles), x = n-splits
  pcl_mfma3_kernel<<<dim3(256, 8), 256, 0, stream>>>(Zgu, E16u, NU / 16, 256, Su);
  pcl_mfma3_kernel<<<dim3(128, 8), 256, 0, stream>>>(Zgi, E16i, NI / 16, 128, Si);

  pclpos2_kernel<<<2 * BATCH / 4, 256, 0, stream>>>(Zu, Eu, uids, Zi, Ev, iids, acc);

  sumsq3_kernel<<<1024, 256, 0, stream>>>(Eu0, NU * DD, Ev0, NI * DD, Eb, NBK * DD, acc);

  finalize_kernel<<<1, 256, 0, stream>>>(Su, Si, acc, out);
}

// Round 8
// 1083.596 us; speedup vs baseline: 5.0912x; 1.0596x over previous
//
#include <hip/hip_runtime.h>
#include <stdint.h>

#define NU 100000
#define NI 50000
#define NBK 10
#define DD 64
#define NE 1000000
#define BATCH 2048
#define NSLICE 8
#define USLICE ((NU + NSLICE - 1) / NSLICE)   // 12500
#define ISLICE ((NI + NSLICE - 1) / NSLICE)   // 6250
#define NCHUNK 512
#define EPC ((NE + NCHUNK - 1) / NCHUNK)      // 1954
// fp8 storage scale: embeddings ~0.01 are subnormal in e4m3; x128 -> normal range.
// Combined descale: (4/3 dropout) / 128 = 1/96.
#define FP8_SCALE 128.0f
#define SPMM_DESCALE (1.0f / 96.0f)

typedef __bf16 bf16x8 __attribute__((ext_vector_type(8)));
typedef float f32x4 __attribute__((ext_vector_type(4)));

struct Keys8 { uint32_t k[8][2]; };   // U:p0l0,p0l1,p1l0,p1l1 then I: same order

// ---------------- threefry2x32 (JAX-compatible, 20 rounds) ----------------
__host__ __device__ inline void tf2x32(uint32_t k0, uint32_t k1, uint32_t x0, uint32_t x1,
                                       uint32_t& o0, uint32_t& o1) {
  uint32_t ks0 = k0, ks1 = k1, ks2 = k0 ^ k1 ^ 0x1BD11BDAu;
  x0 += ks0; x1 += ks1;
#define TFR(r) { x0 += x1; x1 = (x1 << (r)) | (x1 >> (32 - (r))); x1 ^= x0; }
  TFR(13) TFR(15) TFR(26) TFR(6)   x0 += ks1; x1 += ks2 + 1u;
  TFR(17) TFR(29) TFR(16) TFR(24)  x0 += ks2; x1 += ks0 + 2u;
  TFR(13) TFR(15) TFR(26) TFR(6)   x0 += ks0; x1 += ks1 + 3u;
  TFR(17) TFR(29) TFR(16) TFR(24)  x0 += ks1; x1 += ks2 + 4u;
  TFR(13) TFR(15) TFR(26) TFR(6)   x0 += ks2; x1 += ks0 + 5u;
#undef TFR
  o0 = x0; o1 = x1;
}

__device__ inline uint16_t f2bf(float f) {
  uint32_t u = __float_as_uint(f);
  return (uint16_t)((u + 0x7fffu + ((u >> 16) & 1u)) >> 16);   // RNE
}
__device__ inline float bf2f(uint16_t u) {
  return __uint_as_float(((uint32_t)u) << 16);
}

// ---- fp8 e4m3 (OCP) helpers ----
__device__ inline float fp8_to_f32(uint32_t b) {
#if __has_builtin(__builtin_amdgcn_cvt_f32_fp8)
  return __builtin_amdgcn_cvt_f32_fp8(b, 0);
#else
  uint32_t s = b >> 7, e = (b >> 3) & 0xF, m = b & 7;
  float v = (e == 0) ? (float)m * (1.0f / 512.0f)
                     : __uint_as_float(((e + 120) << 23) | (m << 20));
  return s ? -v : v;
#endif
}
__device__ inline uint32_t f32_to_fp8(float f) {
#if __has_builtin(__builtin_amdgcn_cvt_pk_fp8_f32)
  return (uint32_t)__builtin_amdgcn_cvt_pk_fp8_f32(f, f, 0, false) & 0xFFu;
#else
  uint32_t s = (__float_as_uint(f) >> 31) << 7;
  float a = fabsf(f);
  a = fminf(a, 448.0f);
  if (a < 0.015625f) {                          // subnormal: quantum 2^-9
    uint32_t m = (uint32_t)(a * 512.0f + 0.5f);
    return s | m;                               // m==8 rolls into e=1,m=0 correctly
  }
  int ex; float fr = frexpf(a, &ex);            // a = fr*2^ex, fr in [0.5,1)
  uint32_t q = (uint32_t)(fr * 16.0f + 0.5f);   // [8,16]
  int E = ex + 6;
  if (q == 16) { q = 8; E += 1; }
  if (E > 15) { E = 15; q = 14; }
  if (E == 15 && q == 15) q = 14;               // avoid NaN encoding
  return s | ((uint32_t)E << 3) | (q - 8);
#endif
}

__device__ inline uint32_t drop_mask(int e, uint32_t k0, uint32_t k1) {
  const uint32_t half = NE / 2;
  uint32_t lo = (e < (int)half) ? (uint32_t)e : (uint32_t)e - half;
  uint32_t o0, o1;
  tf2x32(k0, k1, lo, lo + half, o0, o1);
  uint32_t bits = (e < (int)half) ? o0 : o1;
  float u = __uint_as_float((bits >> 9) | 0x3f800000u) - 1.0f;
  return (u < 0.75f) ? 1u : 0u;
}

// dropout masks (8 bits/edge) + degree histogram, single pass over edges
__global__ void mask_hist_kernel(const int* __restrict__ rows, const int* __restrict__ cols,
                                 uint8_t* __restrict__ mask,
                                 int* __restrict__ cntU, int* __restrict__ cntI, Keys8 K) {
  int e = blockIdx.x * blockDim.x + threadIdx.x;
  if (e >= NE) return;
  uint32_t m = 0;
#pragma unroll
  for (int j = 0; j < 8; ++j) m |= drop_mask(e, K.k[j][0], K.k[j][1]) << j;
  mask[e] = (uint8_t)m;
  atomicAdd(&cntU[rows[e]], 1);
  atomicAdd(&cntI[cols[e]], 1);
}

#define SCAN_B 256
__global__ void scan_phase1(const int* __restrict__ cntU, const int* __restrict__ cntI,
                            int nbU, int* __restrict__ bs) {
  __shared__ int red[SCAN_B];
  int blk = blockIdx.x, t = threadIdx.x;
  const int* cnt; int n, j;
  if (blk < nbU) { cnt = cntU; n = NU; j = blk; }
  else { cnt = cntI; n = NI; j = blk - nbU; }
  int i = j * SCAN_B + t;
  red[t] = (i < n) ? cnt[i] : 0;
  __syncthreads();
  for (int s = 128; s > 0; s >>= 1) {
    if (t < s) red[t] += red[t + s];
    __syncthreads();
  }
  if (t == 0) bs[blk] = red[0];
}
__global__ void scan_phase2(int* __restrict__ bs, int nbU, int nbI) {
  __shared__ int sh[512];
  int t = threadIdx.x;
  int v = (t < nbU) ? bs[t] : 0;
  sh[t] = v;
  __syncthreads();
  for (int off = 1; off < 512; off <<= 1) {
    int add = (t >= off) ? sh[t - off] : 0;
    __syncthreads();
    sh[t] += add;
    __syncthreads();
  }
  if (t < nbU) bs[t] = sh[t] - v;
  __syncthreads();
  int v2 = (t < nbI) ? bs[nbU + t] : 0;
  sh[t] = v2;
  __syncthreads();
  for (int off = 1; off < 512; off <<= 1) {
    int add = (t >= off) ? sh[t - off] : 0;
    __syncthreads();
    sh[t] += add;
    __syncthreads();
  }
  if (t < nbI) bs[nbU + t] = sh[t] - v2;
}
__global__ void scan_phase3(const int* __restrict__ cntU, const int* __restrict__ cntI,
                            int nbU, const int* __restrict__ bs,
                            int* __restrict__ offU, int* __restrict__ offI) {
  __shared__ int sh[SCAN_B];
  int blk = blockIdx.x, t = threadIdx.x;
  const int* cnt; int n, j; int* off;
  if (blk < nbU) { cnt = cntU; n = NU; j = blk; off = offU; }
  else { cnt = cntI; n = NI; j = blk - nbU; off = offI; }
  int i = j * SCAN_B + t;
  int v = (i < n) ? cnt[i] : 0;
  sh[t] = v;
  __syncthreads();
  for (int o = 1; o < SCAN_B; o <<= 1) {
    int add = (t >= o) ? sh[t - o] : 0;
    __syncthreads();
    sh[t] += add;
    __syncthreads();
  }
  if (i < n) off[i] = bs[blk] + sh[t] - v;
  if (i == n - 1) off[n] = bs[blk] + sh[t];
}

// XCD-sliced scatter (slice = blockIdx&7): each output slice dirtied by one XCD.
// Mask bits packed into col high bits (col <= 17 bits).
__global__ __launch_bounds__(256)
void scatter_kernel(const int* __restrict__ rows, const int* __restrict__ cols,
                    const uint8_t* __restrict__ mask,
                    const int* __restrict__ offU, const int* __restrict__ offI,
                    int* __restrict__ fillU, int* __restrict__ fillI,
                    int2* __restrict__ cpU, int2* __restrict__ cpI) {
  int slice = blockIdx.x & 7;
  int chunk = blockIdx.x >> 3;
  int base = chunk * EPC;
  int end = base + EPC; if (end > NE) end = NE;
  for (int e = base + threadIdx.x; e < end; e += 256) {
    int r = rows[e], c = cols[e];
    uint32_t m = mask[e];
    if (r / USLICE == slice) {
      int packed = c | (int)((m & 0xFu) << 17);
      int pu = offU[r] + atomicAdd(&fillU[r], 1);
      cpU[pu] = make_int2(packed, e);
    }
    if (c / ISLICE == slice) {
      int packed = r | (int)(((m >> 4) & 0xFu) << 17);
      int pi = offI[c] + atomicAdd(&fillI[c], 1);
      cpI[pi] = make_int2(packed, e);
    }
  }
}

// merged U+I gather-reduce SpMM over fp8 tables (64B rows): one wave/output row.
// Tables store value*128; descale (4/3)/128 folded once per row.
// layer0 (base != null): d8 out = fp8(raw*4/3) [=128x true out], sum16 = bf16(base + raw/96)
// layer1: sum16 = bf16(bf2f(sum16) + raw/96)
__global__ __launch_bounds__(256)
void spmm_layer_kernel(const int* __restrict__ offU, const int2* __restrict__ cpU,
                       const int* __restrict__ offI, const int2* __restrict__ cpI,
                       const float* __restrict__ esrc, int shift,
                       const uint8_t* __restrict__ SU, const uint8_t* __restrict__ SI,
                       uint8_t* __restrict__ dU, uint8_t* __restrict__ dI,
                       uint16_t* __restrict__ sumU, uint16_t* __restrict__ sumI,
                       const float* __restrict__ baseU, const float* __restrict__ baseI) {
  int lane = threadIdx.x & 63;
  int r = (blockIdx.x * blockDim.x + threadIdx.x) >> 6;
  const int* off; const int2* cp; const uint8_t* S;
  uint8_t* D; uint16_t* Sum; const float* base; int row;
  if (r < NU) {
    row = r; off = offU; cp = cpU; S = SU; D = dU; Sum = sumU; base = baseU;
  } else {
    row = r - NU; off = offI; cp = cpI; S = SI; D = dI; Sum = sumI; base = baseI;
  }
  int p0 = off[row], p1 = off[row + 1];
  float acc = 0.f;
  int p = p0;
  for (; p + 4 <= p1; p += 4) {          // 4 concurrent 64B row-gathers
    int2 c0 = cp[p], c1 = cp[p + 1], c2 = cp[p + 2], c3 = cp[p + 3];
    float v0 = esrc[c0.y] * (float)((c0.x >> shift) & 1);
    float v1 = esrc[c1.y] * (float)((c1.x >> shift) & 1);
    float v2 = esrc[c2.y] * (float)((c2.x >> shift) & 1);
    float v3 = esrc[c3.y] * (float)((c3.x >> shift) & 1);
    float s0 = fp8_to_f32(S[(size_t)(c0.x & 0x1FFFF) * DD + lane]);
    float s1 = fp8_to_f32(S[(size_t)(c1.x & 0x1FFFF) * DD + lane]);
    float s2 = fp8_to_f32(S[(size_t)(c2.x & 0x1FFFF) * DD + lane]);
    float s3 = fp8_to_f32(S[(size_t)(c3.x & 0x1FFFF) * DD + lane]);
    acc += v0 * s0 + v1 * s1 + v2 * s2 + v3 * s3;
  }
  for (; p < p1; ++p) {
    int2 cc = cp[p];
    float v = esrc[cc.y] * (float)((cc.x >> shift) & 1);
    if (v != 0.f) acc += v * fp8_to_f32(S[(size_t)(cc.x & 0x1FFFF) * DD + lane]);
  }
  size_t idx = (size_t)row * DD + lane;
  if (D) {
    D[idx] = (uint8_t)f32_to_fp8(acc * (4.0f / 3.0f));
    Sum[idx] = f2bf(base[idx] + acc * SPMM_DESCALE);
  } else {
    Sum[idx] = f2bf(bf2f(Sum[idx]) + acc * SPMM_DESCALE);
  }
}

// 4 edges per wave (16 lanes each, ushort4 over dims), bf16 tables
__global__ void edge_logit_kernel(const uint16_t* __restrict__ E16u,
                                  const uint16_t* __restrict__ E16i,
                                  const int* __restrict__ rows, const int* __restrict__ cols,
                                  const float* __restrict__ av, float* __restrict__ aug) {
  int lane = threadIdx.x & 63;
  int sub = lane >> 4, l15 = lane & 15;
  int w = (blockIdx.x * blockDim.x + threadIdx.x) >> 6;
  int nw = (gridDim.x * blockDim.x) >> 6;
  for (int b = w * 4; b < NE; b += nw * 4) {
    int e = b + sub;
    ushort4 a = *(const ushort4*)&E16u[(size_t)rows[e] * DD + l15 * 4];
    ushort4 c = *(const ushort4*)&E16i[(size_t)cols[e] * DD + l15 * 4];
    float p = bf2f(a.x) * bf2f(c.x) + bf2f(a.y) * bf2f(c.y) +
              bf2f(a.z) * bf2f(c.z) + bf2f(a.w) * bf2f(c.w);
#pragma unroll
    for (int off = 8; off > 0; off >>= 1) p += __shfl_down(p, off, 16);
    if (l15 == 0) aug[e] = av[e] / (1.0f + __expf(-p));
  }
}

// both base tables fp32 -> fp8(x128) in one launch, 4 elems/thread
__global__ void cvt2_fp8_kernel(const float4* __restrict__ a, int na4, uint32_t* __restrict__ oa,
                                const float4* __restrict__ b, int nb4, uint32_t* __restrict__ ob) {
  int total = na4 + nb4;
  for (int i = blockIdx.x * blockDim.x + threadIdx.x; i < total; i += gridDim.x * blockDim.x) {
    float4 v = (i < na4) ? a[i] : b[i - na4];
    uint32_t w = f32_to_fp8(v.x * FP8_SCALE) | (f32_to_fp8(v.y * FP8_SCALE) << 8) |
                 (f32_to_fp8(v.z * FP8_SCALE) << 16) | (f32_to_fp8(v.w * FP8_SCALE) << 24);
    if (i < na4) oa[i] = w; else ob[i - na4] = w;
  }
}

// gather both Z row sets (bf16 tables, direct u16 copy)
__global__ void gather2_rows_kernel(const uint16_t* __restrict__ Z16u, const int* __restrict__ uids,
                                    uint16_t* __restrict__ ou,
                                    const uint16_t* __restrict__ Z16i, const int* __restrict__ iids,
                                    uint16_t* __restrict__ oi) {
  int b = blockIdx.x, lane = threadIdx.x;
  if (b < BATCH) ou[(size_t)b * 64 + lane] = Z16u[(size_t)uids[b] * 64 + lane];
  else {
    int bb = b - BATCH;
    oi[(size_t)bb * 64 + lane] = Z16i[(size_t)iids[bb] * 64 + lane];
  }
}

// PCL denominator: S[m] += sum_n exp(5*dot(Zg[m],E[n])), bf16 MFMA 16x16x32.
// Wave pins A-frags for 4 m-tiles (64 m-rows); per B-tile: 8 MFMA + 16 exp2.
__global__ __launch_bounds__(256)
void pcl_mfma3_kernel(const uint16_t* __restrict__ Zg, const uint16_t* __restrict__ E16,
                      int NT, int SPL, float* __restrict__ S) {
  int lane = threadIdx.x & 63;
  int wave = threadIdx.x >> 6;
  int quad = lane >> 4, l15 = lane & 15;
  int mt0 = (blockIdx.y * 4 + wave) * 4;
  bf16x8 a0[4], a1[4];
#pragma unroll
  for (int i = 0; i < 4; ++i) {
    const uint16_t* ar = Zg + (size_t)((mt0 + i) * 16 + l15) * 64 + quad * 8;
    a0[i] = *(const bf16x8*)ar;
    a1[i] = *(const bf16x8*)(ar + 32);
  }
  f32x4 rs[4] = {};
  int nt = blockIdx.x;
  bf16x8 b0 = {}, b1 = {};
  if (nt < NT) {
    const uint16_t* br = E16 + (size_t)(nt * 16 + l15) * 64 + quad * 8;
    b0 = *(const bf16x8*)br;
    b1 = *(const bf16x8*)(br + 32);
  }
  const float LOG2E5 = 7.2134752f;             // 5*log2(e): exp(5x)=2^(x*LOG2E5)
  while (nt < NT) {
    int nn = nt + SPL;
    bf16x8 p0 = {}, p1 = {};
    if (nn < NT) {
      const uint16_t* pr = E16 + (size_t)(nn * 16 + l15) * 64 + quad * 8;
      p0 = *(const bf16x8*)pr;
      p1 = *(const bf16x8*)(pr + 32);
    }
#pragma unroll
    for (int i = 0; i < 4; ++i) {
      f32x4 c = {0.f, 0.f, 0.f, 0.f};
      c = __builtin_amdgcn_mfma_f32_16x16x32_bf16(a0[i], b0, c, 0, 0, 0);
      c = __builtin_amdgcn_mfma_f32_16x16x32_bf16(a1[i], b1, c, 0, 0, 0);
#pragma unroll
      for (int r = 0; r < 4; ++r) rs[i][r] += __builtin_amdgcn_exp2f(c[r] * LOG2E5);
    }
    b0 = p0; b1 = p1; nt = nn;
  }
#pragma unroll
  for (int off = 8; off > 0; off >>= 1) {
#pragma unroll
    for (int i = 0; i < 4; ++i)
#pragma unroll
      for (int r = 0; r < 4; ++r) rs[i][r] += __shfl_down(rs[i][r], off, 16);
  }
  if (l15 == 0) {
#pragma unroll
    for (int i = 0; i < 4; ++i)
#pragma unroll
      for (int r = 0; r < 4; ++r)
        atomicAdd(&S[(mt0 + i) * 16 + quad * 4 + r], rs[i][r]);
  }
}

__global__ void bpr_kernel(const uint16_t* __restrict__ E16u, const uint16_t* __restrict__ E16i,
                           const int* __restrict__ uids, const int* __restrict__ pos,
                           const int* __restrict__ neg, float* __restrict__ ps,
                           float* __restrict__ acc) {
  int lane = threadIdx.x & 63;
  int b = (blockIdx.x * blockDim.x + threadIdx.x) >> 6;
  if (b >= BATCH) return;
  float u = bf2f(E16u[(size_t)uids[b] * DD + lane]);
  float p = u * bf2f(E16i[(size_t)pos[b] * DD + lane]);
  float n = u * bf2f(E16i[(size_t)neg[b] * DD + lane]);
#pragma unroll
  for (int off = 32; off > 0; off >>= 1) { p += __shfl_down(p, off); n += __shfl_down(n, off); }
  if (lane == 0) {
    ps[b] = p;
    float x = p - n;
    atomicAdd(&acc[0], logf(1.0f / (1.0f + __expf(-x))));
  }
}

__global__ void minmax_kernel(const float* __restrict__ ps, float* __restrict__ mm) {
  __shared__ float smn[256], smx[256];
  int tid = threadIdx.x;
  float mn = 3.0e38f, mx = -3.0e38f;
  for (int i = tid; i < BATCH; i += 256) { float v = ps[i]; mn = fminf(mn, v); mx = fmaxf(mx, v); }
  smn[tid] = mn; smx[tid] = mx;
  __syncthreads();
  for (int s = 128; s > 0; s >>= 1) {
    if (tid < s) { smn[tid] = fminf(smn[tid], smn[tid + s]); smx[tid] = fmaxf(smx[tid], smx[tid + s]); }
    __syncthreads();
  }
  if (tid == 0) { mm[0] = smn[0]; mm[1] = smx[0]; }
}

__global__ void bcl_kernel(const uint16_t* __restrict__ E16u, const uint16_t* __restrict__ E16i,
                           const float* __restrict__ Eb, const int* __restrict__ uids,
                           const int* __restrict__ pos, const float* __restrict__ ps,
                           const float* __restrict__ mm, float* __restrict__ acc) {
  int lane = threadIdx.x & 63;
  int b = (blockIdx.x * blockDim.x + threadIdx.x) >> 6;
  if (b >= BATCH) return;
  float wgt = (ps[b] - mm[0]) / (mm[1] - mm[0] + 1e-9f);
  int rel = (int)(wgt * 10.0f);
  rel = rel < 0 ? 0 : (rel > 9 ? 9 : rel);
  float x = bf2f(E16u[(size_t)uids[b] * DD + lane]) * bf2f(E16i[(size_t)pos[b] * DD + lane]);
  float el = 1.0f / (1.0f + __expf(-x));
  float sneg = 0.f, spos = 0.f;
  for (int k = 0; k < NBK; ++k) {
    float d = el * Eb[k * DD + lane];
#pragma unroll
    for (int off = 32; off > 0; off >>= 1) d += __shfl_down(d, off);
    if (lane == 0) { if (k == rel) spos = d; else sneg += d; }
  }
  if (lane == 0) {
    atomicAdd(&acc[5], sneg * 0.1f);
    atomicAdd(&acc[6], spos);
  }
}

// both PCL positive terms in one launch (b < BATCH: U, else I), bf16 tables
__global__ void pclpos2_kernel(const uint16_t* __restrict__ Z16u, const uint16_t* __restrict__ E16u,
                               const int* __restrict__ uids,
                               const uint16_t* __restrict__ Z16i, const uint16_t* __restrict__ E16i,
                               const int* __restrict__ iids, float* __restrict__ acc) {
  int lane = threadIdx.x & 63;
  int b = (blockIdx.x * blockDim.x + threadIdx.x) >> 6;
  if (b >= 2 * BATCH) return;
  const uint16_t *Z, *E; const int* ids; int idx, bb;
  if (b < BATCH) { Z = Z16u; E = E16u; ids = uids; idx = 3; bb = b; }
  else { Z = Z16i; E = E16i; ids = iids; idx = 4; bb = b - BATCH; }
  size_t r = (size_t)ids[bb] * DD + lane;
  float p = bf2f(Z[r]) * bf2f(E[r]);
#pragma unroll
  for (int off = 32; off > 0; off >>= 1) p += __shfl_down(p, off);
  if (lane == 0) {
    float x = p * 5.0f;
    x = fminf(5.0f, fmaxf(-5.0f, x));
    atomicAdd(&acc[idx], x);
  }
}

// L2 reg over all three parameter tensors in one launch
__global__ void sumsq3_kernel(const float* __restrict__ a, int na,
                              const float* __restrict__ b, int nb,
                              const float* __restrict__ c, int nc,
                              float* __restrict__ acc) {
  __shared__ float red[256];
  int tid = threadIdx.x;
  int total = na + nb + nc;
  float s = 0.f;
  for (int i = blockIdx.x * blockDim.x + tid; i < total; i += gridDim.x * blockDim.x) {
    float v = (i < na) ? a[i] : (i < na + nb) ? b[i - na] : c[i - na - nb];
    s += v * v;
  }
  red[tid] = s;
  __syncthreads();
  for (int st = 128; st > 0; st >>= 1) {
    if (tid < st) red[tid] += red[tid + st];
    __syncthreads();
  }
  if (tid == 0) atomicAdd(&acc[7], red[0]);
}

__global__ void finalize_kernel(const float* __restrict__ Su, const float* __restrict__ Si,
                                const float* __restrict__ acc, float* __restrict__ out) {
  __shared__ float r1[256], r2[256];
  int tid = threadIdx.x;
  float su = 0.f, si = 0.f;
  for (int b = tid; b < BATCH; b += 256) {
    su += logf(Su[b] + 1e-8f);
    si += logf(Si[b] + 1e-8f);
  }
  r1[tid] = su; r2[tid] = si;
  __syncthreads();
  for (int s = 128; s > 0; s >>= 1) {
    if (tid < s) { r1[tid] += r1[tid + s]; r2[tid] += r2[tid + s]; }
    __syncthreads();
  }
  if (tid == 0) {
    const float inv = 1.0f / (float)BATCH;
    float neg_s = (r1[0] + r2[0]) * inv;
    float pos_s = (acc[3] + acc[4]) * inv;
    float pcl = neg_s - pos_s;
    float bpr = -acc[0] * inv;
    float bcl = (acc[5] - acc[6]) * inv;
    float reg = 1e-7f * acc[7];
    float loss = bpr + 0.2f * pcl + 0.2f * bcl + reg;
    out[0] = loss; out[1] = bpr; out[2] = 0.2f * pcl; out[3] = 0.2f * bcl;
  }
}

extern "C" void kernel_launch(void* const* d_in, const int* in_sizes, int n_in,
                              void* d_out, int out_size, void* d_ws, size_t ws_size,
                              hipStream_t stream) {
  (void)in_sizes; (void)n_in; (void)out_size; (void)ws_size;
  const float* Eu0 = (const float*)d_in[0];
  const float* Ev0 = (const float*)d_in[1];
  const float* Eb  = (const float*)d_in[2];
  const float* av  = (const float*)d_in[3];
  const int* rows  = (const int*)d_in[4];
  const int* cols  = (const int*)d_in[5];
  const int* uids  = (const int*)d_in[6];
  const int* iids  = (const int*)d_in[7];
  const int* pos   = (const int*)d_in[8];
  const int* neg   = (const int*)d_in[9];
  float* out = (float*)d_out;

  float* w = (float*)d_ws;
  size_t o = 0;
  float* augv = w + o; o += NE;
  float* ps  = w + o; o += BATCH;
  float* Su  = w + o; o += BATCH;
  float* Si  = w + o; o += BATCH;
  float* acc = w + o; o += 16;
  float* mm  = w + o; o += 2;
  // bf16 running-sum tables + gathered Z rows (u16 units)
  uint16_t* hp = (uint16_t*)(w + o);
  uint16_t* E16u = hp; hp += (size_t)NU * DD;   // E_u sums (bf16)
  uint16_t* E16i = hp; hp += (size_t)NI * DD;
  uint16_t* Z16u = hp; hp += (size_t)NU * DD;   // Z_u sums (bf16)
  uint16_t* Z16i = hp; hp += (size_t)NI * DD;
  uint16_t* Zgu  = hp; hp += (size_t)BATCH * DD;
  uint16_t* Zgi  = hp; hp += (size_t)BATCH * DD;
  // fp8 tables
  uint8_t* bp = (uint8_t*)hp;
  uint8_t* E0u8 = bp; bp += (size_t)NU * DD;    // fp8(128*Eu0)
  uint8_t* E0v8 = bp; bp += (size_t)NI * DD;
  uint8_t* d8U  = bp; bp += (size_t)NU * DD;    // layer0 outs (fp8, 128x)
  uint8_t* d8I  = bp; bp += (size_t)NI * DD;
  uint8_t* mask8 = bp; bp += NE;
  // int region (8B aligned)
  int* ip = (int*)(((uintptr_t)bp + 7) & ~(uintptr_t)7);
  int* offU = ip; ip += NU + 1;
  int* offI = ip; ip += NI + 1;
  int* cntU = ip; ip += NU;       // cntU/cntI adjacent: one memset covers both
  int* cntI = ip; ip += NI;
  ip += 2;                        // pad to 8B for int2
  int2* cpU = (int2*)ip; ip += 2 * (size_t)NE;
  int2* cpI = (int2*)ip; ip += 2 * (size_t)NE;

  // key chain: key(42) = (0,42); fold_in(k,d) = threefry2x32(k, [0,d])
  uint32_t bk[2][2];
  tf2x32(0u, 42u, 0u, 0u, bk[0][0], bk[0][1]);
  tf2x32(0u, 42u, 0u, 1u, bk[1][0], bk[1][1]);
  Keys8 K;
  // U-side uses folds 0 (layer0) / 2 (layer1); I-side folds 1 / 3
  for (int p = 0; p < 2; ++p)
    for (int l = 0; l < 2; ++l) {
      tf2x32(bk[p][0], bk[p][1], 0u, (uint32_t)(2 * l),     K.k[p * 2 + l][0], K.k[p * 2 + l][1]);
      tf2x32(bk[p][0], bk[p][1], 0u, (uint32_t)(2 * l + 1), K.k[4 + p * 2 + l][0], K.k[4 + p * 2 + l][1]);
    }

  const int EB = (NE + 255) / 256;
  const int nbU = (NU + SCAN_B - 1) / SCAN_B;   // 391
  const int nbI = (NI + SCAN_B - 1) / SCAN_B;   // 196

  // ---- fp8 base tables + masks/hist + CSR build ----
  cvt2_fp8_kernel<<<2048, 256, 0, stream>>>((const float4*)Eu0, NU * DD / 4, (uint32_t*)E0u8,
                                            (const float4*)Ev0, NI * DD / 4, (uint32_t*)E0v8);
  (void)hipMemsetAsync(cntU, 0, (size_t)(NU + NI) * sizeof(int), stream);
  mask_hist_kernel<<<EB, 256, 0, stream>>>(rows, cols, mask8, cntU, cntI, K);
  {
    int* bs = (int*)cpU;                        // scratch (overwritten by scatter later)
    scan_phase1<<<nbU + nbI, SCAN_B, 0, stream>>>(cntU, cntI, nbU, bs);
    scan_phase2<<<1, 512, 0, stream>>>(bs, nbU, nbI);
    scan_phase3<<<nbU + nbI, SCAN_B, 0, stream>>>(cntU, cntI, nbU, bs, offU, offI);
  }
  (void)hipMemsetAsync(cntU, 0, (size_t)(NU + NI) * sizeof(int), stream);   // reuse as fill
  scatter_kernel<<<NCHUNK * NSLICE, 256, 0, stream>>>(rows, cols, mask8, offU, offI,
                                                      cntU, cntI, cpU, cpI);

  const int SPB = (NU + NI) / 4;   // merged spmm: (NU+NI) waves, 4/block

  // ---- propagation 0 (mask bits 17/18) -> E16u/E16i ----
  spmm_layer_kernel<<<SPB, 256, 0, stream>>>(offU, cpU, offI, cpI, av, 17,
                                             E0v8, E0u8, d8U, d8I,
                                             E16u, E16i, Eu0, Ev0);
  spmm_layer_kernel<<<SPB, 256, 0, stream>>>(offU, cpU, offI, cpI, av, 18,
                                             d8I, d8U, nullptr, nullptr,
                                             E16u, E16i, nullptr, nullptr);

  edge_logit_kernel<<<4096, 256, 0, stream>>>(E16u, E16i, rows, cols, av, augv);

  // ---- propagation 1 (mask bits 19/20) -> Z16u/Z16i ----
  spmm_layer_kernel<<<SPB, 256, 0, stream>>>(offU, cpU, offI, cpI, augv, 19,
                                             E0v8, E0u8, d8U, d8I,
                                             Z16u, Z16i, Eu0, Ev0);
  spmm_layer_kernel<<<SPB, 256, 0, stream>>>(offU, cpU, offI, cpI, augv, 20,
                                             d8I, d8U, nullptr, nullptr,
                                             Z16u, Z16i, nullptr, nullptr);

  gather2_rows_kernel<<<2 * BATCH, 64, 0, stream>>>(Z16u, uids, Zgu, Z16i, iids, Zgi);

  (void)hipMemsetAsync(Su, 0, (2 * BATCH + 16) * sizeof(float), stream);   // Su,Si,acc adjacent

  bpr_kernel<<<BATCH / 4, 256, 0, stream>>>(E16u, E16i, uids, pos, neg, ps, acc);
  minmax_kernel<<<1, 256, 0, stream>>>(ps, mm);
  bcl_kernel<<<BATCH / 4, 256, 0, stream>>>(E16u, E16i, Eb, uids, pos, ps, mm, acc);

  // PCL denominators: wave = 4 m-tiles; grid y=8 (128 m-tiles), x = n-splits
  pcl_mfma3_kernel<<<dim3(256, 8), 256, 0, stream>>>(Zgu, E16u, NU / 16, 256, Su);
  pcl_mfma3_kernel<<<dim3(128, 8), 256, 0, stream>>>(Zgi, E16i, NI / 16, 128, Si);

  pclpos2_kernel<<<2 * BATCH / 4, 256, 0, stream>>>(Z16u, E16u, uids, Z16i, E16i, iids, acc);

  sumsq3_kernel<<<1024, 256, 0, stream>>>(Eu0, NU * DD, Ev0, NI * DD, Eb, NBK * DD, acc);

  finalize_kernel<<<1, 256, 0, stream>>>(Su, Si, acc, out);
}

// Round 10
// 902.079 us; speedup vs baseline: 6.1157x; 1.2012x over previous
//
#include <hip/hip_runtime.h>
#include <stdint.h>

#define NU 100000
#define NI 50000
#define NBK 10
#define DD 64
#define NE 1000000
#define BATCH 2048
#define NSLICE 8
#define USLICE ((NU + NSLICE - 1) / NSLICE)   // 12500
#define ISLICE ((NI + NSLICE - 1) / NSLICE)   // 6250
#define NCHUNK 512
#define EPC ((NE + NCHUNK - 1) / NCHUNK)      // 1954
// fp8 storage scale: embeddings ~0.01 are subnormal in e4m3; x128 -> normal.
// Combined descale: (4/3 dropout) / 128 = 1/96.
#define FP8_SCALE 128.0f
#define SPMM_DESCALE (1.0f / 96.0f)
#define EL_DESCALE (1.0f / 16384.0f)   // edge-logit dot of two 128x fp8 tables

typedef __bf16 bf16x8 __attribute__((ext_vector_type(8)));
typedef float f32x4 __attribute__((ext_vector_type(4)));

struct Keys8 { uint32_t k[8][2]; };

// ---------------- threefry2x32 (JAX-compatible, 20 rounds) ----------------
__host__ __device__ inline void tf2x32(uint32_t k0, uint32_t k1, uint32_t x0, uint32_t x1,
                                       uint32_t& o0, uint32_t& o1) {
  uint32_t ks0 = k0, ks1 = k1, ks2 = k0 ^ k1 ^ 0x1BD11BDAu;
  x0 += ks0; x1 += ks1;
#define TFR(r) { x0 += x1; x1 = (x1 << (r)) | (x1 >> (32 - (r))); x1 ^= x0; }
  TFR(13) TFR(15) TFR(26) TFR(6)   x0 += ks1; x1 += ks2 + 1u;
  TFR(17) TFR(29) TFR(16) TFR(24)  x0 += ks2; x1 += ks0 + 2u;
  TFR(13) TFR(15) TFR(26) TFR(6)   x0 += ks0; x1 += ks1 + 3u;
  TFR(17) TFR(29) TFR(16) TFR(24)  x0 += ks1; x1 += ks2 + 4u;
  TFR(13) TFR(15) TFR(26) TFR(6)   x0 += ks2; x1 += ks0 + 5u;
#undef TFR
  o0 = x0; o1 = x1;
}

__device__ inline uint16_t f2bf(float f) {
  uint32_t u = __float_as_uint(f);
  return (uint16_t)((u + 0x7fffu + ((u >> 16) & 1u)) >> 16);   // RNE
}
__device__ inline float bf2f(uint16_t u) {
  return __uint_as_float(((uint32_t)u) << 16);
}

// ---- fp8 e4m3 (OCP) helpers ----
// byte-select must be an immediate for the builtin -> template parameter
template <int SEL>
__device__ inline float fp8_sel(uint32_t w) {
#if __has_builtin(__builtin_amdgcn_cvt_f32_fp8)
  return __builtin_amdgcn_cvt_f32_fp8((int)w, SEL);
#else
  uint32_t b = (w >> (8 * SEL)) & 0xFFu;
  uint32_t s = b >> 7, e = (b >> 3) & 0xF, m = b & 7;
  float v = (e == 0) ? (float)m * (1.0f / 512.0f)
                     : __uint_as_float(((e + 120) << 23) | (m << 20));
  return s ? -v : v;
#endif
}
__device__ inline uint32_t f32_to_fp8(float f) {
#if __has_builtin(__builtin_amdgcn_cvt_pk_fp8_f32)
  return (uint32_t)__builtin_amdgcn_cvt_pk_fp8_f32(f, f, 0, false) & 0xFFu;
#else
  uint32_t s = (__float_as_uint(f) >> 31) << 7;
  float a = fabsf(f);
  a = fminf(a, 448.0f);
  if (a < 0.015625f) {
    uint32_t m = (uint32_t)(a * 512.0f + 0.5f);
    return s | m;
  }
  int ex; float fr = frexpf(a, &ex);
  uint32_t q = (uint32_t)(fr * 16.0f + 0.5f);
  int E = ex + 6;
  if (q == 16) { q = 8; E += 1; }
  if (E > 15) { E = 15; q = 14; }
  if (E == 15 && q == 15) q = 14;
  return s | ((uint32_t)E << 3) | (q - 8);
#endif
}
__device__ inline uint32_t pack4_fp8(float a, float b, float c, float d) {
  return f32_to_fp8(a) | (f32_to_fp8(b) << 8) | (f32_to_fp8(c) << 16) | (f32_to_fp8(d) << 24);
}

__device__ inline uint32_t drop_mask(int e, uint32_t k0, uint32_t k1) {
  const uint32_t half = NE / 2;
  uint32_t lo = (e < (int)half) ? (uint32_t)e : (uint32_t)e - half;
  uint32_t o0, o1;
  tf2x32(k0, k1, lo, lo + half, o0, o1);
  uint32_t bits = (e < (int)half) ? o0 : o1;
  float u = __uint_as_float((bits >> 9) | 0x3f800000u) - 1.0f;
  return (u < 0.75f) ? 1u : 0u;
}

// dropout masks (8 bits/edge) + degree histogram, single pass over edges
__global__ void mask_hist_kernel(const int* __restrict__ rows, const int* __restrict__ cols,
                                 uint8_t* __restrict__ mask,
                                 int* __restrict__ cntU, int* __restrict__ cntI, Keys8 K) {
  int e = blockIdx.x * blockDim.x + threadIdx.x;
  if (e >= NE) return;
  uint32_t m = 0;
#pragma unroll
  for (int j = 0; j < 8; ++j) m |= drop_mask(e, K.k[j][0], K.k[j][1]) << j;
  mask[e] = (uint8_t)m;
  atomicAdd(&cntU[rows[e]], 1);
  atomicAdd(&cntI[cols[e]], 1);
}

#define SCAN_B 256
__global__ void scan_phase1(const int* __restrict__ cntU, const int* __restrict__ cntI,
                            int nbU, int* __restrict__ bs) {
  __shared__ int red[SCAN_B];
  int blk = blockIdx.x, t = threadIdx.x;
  const int* cnt; int n, j;
  if (blk < nbU) { cnt = cntU; n = NU; j = blk; }
  else { cnt = cntI; n = NI; j = blk - nbU; }
  int i = j * SCAN_B + t;
  red[t] = (i < n) ? cnt[i] : 0;
  __syncthreads();
  for (int s = 128; s > 0; s >>= 1) {
    if (t < s) red[t] += red[t + s];
    __syncthreads();
  }
  if (t == 0) bs[blk] = red[0];
}
__global__ void scan_phase2(int* __restrict__ bs, int nbU, int nbI) {
  __shared__ int sh[512];
  int t = threadIdx.x;
  int v = (t < nbU) ? bs[t] : 0;
  sh[t] = v;
  __syncthreads();
  for (int off = 1; off < 512; off <<= 1) {
    int add = (t >= off) ? sh[t - off] : 0;
    __syncthreads();
    sh[t] += add;
    __syncthreads();
  }
  if (t < nbU) bs[t] = sh[t] - v;
  __syncthreads();
  int v2 = (t < nbI) ? bs[nbU + t] : 0;
  sh[t] = v2;
  __syncthreads();
  for (int off = 1; off < 512; off <<= 1) {
    int add = (t >= off) ? sh[t - off] : 0;
    __syncthreads();
    sh[t] += add;
    __syncthreads();
  }
  if (t < nbI) bs[nbU + t] = sh[t] - v2;
}
__global__ void scan_phase3(const int* __restrict__ cntU, const int* __restrict__ cntI,
                            int nbU, const int* __restrict__ bs,
                            int* __restrict__ offU, int* __restrict__ offI) {
  __shared__ int sh[SCAN_B];
  int blk = blockIdx.x, t = threadIdx.x;
  const int* cnt; int n, j; int* off;
  if (blk < nbU) { cnt = cntU; n = NU; j = blk; off = offU; }
  else { cnt = cntI; n = NI; j = blk - nbU; off = offI; }
  int i = j * SCAN_B + t;
  int v = (i < n) ? cnt[i] : 0;
  sh[t] = v;
  __syncthreads();
  for (int o = 1; o < SCAN_B; o <<= 1) {
    int add = (t >= o) ? sh[t - o] : 0;
    __syncthreads();
    sh[t] += add;
    __syncthreads();
  }
  if (i < n) off[i] = bs[blk] + sh[t] - v;
  if (i == n - 1) off[n] = bs[blk] + sh[t];
}

// XCD-sliced scatter (slice = blockIdx&7): each output slice dirtied by one XCD.
__global__ __launch_bounds__(256)
void scatter_kernel(const int* __restrict__ rows, const int* __restrict__ cols,
                    const uint8_t* __restrict__ mask,
                    const int* __restrict__ offU, const int* __restrict__ offI,
                    int* __restrict__ fillU, int* __restrict__ fillI,
                    int2* __restrict__ cpU, int2* __restrict__ cpI) {
  int slice = blockIdx.x & 7;
  int chunk = blockIdx.x >> 3;
  int base = chunk * EPC;
  int end = base + EPC; if (end > NE) end = NE;
  for (int e = base + threadIdx.x; e < end; e += 256) {
    int r = rows[e], c = cols[e];
    uint32_t m = mask[e];
    if (r / USLICE == slice) {
      int packed = c | (int)((m & 0xFu) << 17);
      int pu = offU[r] + atomicAdd(&fillU[r], 1);
      cpU[pu] = make_int2(packed, e);
    }
    if (c / ISLICE == slice) {
      int packed = r | (int)(((m >> 4) & 0xFu) << 17);
      int pi = offI[c] + atomicAdd(&fillI[c], 1);
      cpI[pi] = make_int2(packed, e);
    }
  }
}

// merged U+I gather-reduce SpMM, sub-wave layout: wave = 4 rows x 16 lanes,
// lane covers 4 dims via one dword fp8 load (cvt_f32_fp8 byte-select).
// layer0 (base!=null): d8 = fp8(raw*4/3), sum = bf16(base + raw/96)
// layer1: sum += raw/96 (bf16 RMW); optional fp8(sum*128) table out (s8*).
__global__ __launch_bounds__(256)
void spmm_layer_kernel(const int* __restrict__ offU, const int2* __restrict__ cpU,
                       const int* __restrict__ offI, const int2* __restrict__ cpI,
                       const float* __restrict__ esrc, int shift,
                       const uint8_t* __restrict__ SU, const uint8_t* __restrict__ SI,
                       uint8_t* __restrict__ dU, uint8_t* __restrict__ dI,
                       uint16_t* __restrict__ sumU, uint16_t* __restrict__ sumI,
                       const float* __restrict__ baseU, const float* __restrict__ baseI,
                       uint8_t* __restrict__ s8U, uint8_t* __restrict__ s8I) {
  int lane = threadIdx.x & 63;
  int g = lane >> 4, l15 = lane & 15;
  int w = (blockIdx.x * blockDim.x + threadIdx.x) >> 6;
  int r = w * 4 + g;                       // NU%4==0 -> wave never straddles U/I
  const int* off; const int2* cp; const uint8_t* S;
  uint8_t* D; uint16_t* Sum; const float* base; uint8_t* S8; int row;
  if (r < NU) {
    row = r; off = offU; cp = cpU; S = SU; D = dU; Sum = sumU; base = baseU; S8 = s8U;
  } else {
    row = r - NU; off = offI; cp = cpI; S = SI; D = dI; Sum = sumI; base = baseI; S8 = s8I;
  }
  int p0 = off[row], p1 = off[row + 1];
  f32x4 acc = {0.f, 0.f, 0.f, 0.f};
  int p = p0;
  for (; p + 2 <= p1; p += 2) {            // 2 gathers in flight per group
    int2 c0 = cp[p], c1 = cp[p + 1];
    uint32_t w0 = *(const uint32_t*)(S + ((size_t)(uint32_t)(c0.x & 0x1FFFF) << 6) + l15 * 4);
    uint32_t w1 = *(const uint32_t*)(S + ((size_t)(uint32_t)(c1.x & 0x1FFFF) << 6) + l15 * 4);
    float v0 = esrc[c0.y] * (float)((c0.x >> shift) & 1);
    float v1 = esrc[c1.y] * (float)((c1.x >> shift) & 1);
    acc[0] += v0 * fp8_sel<0>(w0) + v1 * fp8_sel<0>(w1);
    acc[1] += v0 * fp8_sel<1>(w0) + v1 * fp8_sel<1>(w1);
    acc[2] += v0 * fp8_sel<2>(w0) + v1 * fp8_sel<2>(w1);
    acc[3] += v0 * fp8_sel<3>(w0) + v1 * fp8_sel<3>(w1);
  }
  if (p < p1) {
    int2 c0 = cp[p];
    float v0 = esrc[c0.y] * (float)((c0.x >> shift) & 1);
    if (v0 != 0.f) {
      uint32_t w0 = *(const uint32_t*)(S + ((size_t)(uint32_t)(c0.x & 0x1FFFF) << 6) + l15 * 4);
      acc[0] += v0 * fp8_sel<0>(w0);
      acc[1] += v0 * fp8_sel<1>(w0);
      acc[2] += v0 * fp8_sel<2>(w0);
      acc[3] += v0 * fp8_sel<3>(w0);
    }
  }
  size_t idx = (size_t)row * DD + l15 * 4;
  if (D) {
    *(uint32_t*)(D + idx) = pack4_fp8(acc[0] * (4.0f / 3.0f), acc[1] * (4.0f / 3.0f),
                                      acc[2] * (4.0f / 3.0f), acc[3] * (4.0f / 3.0f));
    float4 b4 = *(const float4*)(base + idx);
    ushort4 s;
    s.x = f2bf(b4.x + acc[0] * SPMM_DESCALE);
    s.y = f2bf(b4.y + acc[1] * SPMM_DESCALE);
    s.z = f2bf(b4.z + acc[2] * SPMM_DESCALE);
    s.w = f2bf(b4.w + acc[3] * SPMM_DESCALE);
    *(ushort4*)(Sum + idx) = s;
  } else {
    ushort4 s = *(const ushort4*)(Sum + idx);
    float s0 = bf2f(s.x) + acc[0] * SPMM_DESCALE;
    float s1 = bf2f(s.y) + acc[1] * SPMM_DESCALE;
    float s2 = bf2f(s.z) + acc[2] * SPMM_DESCALE;
    float s3 = bf2f(s.w) + acc[3] * SPMM_DESCALE;
    s.x = f2bf(s0); s.y = f2bf(s1); s.z = f2bf(s2); s.w = f2bf(s3);
    *(ushort4*)(Sum + idx) = s;
    if (S8)
      *(uint32_t*)(S8 + idx) = pack4_fp8(s0 * FP8_SCALE, s1 * FP8_SCALE,
                                         s2 * FP8_SCALE, s3 * FP8_SCALE);
  }
}

// 4 edges per wave (16 lanes x 4 dims), fp8 sum tables (64B rows)
__global__ void edge_logit_kernel(const uint8_t* __restrict__ E8u,
                                  const uint8_t* __restrict__ E8i,
                                  const int* __restrict__ rows, const int* __restrict__ cols,
                                  const float* __restrict__ av, float* __restrict__ aug) {
  int lane = threadIdx.x & 63;
  int sub = lane >> 4, l15 = lane & 15;
  int w = (blockIdx.x * blockDim.x + threadIdx.x) >> 6;
  int nw = (gridDim.x * blockDim.x) >> 6;
  for (int b = w * 4; b < NE; b += nw * 4) {
    int e = b + sub;
    uint32_t wa = *(const uint32_t*)(E8u + ((size_t)rows[e] << 6) + l15 * 4);
    uint32_t wc = *(const uint32_t*)(E8i + ((size_t)cols[e] << 6) + l15 * 4);
    float p = fp8_sel<0>(wa) * fp8_sel<0>(wc) + fp8_sel<1>(wa) * fp8_sel<1>(wc) +
              fp8_sel<2>(wa) * fp8_sel<2>(wc) + fp8_sel<3>(wa) * fp8_sel<3>(wc);
#pragma unroll
    for (int off = 8; off > 0; off >>= 1) p += __shfl_down(p, off, 16);
    if (l15 == 0) aug[e] = av[e] / (1.0f + __expf(-p * EL_DESCALE));
  }
}

// both base tables fp32 -> fp8(x128) in one launch, 4 elems/thread
__global__ void cvt2_fp8_kernel(const float4* __restrict__ a, int na4, uint32_t* __restrict__ oa,
                                const float4* __restrict__ b, int nb4, uint32_t* __restrict__ ob) {
  int total = na4 + nb4;
  for (int i = blockIdx.x * blockDim.x + threadIdx.x; i < total; i += gridDim.x * blockDim.x) {
    float4 v = (i < na4) ? a[i] : b[i - na4];
    uint32_t w = pack4_fp8(v.x * FP8_SCALE, v.y * FP8_SCALE, v.z * FP8_SCALE, v.w * FP8_SCALE);
    if (i < na4) oa[i] = w; else ob[i - na4] = w;
  }
}

// gather both Z row sets (bf16 tables, direct u16 copy)
__global__ void gather2_rows_kernel(const uint16_t* __restrict__ Z16u, const int* __restrict__ uids,
                                    uint16_t* __restrict__ ou,
                                    const uint16_t* __restrict__ Z16i, const int* __restrict__ iids,
                                    uint16_t* __restrict__ oi) {
  int b = blockIdx.x, lane = threadIdx.x;
  if (b < BATCH) ou[(size_t)b * 64 + lane] = Z16u[(size_t)uids[b] * 64 + lane];
  else {
    int bb = b - BATCH;
    oi[(size_t)bb * 64 + lane] = Z16i[(size_t)iids[bb] * 64 + lane];
  }
}

// PCL denominator: S[m] += sum_n exp(5*dot(Zg[m],E[n])), bf16 MFMA 16x16x32.
// Wave pins A-frags for EIGHT m-tiles (128 m-rows): per B-tile load it runs
// 16 MFMA + 32 exp2, and B-stream duplication halves vs 4-tile version.
__global__ __launch_bounds__(256)
void pcl_mfma4_kernel(const uint16_t* __restrict__ Zg, const uint16_t* __restrict__ E16,
                      int NT, int SPL, float* __restrict__ S) {
  int lane = threadIdx.x & 63;
  int wave = threadIdx.x >> 6;
  int quad = lane >> 4, l15 = lane & 15;
  int mt0 = (blockIdx.y * 4 + wave) * 8;       // 8 consecutive m-tiles per wave
  bf16x8 a0[8], a1[8];
#pragma unroll
  for (int i = 0; i < 8; ++i) {
    const uint16_t* ar = Zg + (size_t)((mt0 + i) * 16 + l15) * 64 + quad * 8;
    a0[i] = *(const bf16x8*)ar;
    a1[i] = *(const bf16x8*)(ar + 32);
  }
  f32x4 rs[8] = {};
  int nt = blockIdx.x;
  bf16x8 b0 = {}, b1 = {};
  if (nt < NT) {
    const uint16_t* br = E16 + (size_t)(nt * 16 + l15) * 64 + quad * 8;
    b0 = *(const bf16x8*)br;
    b1 = *(const bf16x8*)(br + 32);
  }
  const float LOG2E5 = 7.2134752f;             // 5*log2(e): exp(5x)=2^(x*LOG2E5)
  while (nt < NT) {
    int nn = nt + SPL;
    bf16x8 p0 = {}, p1 = {};
    if (nn < NT) {
      const uint16_t* pr = E16 + (size_t)(nn * 16 + l15) * 64 + quad * 8;
      p0 = *(const bf16x8*)pr;
      p1 = *(const bf16x8*)(pr + 32);
    }
#pragma unroll
    for (int i = 0; i < 8; ++i) {
      f32x4 c = {0.f, 0.f, 0.f, 0.f};
      c = __builtin_amdgcn_mfma_f32_16x16x32_bf16(a0[i], b0, c, 0, 0, 0);
      c = __builtin_amdgcn_mfma_f32_16x16x32_bf16(a1[i], b1, c, 0, 0, 0);
#pragma unroll
      for (int r = 0; r < 4; ++r) rs[i][r] += __builtin_amdgcn_exp2f(c[r] * LOG2E5);
    }
    b0 = p0; b1 = p1; nt = nn;
  }
#pragma unroll
  for (int off = 8; off > 0; off >>= 1) {
#pragma unroll
    for (int i = 0; i < 8; ++i)
#pragma unroll
      for (int r = 0; r < 4; ++r) rs[i][r] += __shfl_down(rs[i][r], off, 16);
  }
  if (l15 == 0) {
#pragma unroll
    for (int i = 0; i < 8; ++i)
#pragma unroll
      for (int r = 0; r < 4; ++r)
        atomicAdd(&S[(mt0 + i) * 16 + quad * 4 + r], rs[i][r]);
  }
}

__global__ void bpr_kernel(const uint16_t* __restrict__ E16u, const uint16_t* __restrict__ E16i,
                           const int* __restrict__ uids, const int* __restrict__ pos,
                           const int* __restrict__ neg, float* __restrict__ ps,
                           float* __restrict__ acc) {
  int lane = threadIdx.x & 63;
  int b = (blockIdx.x * blockDim.x + threadIdx.x) >> 6;
  if (b >= BATCH) return;
  float u = bf2f(E16u[(size_t)uids[b] * DD + lane]);
  float p = u * bf2f(E16i[(size_t)pos[b] * DD + lane]);
  float n = u * bf2f(E16i[(size_t)neg[b] * DD + lane]);
#pragma unroll
  for (int off = 32; off > 0; off >>= 1) { p += __shfl_down(p, off); n += __shfl_down(n, off); }
  if (lane == 0) {
    ps[b] = p;
    float x = p - n;
    atomicAdd(&acc[0], logf(1.0f / (1.0f + __expf(-x))));
  }
}

__global__ void minmax_kernel(const float* __restrict__ ps, float* __restrict__ mm) {
  __shared__ float smn[256], smx[256];
  int tid = threadIdx.x;
  float mn = 3.0e38f, mx = -3.0e38f;
  for (int i = tid; i < BATCH; i += 256) { float v = ps[i]; mn = fminf(mn, v); mx = fmaxf(mx, v); }
  smn[tid] = mn; smx[tid] = mx;
  __syncthreads();
  for (int s = 128; s > 0; s >>= 1) {
    if (tid < s) { smn[tid] = fminf(smn[tid], smn[tid + s]); smx[tid] = fmaxf(smx[tid], smx[tid + s]); }
    __syncthreads();
  }
  if (tid == 0) { mm[0] = smn[0]; mm[1] = smx[0]; }
}

__global__ void bcl_kernel(const uint16_t* __restrict__ E16u, const uint16_t* __restrict__ E16i,
                           const float* __restrict__ Eb, const int* __restrict__ uids,
                           const int* __restrict__ pos, const float* __restrict__ ps,
                           const float* __restrict__ mm, float* __restrict__ acc) {
  int lane = threadIdx.x & 63;
  int b = (blockIdx.x * blockDim.x + threadIdx.x) >> 6;
  if (b >= BATCH) return;
  float wgt = (ps[b] - mm[0]) / (mm[1] - mm[0] + 1e-9f);
  int rel = (int)(wgt * 10.0f);
  rel = rel < 0 ? 0 : (rel > 9 ? 9 : rel);
  float x = bf2f(E16u[(size_t)uids[b] * DD + lane]) * bf2f(E16i[(size_t)pos[b] * DD + lane]);
  float el = 1.0f / (1.0f + __expf(-x));
  float sneg = 0.f, spos = 0.f;
  for (int k = 0; k < NBK; ++k) {
    float d = el * Eb[k * DD + lane];
#pragma unroll
    for (int off = 32; off > 0; off >>= 1) d += __shfl_down(d, off);
    if (lane == 0) { if (k == rel) spos = d; else sneg += d; }
  }
  if (lane == 0) {
    atomicAdd(&acc[5], sneg * 0.1f);
    atomicAdd(&acc[6], spos);
  }
}

__global__ void pclpos2_kernel(const uint16_t* __restrict__ Z16u, const uint16_t* __restrict__ E16u,
                               const int* __restrict__ uids,
                               const uint16_t* __restrict__ Z16i, const uint16_t* __restrict__ E16i,
                               const int* __restrict__ iids, float* __restrict__ acc) {
  int lane = threadIdx.x & 63;
  int b = (blockIdx.x * blockDim.x + threadIdx.x) >> 6;
  if (b >= 2 * BATCH) return;
  const uint16_t *Z, *E; const int* ids; int idx, bb;
  if (b < BATCH) { Z = Z16u; E = E16u; ids = uids; idx = 3; bb = b; }
  else { Z = Z16i; E = E16i; ids = iids; idx = 4; bb = b - BATCH; }
  size_t r = (size_t)ids[bb] * DD + lane;
  float p = bf2f(Z[r]) * bf2f(E[r]);
#pragma unroll
  for (int off = 32; off > 0; off >>= 1) p += __shfl_down(p, off);
  if (lane == 0) {
    float x = p * 5.0f;
    x = fminf(5.0f, fmaxf(-5.0f, x));
    atomicAdd(&acc[idx], x);
  }
}

__global__ void sumsq3_kernel(const float* __restrict__ a, int na,
                              const float* __restrict__ b, int nb,
                              const float* __restrict__ c, int nc,
                              float* __restrict__ acc) {
  __shared__ float red[256];
  int tid = threadIdx.x;
  int total = na + nb + nc;
  float s = 0.f;
  for (int i = blockIdx.x * blockDim.x + tid; i < total; i += gridDim.x * blockDim.x) {
    float v = (i < na) ? a[i] : (i < na + nb) ? b[i - na] : c[i - na - nb];
    s += v * v;
  }
  red[tid] = s;
  __syncthreads();
  for (int st = 128; st > 0; st >>= 1) {
    if (tid < st) red[tid] += red[tid + st];
    __syncthreads();
  }
  if (tid == 0) atomicAdd(&acc[7], red[0]);
}

__global__ void finalize_kernel(const float* __restrict__ Su, const float* __restrict__ Si,
                                const float* __restrict__ acc, float* __restrict__ out) {
  __shared__ float r1[256], r2[256];
  int tid = threadIdx.x;
  float su = 0.f, si = 0.f;
  for (int b = tid; b < BATCH; b += 256) {
    su += logf(Su[b] + 1e-8f);
    si += logf(Si[b] + 1e-8f);
  }
  r1[tid] = su; r2[tid] = si;
  __syncthreads();
  for (int s = 128; s > 0; s >>= 1) {
    if (tid < s) { r1[tid] += r1[tid + s]; r2[tid] += r2[tid + s]; }
    __syncthreads();
  }
  if (tid == 0) {
    const float inv = 1.0f / (float)BATCH;
    float neg_s = (r1[0] + r2[0]) * inv;
    float pos_s = (acc[3] + acc[4]) * inv;
    float pcl = neg_s - pos_s;
    float bpr = -acc[0] * inv;
    float bcl = (acc[5] - acc[6]) * inv;
    float reg = 1e-7f * acc[7];
    float loss = bpr + 0.2f * pcl + 0.2f * bcl + reg;
    out[0] = loss; out[1] = bpr; out[2] = 0.2f * pcl; out[3] = 0.2f * bcl;
  }
}

extern "C" void kernel_launch(void* const* d_in, const int* in_sizes, int n_in,
                              void* d_out, int out_size, void* d_ws, size_t ws_size,
                              hipStream_t stream) {
  (void)in_sizes; (void)n_in; (void)out_size; (void)ws_size;
  const float* Eu0 = (const float*)d_in[0];
  const float* Ev0 = (const float*)d_in[1];
  const float* Eb  = (const float*)d_in[2];
  const float* av  = (const float*)d_in[3];
  const int* rows  = (const int*)d_in[4];
  const int* cols  = (const int*)d_in[5];
  const int* uids  = (const int*)d_in[6];
  const int* iids  = (const int*)d_in[7];
  const int* pos   = (const int*)d_in[8];
  const int* neg   = (const int*)d_in[9];
  float* out = (float*)d_out;

  float* w = (float*)d_ws;
  size_t o = 0;
  float* augv = w + o; o += NE;
  float* ps  = w + o; o += BATCH;
  float* Su  = w + o; o += BATCH;
  float* Si  = w + o; o += BATCH;
  float* acc = w + o; o += 16;
  float* mm  = w + o; o += 2;
  // bf16 running-sum tables + gathered Z rows
  uint16_t* hp = (uint16_t*)(w + o);
  uint16_t* E16u = hp; hp += (size_t)NU * DD;
  uint16_t* E16i = hp; hp += (size_t)NI * DD;
  uint16_t* Z16u = hp; hp += (size_t)NU * DD;
  uint16_t* Z16i = hp; hp += (size_t)NI * DD;
  uint16_t* Zgu  = hp; hp += (size_t)BATCH * DD;
  uint16_t* Zgi  = hp; hp += (size_t)BATCH * DD;
  // fp8 tables
  uint8_t* bp = (uint8_t*)hp;
  uint8_t* E0u8 = bp; bp += (size_t)NU * DD;    // fp8(128*Eu0)
  uint8_t* E0v8 = bp; bp += (size_t)NI * DD;
  uint8_t* d8U  = bp; bp += (size_t)NU * DD;    // layer0 outs (fp8, 128x)
  uint8_t* d8I  = bp; bp += (size_t)NI * DD;
  uint8_t* E8su = bp; bp += (size_t)NU * DD;    // fp8(128*E_u sums) for edge_logit
  uint8_t* E8si = bp; bp += (size_t)NI * DD;
  uint8_t* mask8 = bp; bp += NE;
  // int region (8B aligned)
  int* ip = (int*)(((uintptr_t)bp + 7) & ~(uintptr_t)7);
  int* offU = ip; ip += NU + 1;
  int* offI = ip; ip += NI + 1;
  int* cntU = ip; ip += NU;
  int* cntI = ip; ip += NI;
  ip += 2;
  int2* cpU = (int2*)ip; ip += 2 * (size_t)NE;
  int2* cpI = (int2*)ip; ip += 2 * (size_t)NE;

  // key chain: key(42) = (0,42); fold_in(k,d) = threefry2x32(k, [0,d])
  uint32_t bk[2][2];
  tf2x32(0u, 42u, 0u, 0u, bk[0][0], bk[0][1]);
  tf2x32(0u, 42u, 0u, 1u, bk[1][0], bk[1][1]);
  Keys8 K;
  for (int p = 0; p < 2; ++p)
    for (int l = 0; l < 2; ++l) {
      tf2x32(bk[p][0], bk[p][1], 0u, (uint32_t)(2 * l),     K.k[p * 2 + l][0], K.k[p * 2 + l][1]);
      tf2x32(bk[p][0], bk[p][1], 0u, (uint32_t)(2 * l + 1), K.k[4 + p * 2 + l][0], K.k[4 + p * 2 + l][1]);
    }

  const int EB = (NE + 255) / 256;
  const int nbU = (NU + SCAN_B - 1) / SCAN_B;
  const int nbI = (NI + SCAN_B - 1) / SCAN_B;

  cvt2_fp8_kernel<<<2048, 256, 0, stream>>>((const float4*)Eu0, NU * DD / 4, (uint32_t*)E0u8,
                                            (const float4*)Ev0, NI * DD / 4, (uint32_t*)E0v8);
  (void)hipMemsetAsync(cntU, 0, (size_t)(NU + NI) * sizeof(int), stream);
  mask_hist_kernel<<<EB, 256, 0, stream>>>(rows, cols, mask8, cntU, cntI, K);
  {
    int* bs = (int*)cpU;
    scan_phase1<<<nbU + nbI, SCAN_B, 0, stream>>>(cntU, cntI, nbU, bs);
    scan_phase2<<<1, 512, 0, stream>>>(bs, nbU, nbI);
    scan_phase3<<<nbU + nbI, SCAN_B, 0, stream>>>(cntU, cntI, nbU, bs, offU, offI);
  }
  (void)hipMemsetAsync(cntU, 0, (size_t)(NU + NI) * sizeof(int), stream);
  scatter_kernel<<<NCHUNK * NSLICE, 256, 0, stream>>>(rows, cols, mask8, offU, offI,
                                                      cntU, cntI, cpU, cpI);

  const int SPB = (NU + NI) / 16;   // 4 rows/wave, 4 waves/block -> 9375 blocks

  // ---- propagation 0 (mask bits 17/18) -> E16u/E16i (+fp8 sums) ----
  spmm_layer_kernel<<<SPB, 256, 0, stream>>>(offU, cpU, offI, cpI, av, 17,
                                             E0v8, E0u8, d8U, d8I,
                                             E16u, E16i, Eu0, Ev0, nullptr, nullptr);
  spmm_layer_kernel<<<SPB, 256, 0, stream>>>(offU, cpU, offI, cpI, av, 18,
                                             d8I, d8U, nullptr, nullptr,
                                             E16u, E16i, nullptr, nullptr, E8su, E8si);

  edge_logit_kernel<<<4096, 256, 0, stream>>>(E8su, E8si, rows, cols, av, augv);

  // ---- propagation 1 (mask bits 19/20) -> Z16u/Z16i ----
  spmm_layer_kernel<<<SPB, 256, 0, stream>>>(offU, cpU, offI, cpI, augv, 19,
                                             E0v8, E0u8, d8U, d8I,
                                             Z16u, Z16i, Eu0, Ev0, nullptr, nullptr);
  spmm_layer_kernel<<<SPB, 256, 0, stream>>>(offU, cpU, offI, cpI, augv, 20,
                                             d8I, d8U, nullptr, nullptr,
                                             Z16u, Z16i, nullptr, nullptr, nullptr, nullptr);

  gather2_rows_kernel<<<2 * BATCH, 64, 0, stream>>>(Z16u, uids, Zgu, Z16i, iids, Zgi);

  (void)hipMemsetAsync(Su, 0, (2 * BATCH + 16) * sizeof(float), stream);

  bpr_kernel<<<BATCH / 4, 256, 0, stream>>>(E16u, E16i, uids, pos, neg, ps, acc);
  minmax_kernel<<<1, 256, 0, stream>>>(ps, mm);
  bcl_kernel<<<BATCH / 4, 256, 0, stream>>>(E16u, E16i, Eb, uids, pos, ps, mm, acc);

  // PCL denominators: wave = 8 m-tiles; grid y=4 (128 m-tiles), x = n-splits
  pcl_mfma4_kernel<<<dim3(256, 4), 256, 0, stream>>>(Zgu, E16u, NU / 16, 256, Su);
  pcl_mfma4_kernel<<<dim3(128, 4), 256, 0, stream>>>(Zgi, E16i, NI / 16, 128, Si);

  pclpos2_kernel<<<2 * BATCH / 4, 256, 0, stream>>>(Z16u, E16u, uids, Z16i, E16i, iids, acc);

  sumsq3_kernel<<<1024, 256, 0, stream>>>(Eu0, NU * DD, Ev0, NI * DD, Eb, NBK * DD, acc);

  finalize_kernel<<<1, 256, 0, stream>>>(Su, Si, acc, out);
}